// Round 1
// baseline (1245.433 us; speedup 1.0000x reference)
//
#include <hip/hip_runtime.h>
#include <math.h>

#define GH 128
#define GW 128
#define HWC 16384
#define CW 64
#define NM 24
#define NKX 48
#define NMODE 1152
#define PI_F 3.14159265358979323846f

__device__ __forceinline__ float gelu_f(float x) {
  return 0.5f * x * (1.0f + erff(x * 0.70710678118654752f));
}

// ---------------- points: deform MLP + lift + scatter + bilinear data ----------------
__global__ __launch_bounds__(256) void k_points(
    const float* __restrict__ coords, const float* __restrict__ feats,
    const float* __restrict__ dw0, const float* __restrict__ db0,
    const float* __restrict__ dw1, const float* __restrict__ db1,
    const float* __restrict__ dw2, const float* __restrict__ db2,
    const float* __restrict__ lw, const float* __restrict__ lb,
    float* __restrict__ sums, float* __restrict__ cnts,
    int* __restrict__ pd_idx, float* __restrict__ pd_th, float* __restrict__ pd_tw)
{
  __shared__ float s_dw0[64], s_db0[32], s_dw1[1024], s_db1[32], s_dw2[64], s_db2[2], s_lw[320], s_lb[64];
  int t = threadIdx.x;
  for (int i = t; i < 1024; i += 256) s_dw1[i] = dw1[i];
  for (int i = t; i < 320;  i += 256) s_lw[i] = lw[i];
  if (t < 64) { s_dw0[t] = dw0[t]; s_dw2[t] = dw2[t]; s_lb[t] = lb[t]; }
  if (t < 32) { s_db0[t] = db0[t]; s_db1[t] = db1[t]; }
  if (t < 2)  { s_db2[t] = db2[t]; }
  __syncthreads();

  int pid = blockIdx.x * 256 + t;
  float2 c = ((const float2*)coords)[pid];
  float h1[32], h2[32];
#pragma unroll
  for (int j = 0; j < 32; ++j)
    h1[j] = gelu_f(fmaf(c.x, s_dw0[j], fmaf(c.y, s_dw0[32 + j], s_db0[j])));
#pragma unroll
  for (int j = 0; j < 32; ++j) {
    float a = s_db1[j];
#pragma unroll
    for (int k = 0; k < 32; ++k) a = fmaf(h1[k], s_dw1[k * 32 + j], a);
    h2[j] = gelu_f(a);
  }
  float d0 = s_db2[0], d1 = s_db2[1];
#pragma unroll
  for (int k = 0; k < 32; ++k) { d0 = fmaf(h2[k], s_dw2[2 * k], d0); d1 = fmaf(h2[k], s_dw2[2 * k + 1], d1); }
  float l0 = fminf(fmaxf(c.x + d0, -1.f), 1.f);
  float l1 = fminf(fmaxf(c.y + d1, -1.f), 1.f);
  float ph = (l0 + 1.f) * 0.5f * 127.f;
  float pw = (l1 + 1.f) * 0.5f * 127.f;
  int ih = min(max((int)rintf(ph), 0), 127);
  int iw = min(max((int)rintf(pw), 0), 127);
  int b = pid >> 14;
  int cell = b * HWC + ih * GW + iw;

  float f0 = feats[pid * 3], f1 = feats[pid * 3 + 1], f2 = feats[pid * 3 + 2];
  float* srow = sums + (size_t)cell * 64;
#pragma unroll
  for (int o = 0; o < 64; ++o) {
    float v = s_lb[o];
    v = fmaf(f0, s_lw[o], v);
    v = fmaf(f1, s_lw[64 + o], v);
    v = fmaf(f2, s_lw[128 + o], v);
    v = fmaf(c.x, s_lw[192 + o], v);
    v = fmaf(c.y, s_lw[256 + o], v);
    atomicAdd(srow + o, v);
  }
  atomicAdd(cnts + cell, 1.f);

  float fh = floorf(ph), fw = floorf(pw);
  int h0i = min(max((int)fh, 0), 127), w0i = min(max((int)fw, 0), 127);
  pd_idx[pid] = h0i | (w0i << 8);
  pd_th[pid] = ph - fh;
  pd_tw[pid] = pw - fw;
}

// ---------------- scatter-mean normalize: (B,HW,C) sums -> (B,C,HW) grid ----------------
__global__ __launch_bounds__(256) void k_gridnorm(const float* __restrict__ sums,
                                                  const float* __restrict__ cnts,
                                                  float* __restrict__ G)
{
  __shared__ float tile[64][129];
  int b = blockIdx.y;
  int cbase = blockIdx.x * 128;
  for (int l = threadIdx.x; l < 8192; l += 256) {
    int ch = l & 63, cl = l >> 6;
    tile[ch][cl] = sums[(size_t)(b * HWC + cbase + cl) * 64 + ch];
  }
  __syncthreads();
  int cl = threadIdx.x & 127;
  int oh = threadIdx.x >> 7;
  float cnt = cnts[b * HWC + cbase + cl];
  float inv = 1.f / fmaxf(cnt, 1.f);
  for (int j = 0; j < 32; ++j) {
    int o = oh * 32 + j;
    G[(size_t)(b * 64 + o) * HWC + cbase + cl] = tile[o][cl] * inv;
  }
}

// ---------------- forward DFT along w: G(B,C,H,W) -> Xw(B,C,24,H) complex ----------------
__global__ __launch_bounds__(256) void k_dft_w(const float* __restrict__ G,
                                               float* __restrict__ Xwr, float* __restrict__ Xwi)
{
  __shared__ float img[64][133];
  int bc = blockIdx.x;
  int tid = threadIdx.x;
  int hq = tid >> 3, kg = tid & 7;
  float stc[3], sts[3];
#pragma unroll
  for (int tt = 0; tt < 3; ++tt) {
    float s, c2;
    sincosf((float)(kg * 3 + tt) * (PI_F / 64.f), &s, &c2);
    sts[tt] = s; stc[tt] = c2;
  }
  for (int half = 0; half < 2; ++half) {
    for (int l = tid; l < 8192; l += 256) {
      int hl = l >> 7, w = l & 127;
      img[hl][w] = G[(size_t)bc * HWC + (half * 64 + hl) * 128 + w];
    }
    __syncthreads();
    float aR0[3] = {0,0,0}, aI0[3] = {0,0,0}, aR1[3] = {0,0,0}, aI1[3] = {0,0,0};
    float pR[3] = {1.f,1.f,1.f}, pI[3] = {0.f,0.f,0.f};
    int h0 = hq * 2;
    for (int w = 0; w < 128; ++w) {
      float x0 = img[h0][w], x1 = img[h0 + 1][w];
#pragma unroll
      for (int tt = 0; tt < 3; ++tt) {
        aR0[tt] = fmaf(x0, pR[tt], aR0[tt]);
        aI0[tt] = fmaf(x0, pI[tt], aI0[tt]);
        aR1[tt] = fmaf(x1, pR[tt], aR1[tt]);
        aI1[tt] = fmaf(x1, pI[tt], aI1[tt]);
        // multiply phasor by e^{-i theta}: (c, -s)
        float nr = fmaf(pR[tt], stc[tt], pI[tt] * sts[tt]);
        pI[tt] = fmaf(pI[tt], stc[tt], -pR[tt] * sts[tt]);
        pR[tt] = nr;
      }
    }
    int hg = half * 64 + h0;
#pragma unroll
    for (int tt = 0; tt < 3; ++tt) {
      int ky = kg * 3 + tt;
      int o = (bc * 24 + ky) * 128 + hg;
      Xwr[o] = aR0[tt]; Xwr[o + 1] = aR1[tt];
      Xwi[o] = aI0[tt]; Xwi[o + 1] = aI1[tt];
    }
    __syncthreads();
  }
}

// ---------------- forward DFT along h: Xw(B,C,24,H) -> Xf(B,C,1152) complex ----------------
__global__ __launch_bounds__(192) void k_dft_h(const float* __restrict__ Xwr, const float* __restrict__ Xwi,
                                               float* __restrict__ Xfr, float* __restrict__ Xfi)
{
  __shared__ float2 xw[24][130];
  int bc = blockIdx.x;
  int tid = threadIdx.x;
  for (int l = tid; l < 3072; l += 192) {
    int ky = l >> 7, h = l & 127;
    int o = (bc * 24 + ky) * 128 + h;
    xw[ky][h] = make_float2(Xwr[o], Xwi[o]);
  }
  __syncthreads();
  int kxi = tid >> 2, kg = tid & 3;
  int kxe = kxi < 24 ? kxi : kxi + 80;
  float sn, cn;
  sincosf((float)kxe * (PI_F / 64.f), &sn, &cn);
  float aR[6] = {0,0,0,0,0,0}, aI[6] = {0,0,0,0,0,0};
  float pR = 1.f, pI = 0.f;
  for (int h = 0; h < 128; ++h) {
#pragma unroll
    for (int tt = 0; tt < 6; ++tt) {
      float2 v = xw[kg * 6 + tt][h];
      aR[tt] = fmaf(v.x, pR, aR[tt]); aR[tt] = fmaf(-v.y, pI, aR[tt]);
      aI[tt] = fmaf(v.x, pI, aI[tt]); aI[tt] = fmaf(v.y, pR, aI[tt]);
    }
    float nr = fmaf(pR, cn, pI * sn);   // e^{-i theta}
    pI = fmaf(pI, cn, -pR * sn);
    pR = nr;
  }
#pragma unroll
  for (int tt = 0; tt < 6; ++tt) {
    int m = kxi * 24 + kg * 6 + tt;
    Xfr[bc * NMODE + m] = aR[tt];
    Xfi[bc * NMODE + m] = aI[tt];
  }
}

// ---------------- per-mode 64x64 complex channel mix ----------------
__global__ __launch_bounds__(64) void k_mix(const float* __restrict__ Xfr, const float* __restrict__ Xfi,
    const float* __restrict__ w1r, const float* __restrict__ w1i,
    const float* __restrict__ w2r, const float* __restrict__ w2i,
    float* __restrict__ Yfr, float* __restrict__ Yfi)
{
  int m = blockIdx.x * 64 + threadIdx.x;     // 0..575 within half
  int o0 = blockIdx.y * 4;
  int half = blockIdx.z >> 1;
  int b0 = (blockIdx.z & 1) * 4;
  int gm = half * 576 + m;
  const float* wr_ = half ? w2r : w1r;
  const float* wi_ = half ? w2i : w1i;
  float aR[4][4] = {}, aI[4][4] = {};
  for (int i = 0; i < 64; ++i) {
    float wr[4], wi[4];
#pragma unroll
    for (int oq = 0; oq < 4; ++oq) {
      int widx = (i * 64 + o0 + oq) * 576 + m;
      wr[oq] = wr_[widx]; wi[oq] = wi_[widx];
    }
#pragma unroll
    for (int bq = 0; bq < 4; ++bq) {
      int xb = ((b0 + bq) * 64 + i) * NMODE + gm;
      float xr = Xfr[xb], xi = Xfi[xb];
#pragma unroll
      for (int oq = 0; oq < 4; ++oq) {
        aR[bq][oq] = fmaf(xr, wr[oq], aR[bq][oq]);
        aR[bq][oq] = fmaf(-xi, wi[oq], aR[bq][oq]);
        aI[bq][oq] = fmaf(xr, wi[oq], aI[bq][oq]);
        aI[bq][oq] = fmaf(xi, wr[oq], aI[bq][oq]);
      }
    }
  }
#pragma unroll
  for (int bq = 0; bq < 4; ++bq)
#pragma unroll
    for (int oq = 0; oq < 4; ++oq) {
      int yi = ((b0 + bq) * 64 + o0 + oq) * NMODE + gm;
      Yfr[yi] = aR[bq][oq]; Yfi[yi] = aI[bq][oq];
    }
}

// ---------------- inverse DFT along kx: Yf(B,C,1152) -> Tw(B,C,24,H) complex ----------------
__global__ __launch_bounds__(256) void k_idft_h(const float* __restrict__ Yfr, const float* __restrict__ Yfi,
                                                float* __restrict__ Twr, float* __restrict__ Twi)
{
  __shared__ float2 yf[48][24];
  int bc = blockIdx.x;
  int tid = threadIdx.x;
  for (int l = tid; l < 1152; l += 256) {
    int kxi = l / 24, ky = l - kxi * 24;
    yf[kxi][ky] = make_float2(Yfr[bc * NMODE + l], Yfi[bc * NMODE + l]);
  }
  __syncthreads();
  int h = tid & 127, kyb = (tid >> 7) * 12;
  float aR[12] = {}, aI[12] = {};
  float sc, cc;
  sincosf((float)h * (PI_F / 64.f), &sc, &cc);
  float pR = 1.f, pI = 0.f;
  for (int run = 0; run < 2; ++run) {
    if (run == 1) {
      int k0 = (104 * h) & 127;
      sincosf((float)k0 * (PI_F / 64.f), &pI, &pR);  // sin -> pI, cos -> pR
    }
    int kxs = run * 24;
    for (int kk = 0; kk < 24; ++kk) {
      int kxi = kxs + kk;
#pragma unroll
      for (int q = 0; q < 12; ++q) {
        float2 v = yf[kxi][kyb + q];
        aR[q] = fmaf(v.x, pR, aR[q]); aR[q] = fmaf(-v.y, pI, aR[q]);
        aI[q] = fmaf(v.x, pI, aI[q]); aI[q] = fmaf(v.y, pR, aI[q]);
      }
      float nr = fmaf(pR, cc, -pI * sc);  // e^{+i theta}
      pI = fmaf(pI, cc, pR * sc);
      pR = nr;
    }
  }
#pragma unroll
  for (int q = 0; q < 12; ++q) {
    int o = (bc * 24 + kyb + q) * 128 + h;
    Twr[o] = aR[q]; Twi[o] = aI[q];
  }
}

// ---------------- pointwise conv: y = G @ pw + bias ----------------
__global__ __launch_bounds__(256) void k_pw(const float* __restrict__ G, const float* __restrict__ pww,
                                            const float* __restrict__ pwb, float* __restrict__ y)
{
  __shared__ float g_lds[64][132];
  __shared__ float pw_lds[64][64];
  int b = blockIdx.y;
  int pbase = blockIdx.x * 128;
  int tid = threadIdx.x;
  for (int l = tid; l < 8192; l += 256) {
    int i = l >> 7, p = l & 127;
    g_lds[i][p] = G[(size_t)(b * 64 + i) * HWC + pbase + p];
  }
  for (int l = tid; l < 4096; l += 256) pw_lds[l >> 6][l & 63] = pww[l];
  __syncthreads();
  int og = tid >> 5, pg = tid & 31;
  int o0 = og * 8, px0 = pg * 4;
  float acc[8][4] = {};
  for (int i = 0; i < 64; ++i) {
    float4 xv = *(const float4*)&g_lds[i][px0];
    float4 wa = *(const float4*)&pw_lds[i][o0];
    float4 wb = *(const float4*)&pw_lds[i][o0 + 4];
    float xs[4] = {xv.x, xv.y, xv.z, xv.w};
    float wv[8] = {wa.x, wa.y, wa.z, wa.w, wb.x, wb.y, wb.z, wb.w};
#pragma unroll
    for (int oo = 0; oo < 8; ++oo)
#pragma unroll
      for (int j = 0; j < 4; ++j) acc[oo][j] = fmaf(xs[j], wv[oo], acc[oo][j]);
  }
#pragma unroll
  for (int oo = 0; oo < 8; ++oo) {
    float bias = pwb[o0 + oo];
    float4 v = make_float4(acc[oo][0] + bias, acc[oo][1] + bias, acc[oo][2] + bias, acc[oo][3] + bias);
    *(float4*)&y[(size_t)(b * 64 + o0 + oo) * HWC + pbase + px0] = v;
  }
}

// ---------------- inverse DFT along ky + add + instnorm stats ----------------
__global__ __launch_bounds__(256) void k_idft_w(const float* __restrict__ Twr, const float* __restrict__ Twi,
                                                float* __restrict__ y, float* __restrict__ stats)
{
  __shared__ float2 t_lds[128][26];
  __shared__ float2 cs[24][132];
  __shared__ float rs[256], rq[256];
  int bc = blockIdx.x;
  int tid = threadIdx.x;
  for (int l = tid; l < 3072; l += 256) {
    int ky = l >> 7, x = l & 127;
    int o = (bc * 24 + ky) * 128 + x;
    t_lds[x][ky] = make_float2(Twr[o], Twi[o]);
    int k = (ky * x) & 127;
    float s, c2; sincosf((float)k * (PI_F / 64.f), &s, &c2);
    cs[ky][x] = make_float2(c2, s);
  }
  __syncthreads();
  int w = tid & 127, hh = tid >> 7;
  float csr[23], csi[23];
#pragma unroll
  for (int ky = 1; ky < 24; ++ky) { float2 cc = cs[ky][w]; csr[ky - 1] = cc.x; csi[ky - 1] = cc.y; }
  float sum = 0.f, ssq = 0.f;
  for (int h = hh * 64; h < hh * 64 + 64; ++h) {
    float t0 = t_lds[h][0].x;
    float s2 = 0.f;
#pragma unroll
    for (int ky = 1; ky < 24; ++ky) {
      float2 tv = t_lds[h][ky];
      s2 = fmaf(tv.x, csr[ky - 1], s2);
      s2 = fmaf(-tv.y, csi[ky - 1], s2);
    }
    int p = bc * HWC + h * 128 + w;
    float v = y[p] + (t0 + 2.f * s2) * (1.f / 16384.f);
    y[p] = v;
    sum += v; ssq = fmaf(v, v, ssq);
  }
  rs[tid] = sum; rq[tid] = ssq;
  __syncthreads();
  for (int sft = 128; sft > 0; sft >>= 1) {
    if (tid < sft) { rs[tid] += rs[tid + sft]; rq[tid] += rq[tid + sft]; }
    __syncthreads();
  }
  if (tid == 0) {
    float mu = rs[0] * (1.f / 16384.f);
    float var = fmaxf(rq[0] * (1.f / 16384.f) - mu * mu, 0.f);
    stats[bc * 2] = mu;
    stats[bc * 2 + 1] = rsqrtf(var + 1e-5f);
  }
}

// ---------------- instance-norm apply + gelu ----------------
__global__ __launch_bounds__(256) void k_norm_gelu(const float* __restrict__ y,
                                                   const float* __restrict__ stats,
                                                   float* __restrict__ G)
{
  int idx4 = blockIdx.x * 256 + threadIdx.x;
  int bc = idx4 >> 12;
  float mu = stats[bc * 2], rstd = stats[bc * 2 + 1];
  float4 v = ((const float4*)y)[idx4];
  v.x = gelu_f((v.x - mu) * rstd);
  v.y = gelu_f((v.y - mu) * rstd);
  v.z = gelu_f((v.z - mu) * rstd);
  v.w = gelu_f((v.w - mu) * rstd);
  ((float4*)G)[idx4] = v;
}

// ---------------- G2P bilinear gather + projection MLP ----------------
__global__ __launch_bounds__(256) void k_g2p(const float* __restrict__ G,
    const int* __restrict__ pd_idx, const float* __restrict__ pd_th, const float* __restrict__ pd_tw,
    const float* __restrict__ p1w, const float* __restrict__ p1b,
    const float* __restrict__ p2w, const float* __restrict__ p2b,
    float* __restrict__ out)
{
  __shared__ float s_lds[64][65];
  __shared__ float p1_lds[64][128];
  __shared__ float p1b_lds[128];
  __shared__ float p2_lds[128];
  __shared__ float red[4][64];
  int tid = threadIdx.x;
  for (int l = tid; l < 8192; l += 256) ((float*)p1_lds)[l] = p1w[l];
  if (tid < 128) { p1b_lds[tid] = p1b[tid]; p2_lds[tid] = p2w[tid]; }

  int pt = tid & 63, og = tid >> 6;
  int pid = blockIdx.x * 64 + pt;
  int b = pid >> 14;
  int packed = pd_idx[pid];
  float th = pd_th[pid], tw = pd_tw[pid];
  int h0 = packed & 255, w0 = (packed >> 8) & 255;
  int h1 = min(h0 + 1, 127), w1 = min(w0 + 1, 127);
  int i00 = h0 * 128 + w0, i01 = h0 * 128 + w1, i10 = h1 * 128 + w0, i11 = h1 * 128 + w1;
  float w00 = (1.f - th) * (1.f - tw), w01 = (1.f - th) * tw;
  float w10 = th * (1.f - tw), w11 = th * tw;
#pragma unroll
  for (int j = 0; j < 16; ++j) {
    int o = og * 16 + j;
    const float* gb = G + (size_t)(b * 64 + o) * HWC;
    s_lds[pt][o] = w00 * gb[i00] + w01 * gb[i01] + w10 * gb[i10] + w11 * gb[i11];
  }
  __syncthreads();

  int jg = og;
  float acc[32] = {};
  for (int o = 0; o < 64; ++o) {
    float sv = s_lds[pt][o];
    const float* prow = &p1_lds[o][jg * 32];
#pragma unroll
    for (int q = 0; q < 8; ++q) {
      float4 pv = *(const float4*)&prow[q * 4];
      acc[q * 4 + 0] = fmaf(sv, pv.x, acc[q * 4 + 0]);
      acc[q * 4 + 1] = fmaf(sv, pv.y, acc[q * 4 + 1]);
      acc[q * 4 + 2] = fmaf(sv, pv.z, acc[q * 4 + 2]);
      acc[q * 4 + 3] = fmaf(sv, pv.w, acc[q * 4 + 3]);
    }
  }
  float partial = 0.f;
#pragma unroll
  for (int jj = 0; jj < 32; ++jj) {
    int j = jg * 32 + jj;
    partial = fmaf(gelu_f(acc[jj] + p1b_lds[j]), p2_lds[j], partial);
  }
  red[jg][pt] = partial;
  __syncthreads();
  if (tid < 64)
    out[blockIdx.x * 64 + tid] = red[0][tid] + red[1][tid] + red[2][tid] + red[3][tid] + p2b[0];
}

extern "C" void kernel_launch(void* const* d_in, const int* in_sizes, int n_in,
                              void* d_out, int out_size, void* d_ws, size_t ws_size,
                              hipStream_t stream) {
  const float* coords = (const float*)d_in[0];
  const float* feats  = (const float*)d_in[1];
  const float* dw0 = (const float*)d_in[2];
  const float* db0 = (const float*)d_in[3];
  const float* dw1 = (const float*)d_in[4];
  const float* db1 = (const float*)d_in[5];
  const float* dw2 = (const float*)d_in[6];
  const float* db2 = (const float*)d_in[7];
  const float* liftw = (const float*)d_in[8];
  const float* liftb = (const float*)d_in[9];
  const float* sw1r = (const float*)d_in[10];
  const float* sw1i = (const float*)d_in[11];
  const float* sw2r = (const float*)d_in[12];
  const float* sw2i = (const float*)d_in[13];
  const float* pww = (const float*)d_in[14];
  const float* pwb = (const float*)d_in[15];
  const float* p1w = (const float*)d_in[16];
  const float* p1b = (const float*)d_in[17];
  const float* p2w = (const float*)d_in[18];
  const float* p2b = (const float*)d_in[19];
  float* out = (float*)d_out;
  float* ws = (float*)d_ws;

  float* sums  = ws;                    // 8,388,608 f  (aliased as y later)
  float* cnts  = sums + 8388608;        // 131,072 f
  float* G     = cnts + 131072;         // 8,388,608 f
  float* XTr   = G + 8388608;           // 1,572,864 f  (Xw / Tw, reused)
  float* XTi   = XTr + 1572864;
  float* Xfr   = XTi + 1572864;         // 589,824 f
  float* Xfi   = Xfr + 589824;
  float* Yfr   = Xfi + 589824;
  float* Yfi   = Yfr + 589824;
  float* stats = Yfi + 589824;          // 1,024 f
  float* pd_th = stats + 1024;          // 131,072 f
  float* pd_tw = pd_th + 131072;        // 131,072 f
  int*   pd_idx = (int*)(pd_tw + 131072); // 131,072 i
  float* y = sums;                      // alias: sums dead after k_gridnorm

  hipMemsetAsync(sums, 0, (size_t)(8388608 + 131072) * sizeof(float), stream);

  k_points<<<512, 256, 0, stream>>>(coords, feats, dw0, db0, dw1, db1, dw2, db2,
                                    liftw, liftb, sums, cnts, pd_idx, pd_th, pd_tw);
  k_gridnorm<<<dim3(128, 8), 256, 0, stream>>>(sums, cnts, G);

  for (int d = 0; d < 4; ++d) {
    const int swoff = d * 2359296;   // 64*64*24*24
    k_dft_w<<<512, 256, 0, stream>>>(G, XTr, XTi);
    k_dft_h<<<512, 192, 0, stream>>>(XTr, XTi, Xfr, Xfi);
    k_mix<<<dim3(9, 16, 4), 64, 0, stream>>>(Xfr, Xfi, sw1r + swoff, sw1i + swoff,
                                             sw2r + swoff, sw2i + swoff, Yfr, Yfi);
    k_idft_h<<<512, 256, 0, stream>>>(Yfr, Yfi, XTr, XTi);
    k_pw<<<dim3(128, 8), 256, 0, stream>>>(G, pww + d * 4096, pwb + d * 64, y);
    k_idft_w<<<512, 256, 0, stream>>>(XTr, XTi, y, stats);
    k_norm_gelu<<<8192, 256, 0, stream>>>(y, stats, G);
  }

  k_g2p<<<2048, 256, 0, stream>>>(G, pd_idx, pd_th, pd_tw, p1w, p1b, p2w, p2b, out);
}

// Round 2
// 853.835 us; speedup vs baseline: 1.4586x; 1.4586x over previous
//
#include <hip/hip_runtime.h>
#include <math.h>

#define GH 128
#define GW 128
#define HWC 16384
#define CW 64
#define NM 24
#define NKX 48
#define NMODE 1152
#define PI_F 3.14159265358979323846f

__device__ __forceinline__ float gelu_f(float x) {
  return 0.5f * x * (1.0f + erff(x * 0.70710678118654752f));
}

// ---------------- points: deform MLP + scatter raw inputs + bilinear data ----------------
__global__ __launch_bounds__(256) void k_points(
    const float* __restrict__ coords, const float* __restrict__ feats,
    const float* __restrict__ dw0, const float* __restrict__ db0,
    const float* __restrict__ dw1, const float* __restrict__ db1,
    const float* __restrict__ dw2, const float* __restrict__ db2,
    float* __restrict__ sums6,
    int* __restrict__ pd_idx, float* __restrict__ pd_th, float* __restrict__ pd_tw)
{
  __shared__ float s_dw0[64], s_db0[32], s_dw1[1024], s_db1[32], s_dw2[64], s_db2[2];
  int t = threadIdx.x;
  for (int i = t; i < 1024; i += 256) s_dw1[i] = dw1[i];
  if (t < 64) { s_dw0[t] = dw0[t]; s_dw2[t] = dw2[t]; }
  if (t < 32) { s_db0[t] = db0[t]; s_db1[t] = db1[t]; }
  if (t < 2)  { s_db2[t] = db2[t]; }
  __syncthreads();

  int pid = blockIdx.x * 256 + t;
  float2 c = ((const float2*)coords)[pid];
  float h1[32], h2[32];
#pragma unroll
  for (int j = 0; j < 32; ++j)
    h1[j] = gelu_f(fmaf(c.x, s_dw0[j], fmaf(c.y, s_dw0[32 + j], s_db0[j])));
#pragma unroll
  for (int j = 0; j < 32; ++j) {
    float a = s_db1[j];
#pragma unroll
    for (int k = 0; k < 32; ++k) a = fmaf(h1[k], s_dw1[k * 32 + j], a);
    h2[j] = gelu_f(a);
  }
  float d0 = s_db2[0], d1 = s_db2[1];
#pragma unroll
  for (int k = 0; k < 32; ++k) { d0 = fmaf(h2[k], s_dw2[2 * k], d0); d1 = fmaf(h2[k], s_dw2[2 * k + 1], d1); }
  float l0 = fminf(fmaxf(c.x + d0, -1.f), 1.f);
  float l1 = fminf(fmaxf(c.y + d1, -1.f), 1.f);
  float ph = (l0 + 1.f) * 0.5f * 127.f;
  float pw = (l1 + 1.f) * 0.5f * 127.f;
  int ih = min(max((int)rintf(ph), 0), 127);
  int iw = min(max((int)rintf(pw), 0), 127);
  int b = pid >> 14;
  int cell = b * HWC + ih * GW + iw;

  float f0 = feats[pid * 3], f1 = feats[pid * 3 + 1], f2 = feats[pid * 3 + 2];
  float* srow = sums6 + (size_t)cell * 6;
  atomicAdd(srow + 0, f0);
  atomicAdd(srow + 1, f1);
  atomicAdd(srow + 2, f2);
  atomicAdd(srow + 3, c.x);
  atomicAdd(srow + 4, c.y);
  atomicAdd(srow + 5, 1.f);

  float fh = floorf(ph), fw = floorf(pw);
  int h0i = min(max((int)fh, 0), 127), w0i = min(max((int)fw, 0), 127);
  pd_idx[pid] = h0i | (w0i << 8);
  pd_th[pid] = ph - fh;
  pd_tw[pid] = pw - fw;
}

// ---------------- scatter-mean normalize + lift: sums6(B,HW,6) -> G(B,C,HW) ----------------
__global__ __launch_bounds__(256) void k_gridlift(const float* __restrict__ sums6,
                                                  const float* __restrict__ lw,
                                                  const float* __restrict__ lb,
                                                  float* __restrict__ G)
{
  __shared__ float s6[128][6];
  __shared__ float s_lw[5][64];
  __shared__ float s_lb[64];
  int b = blockIdx.y, cbase = blockIdx.x * 128, tid = threadIdx.x;
  for (int l = tid; l < 768; l += 256) ((float*)s6)[l] = sums6[(size_t)(b * HWC + cbase) * 6 + l];
  for (int l = tid; l < 320; l += 256) ((float*)s_lw)[l] = lw[l];
  if (tid < 64) s_lb[tid] = lb[tid];
  __syncthreads();
  int cl = tid & 127, oh = tid >> 7;
  float v0 = s6[cl][0], v1 = s6[cl][1], v2 = s6[cl][2], v3 = s6[cl][3], v4 = s6[cl][4];
  float cnt = s6[cl][5];
  float inv = 1.f / fmaxf(cnt, 1.f);
#pragma unroll
  for (int j = 0; j < 32; ++j) {
    int o = oh * 32 + j;
    float val = cnt * s_lb[o];
    val = fmaf(v0, s_lw[0][o], val);
    val = fmaf(v1, s_lw[1][o], val);
    val = fmaf(v2, s_lw[2][o], val);
    val = fmaf(v3, s_lw[3][o], val);
    val = fmaf(v4, s_lw[4][o], val);
    G[(size_t)(b * 64 + o) * HWC + cbase + cl] = val * inv;
  }
}

// ---------------- forward DFT along w: G(B,C,H,W) -> Xw(B,C,24,H) complex ----------------
__global__ __launch_bounds__(256) void k_dft_w(const float* __restrict__ G,
                                               float* __restrict__ Xwr, float* __restrict__ Xwi)
{
  __shared__ float img[64][133];
  int bc = blockIdx.x;
  int tid = threadIdx.x;
  int hq = tid >> 3, kg = tid & 7;
  float stc[3], sts[3];
#pragma unroll
  for (int tt = 0; tt < 3; ++tt) {
    float s, c2;
    sincosf((float)(kg * 3 + tt) * (PI_F / 64.f), &s, &c2);
    sts[tt] = s; stc[tt] = c2;
  }
  for (int half = 0; half < 2; ++half) {
    for (int l = tid; l < 8192; l += 256) {
      int hl = l >> 7, w = l & 127;
      img[hl][w] = G[(size_t)bc * HWC + (half * 64 + hl) * 128 + w];
    }
    __syncthreads();
    float aR0[3] = {0,0,0}, aI0[3] = {0,0,0}, aR1[3] = {0,0,0}, aI1[3] = {0,0,0};
    float pR[3] = {1.f,1.f,1.f}, pI[3] = {0.f,0.f,0.f};
    int h0 = hq * 2;
    for (int w = 0; w < 128; ++w) {
      float x0 = img[h0][w], x1 = img[h0 + 1][w];
#pragma unroll
      for (int tt = 0; tt < 3; ++tt) {
        aR0[tt] = fmaf(x0, pR[tt], aR0[tt]);
        aI0[tt] = fmaf(x0, pI[tt], aI0[tt]);
        aR1[tt] = fmaf(x1, pR[tt], aR1[tt]);
        aI1[tt] = fmaf(x1, pI[tt], aI1[tt]);
        float nr = fmaf(pR[tt], stc[tt], pI[tt] * sts[tt]);
        pI[tt] = fmaf(pI[tt], stc[tt], -pR[tt] * sts[tt]);
        pR[tt] = nr;
      }
    }
    int hg = half * 64 + h0;
#pragma unroll
    for (int tt = 0; tt < 3; ++tt) {
      int ky = kg * 3 + tt;
      int o = (bc * 24 + ky) * 128 + hg;
      Xwr[o] = aR0[tt]; Xwr[o + 1] = aR1[tt];
      Xwi[o] = aI0[tt]; Xwi[o + 1] = aI1[tt];
    }
    __syncthreads();
  }
}

// ---------------- forward DFT along h: Xw(B,C,24,H) -> Xf(B,C,1152) complex ----------------
__global__ __launch_bounds__(192) void k_dft_h(const float* __restrict__ Xwr, const float* __restrict__ Xwi,
                                               float* __restrict__ Xfr, float* __restrict__ Xfi)
{
  __shared__ float2 xw[24][130];
  int bc = blockIdx.x;
  int tid = threadIdx.x;
  for (int l = tid; l < 3072; l += 192) {
    int ky = l >> 7, h = l & 127;
    int o = (bc * 24 + ky) * 128 + h;
    xw[ky][h] = make_float2(Xwr[o], Xwi[o]);
  }
  __syncthreads();
  int kxi = tid >> 2, kg = tid & 3;
  int kxe = kxi < 24 ? kxi : kxi + 80;
  float sn, cn;
  sincosf((float)kxe * (PI_F / 64.f), &sn, &cn);
  float aR[6] = {0,0,0,0,0,0}, aI[6] = {0,0,0,0,0,0};
  float pR = 1.f, pI = 0.f;
  for (int h = 0; h < 128; ++h) {
#pragma unroll
    for (int tt = 0; tt < 6; ++tt) {
      float2 v = xw[kg * 6 + tt][h];
      aR[tt] = fmaf(v.x, pR, aR[tt]); aR[tt] = fmaf(-v.y, pI, aR[tt]);
      aI[tt] = fmaf(v.x, pI, aI[tt]); aI[tt] = fmaf(v.y, pR, aI[tt]);
    }
    float nr = fmaf(pR, cn, pI * sn);
    pI = fmaf(pI, cn, -pR * sn);
    pR = nr;
  }
#pragma unroll
  for (int tt = 0; tt < 6; ++tt) {
    int m = kxi * 24 + kg * 6 + tt;
    Xfr[bc * NMODE + m] = aR[tt];
    Xfi[bc * NMODE + m] = aI[tt];
  }
}

// ---------------- per-mode 64x64 complex channel mix: thread=(o,m), all 8 batches ----------------
__global__ __launch_bounds__(256) void k_mix(const float* __restrict__ Xfr, const float* __restrict__ Xfi,
    const float* __restrict__ w1r, const float* __restrict__ w1i,
    const float* __restrict__ w2r, const float* __restrict__ w2i,
    float* __restrict__ Yfr, float* __restrict__ Yfi)
{
  int m = blockIdx.x * 64 + (threadIdx.x & 63);   // 0..575 within half
  int o = blockIdx.y * 4 + (threadIdx.x >> 6);    // 0..63
  int half = blockIdx.z;
  int gm = half * 576 + m;
  const float* wr_ = half ? w2r : w1r;
  const float* wi_ = half ? w2i : w1i;
  float aR[8] = {}, aI[8] = {};
  for (int i = 0; i < 64; ++i) {
    int widx = (i * 64 + o) * 576 + m;
    float wr = wr_[widx], wi = wi_[widx];
#pragma unroll
    for (int b = 0; b < 8; ++b) {
      int xb = (b * 64 + i) * NMODE + gm;
      float xr = Xfr[xb], xi = Xfi[xb];
      aR[b] = fmaf(xr, wr, aR[b]); aR[b] = fmaf(-xi, wi, aR[b]);
      aI[b] = fmaf(xr, wi, aI[b]); aI[b] = fmaf(xi, wr, aI[b]);
    }
  }
#pragma unroll
  for (int b = 0; b < 8; ++b) {
    int yi = (b * 64 + o) * NMODE + gm;
    Yfr[yi] = aR[b]; Yfi[yi] = aI[b];
  }
}

// ---------------- inverse DFT along kx: Yf(B,C,1152) -> Tw(B,C,24,H) complex ----------------
__global__ __launch_bounds__(256) void k_idft_h(const float* __restrict__ Yfr, const float* __restrict__ Yfi,
                                                float* __restrict__ Twr, float* __restrict__ Twi)
{
  __shared__ float2 yf[48][24];
  int bc = blockIdx.x;
  int tid = threadIdx.x;
  for (int l = tid; l < 1152; l += 256) {
    int kxi = l / 24, ky = l - kxi * 24;
    yf[kxi][ky] = make_float2(Yfr[bc * NMODE + l], Yfi[bc * NMODE + l]);
  }
  __syncthreads();
  int h = tid & 127, kyb = (tid >> 7) * 12;
  float aR[12] = {}, aI[12] = {};
  float sc, cc;
  sincosf((float)h * (PI_F / 64.f), &sc, &cc);
  float pR = 1.f, pI = 0.f;
  for (int run = 0; run < 2; ++run) {
    if (run == 1) {
      int k0 = (104 * h) & 127;
      sincosf((float)k0 * (PI_F / 64.f), &pI, &pR);
    }
    int kxs = run * 24;
    for (int kk = 0; kk < 24; ++kk) {
      int kxi = kxs + kk;
#pragma unroll
      for (int q = 0; q < 12; ++q) {
        float2 v = yf[kxi][kyb + q];
        aR[q] = fmaf(v.x, pR, aR[q]); aR[q] = fmaf(-v.y, pI, aR[q]);
        aI[q] = fmaf(v.x, pI, aI[q]); aI[q] = fmaf(v.y, pR, aI[q]);
      }
      float nr = fmaf(pR, cc, -pI * sc);
      pI = fmaf(pI, cc, pR * sc);
      pR = nr;
    }
  }
#pragma unroll
  for (int q = 0; q < 12; ++q) {
    int o = (bc * 24 + kyb + q) * 128 + h;
    Twr[o] = aR[q]; Twi[o] = aI[q];
  }
}

// ---------------- pointwise conv: y = G @ pw + bias ----------------
__global__ __launch_bounds__(256) void k_pw(const float* __restrict__ G, const float* __restrict__ pww,
                                            const float* __restrict__ pwb, float* __restrict__ y)
{
  __shared__ float g_lds[64][132];
  __shared__ float pw_lds[64][64];
  int b = blockIdx.y;
  int pbase = blockIdx.x * 128;
  int tid = threadIdx.x;
  for (int l = tid; l < 8192; l += 256) {
    int i = l >> 7, p = l & 127;
    g_lds[i][p] = G[(size_t)(b * 64 + i) * HWC + pbase + p];
  }
  for (int l = tid; l < 4096; l += 256) pw_lds[l >> 6][l & 63] = pww[l];
  __syncthreads();
  int og = tid >> 5, pg = tid & 31;
  int o0 = og * 8, px0 = pg * 4;
  float acc[8][4] = {};
  for (int i = 0; i < 64; ++i) {
    float4 xv = *(const float4*)&g_lds[i][px0];
    float4 wa = *(const float4*)&pw_lds[i][o0];
    float4 wb = *(const float4*)&pw_lds[i][o0 + 4];
    float xs[4] = {xv.x, xv.y, xv.z, xv.w};
    float wv[8] = {wa.x, wa.y, wa.z, wa.w, wb.x, wb.y, wb.z, wb.w};
#pragma unroll
    for (int oo = 0; oo < 8; ++oo)
#pragma unroll
      for (int j = 0; j < 4; ++j) acc[oo][j] = fmaf(xs[j], wv[oo], acc[oo][j]);
  }
#pragma unroll
  for (int oo = 0; oo < 8; ++oo) {
    float bias = pwb[o0 + oo];
    float4 v = make_float4(acc[oo][0] + bias, acc[oo][1] + bias, acc[oo][2] + bias, acc[oo][3] + bias);
    *(float4*)&y[(size_t)(b * 64 + o0 + oo) * HWC + pbase + px0] = v;
  }
}

// ---------------- inverse DFT along ky + add + instnorm + gelu (fused) ----------------
__global__ __launch_bounds__(256) void k_idft_w(const float* __restrict__ Twr, const float* __restrict__ Twi,
                                                const float* __restrict__ y, float* __restrict__ G)
{
  __shared__ float2 t_lds[128][26];
  __shared__ float2 cs[24][132];
  __shared__ float rs[256], rq[256];
  __shared__ float s_mu, s_rstd;
  int bc = blockIdx.x;
  int tid = threadIdx.x;
  for (int l = tid; l < 3072; l += 256) {
    int ky = l >> 7, x = l & 127;
    int o = (bc * 24 + ky) * 128 + x;
    t_lds[x][ky] = make_float2(Twr[o], Twi[o]);
    int k = (ky * x) & 127;
    float s, c2; sincosf((float)k * (PI_F / 64.f), &s, &c2);
    cs[ky][x] = make_float2(c2, s);
  }
  __syncthreads();
  int w = tid & 127, hh = tid >> 7;
  float csr[23], csi[23];
#pragma unroll
  for (int ky = 1; ky < 24; ++ky) { float2 cc = cs[ky][w]; csr[ky - 1] = cc.x; csi[ky - 1] = cc.y; }
  float vst[64];
  float sum = 0.f, ssq = 0.f;
#pragma unroll
  for (int j = 0; j < 64; ++j) {
    int h = hh * 64 + j;
    float t0 = t_lds[h][0].x;
    float s2 = 0.f;
#pragma unroll
    for (int ky = 1; ky < 24; ++ky) {
      float2 tv = t_lds[h][ky];
      s2 = fmaf(tv.x, csr[ky - 1], s2);
      s2 = fmaf(-tv.y, csi[ky - 1], s2);
    }
    float v = y[bc * HWC + h * 128 + w] + (t0 + 2.f * s2) * (1.f / 16384.f);
    vst[j] = v;
    sum += v; ssq = fmaf(v, v, ssq);
  }
  rs[tid] = sum; rq[tid] = ssq;
  __syncthreads();
  for (int sft = 128; sft > 0; sft >>= 1) {
    if (tid < sft) { rs[tid] += rs[tid + sft]; rq[tid] += rq[tid + sft]; }
    __syncthreads();
  }
  if (tid == 0) {
    float mu = rs[0] * (1.f / 16384.f);
    float var = fmaxf(rq[0] * (1.f / 16384.f) - mu * mu, 0.f);
    s_mu = mu;
    s_rstd = rsqrtf(var + 1e-5f);
  }
  __syncthreads();
  float mu = s_mu, rstd = s_rstd;
#pragma unroll
  for (int j = 0; j < 64; ++j) {
    int h = hh * 64 + j;
    G[bc * HWC + h * 128 + w] = gelu_f((vst[j] - mu) * rstd);
  }
}

// ---------------- G2P bilinear gather + projection MLP ----------------
__global__ __launch_bounds__(256) void k_g2p(const float* __restrict__ G,
    const int* __restrict__ pd_idx, const float* __restrict__ pd_th, const float* __restrict__ pd_tw,
    const float* __restrict__ p1w, const float* __restrict__ p1b,
    const float* __restrict__ p2w, const float* __restrict__ p2b,
    float* __restrict__ out)
{
  __shared__ float s_lds[64][65];
  __shared__ float p1_lds[64][128];
  __shared__ float p1b_lds[128];
  __shared__ float p2_lds[128];
  __shared__ float red[4][64];
  int tid = threadIdx.x;
  for (int l = tid; l < 8192; l += 256) ((float*)p1_lds)[l] = p1w[l];
  if (tid < 128) { p1b_lds[tid] = p1b[tid]; p2_lds[tid] = p2w[tid]; }

  int pt = tid & 63, og = tid >> 6;
  int pid = blockIdx.x * 64 + pt;
  int b = pid >> 14;
  int packed = pd_idx[pid];
  float th = pd_th[pid], tw = pd_tw[pid];
  int h0 = packed & 255, w0 = (packed >> 8) & 255;
  int h1 = min(h0 + 1, 127), w1 = min(w0 + 1, 127);
  int i00 = h0 * 128 + w0, i01 = h0 * 128 + w1, i10 = h1 * 128 + w0, i11 = h1 * 128 + w1;
  float w00 = (1.f - th) * (1.f - tw), w01 = (1.f - th) * tw;
  float w10 = th * (1.f - tw), w11 = th * tw;
#pragma unroll
  for (int j = 0; j < 16; ++j) {
    int o = og * 16 + j;
    const float* gb = G + (size_t)(b * 64 + o) * HWC;
    s_lds[pt][o] = w00 * gb[i00] + w01 * gb[i01] + w10 * gb[i10] + w11 * gb[i11];
  }
  __syncthreads();

  int jg = og;
  float acc[32] = {};
  for (int o = 0; o < 64; ++o) {
    float sv = s_lds[pt][o];
    const float* prow = &p1_lds[o][jg * 32];
#pragma unroll
    for (int q = 0; q < 8; ++q) {
      float4 pv = *(const float4*)&prow[q * 4];
      acc[q * 4 + 0] = fmaf(sv, pv.x, acc[q * 4 + 0]);
      acc[q * 4 + 1] = fmaf(sv, pv.y, acc[q * 4 + 1]);
      acc[q * 4 + 2] = fmaf(sv, pv.z, acc[q * 4 + 2]);
      acc[q * 4 + 3] = fmaf(sv, pv.w, acc[q * 4 + 3]);
    }
  }
  float partial = 0.f;
#pragma unroll
  for (int jj = 0; jj < 32; ++jj) {
    int j = jg * 32 + jj;
    partial = fmaf(gelu_f(acc[jj] + p1b_lds[j]), p2_lds[j], partial);
  }
  red[jg][pt] = partial;
  __syncthreads();
  if (tid < 64)
    out[blockIdx.x * 64 + tid] = red[0][tid] + red[1][tid] + red[2][tid] + red[3][tid] + p2b[0];
}

extern "C" void kernel_launch(void* const* d_in, const int* in_sizes, int n_in,
                              void* d_out, int out_size, void* d_ws, size_t ws_size,
                              hipStream_t stream) {
  const float* coords = (const float*)d_in[0];
  const float* feats  = (const float*)d_in[1];
  const float* dw0 = (const float*)d_in[2];
  const float* db0 = (const float*)d_in[3];
  const float* dw1 = (const float*)d_in[4];
  const float* db1 = (const float*)d_in[5];
  const float* dw2 = (const float*)d_in[6];
  const float* db2 = (const float*)d_in[7];
  const float* liftw = (const float*)d_in[8];
  const float* liftb = (const float*)d_in[9];
  const float* sw1r = (const float*)d_in[10];
  const float* sw1i = (const float*)d_in[11];
  const float* sw2r = (const float*)d_in[12];
  const float* sw2i = (const float*)d_in[13];
  const float* pww = (const float*)d_in[14];
  const float* pwb = (const float*)d_in[15];
  const float* p1w = (const float*)d_in[16];
  const float* p1b = (const float*)d_in[17];
  const float* p2w = (const float*)d_in[18];
  const float* p2b = (const float*)d_in[19];
  float* out = (float*)d_out;
  float* ws = (float*)d_ws;

  // region A (8.4M floats): sums6 (786K, dead after gridlift) then y (pw output)
  float* sums6 = ws;
  float* y     = ws;
  float* G     = ws + 8388608;
  float* XTr   = G + 8388608;           // Xw / Tw (reused)
  float* XTi   = XTr + 1572864;
  float* Xfr   = XTi + 1572864;
  float* Xfi   = Xfr + 589824;
  float* Yfr   = Xfi + 589824;
  float* Yfi   = Yfr + 589824;
  float* pd_th = Yfi + 589824;
  float* pd_tw = pd_th + 131072;
  int*   pd_idx = (int*)(pd_tw + 131072);

  hipMemsetAsync(sums6, 0, (size_t)786432 * sizeof(float), stream);

  k_points<<<512, 256, 0, stream>>>(coords, feats, dw0, db0, dw1, db1, dw2, db2,
                                    sums6, pd_idx, pd_th, pd_tw);
  k_gridlift<<<dim3(128, 8), 256, 0, stream>>>(sums6, liftw, liftb, G);

  for (int d = 0; d < 4; ++d) {
    const int swoff = d * 2359296;   // 64*64*24*24
    k_dft_w<<<512, 256, 0, stream>>>(G, XTr, XTi);
    k_dft_h<<<512, 192, 0, stream>>>(XTr, XTi, Xfr, Xfi);
    k_mix<<<dim3(9, 16, 2), 256, 0, stream>>>(Xfr, Xfi, sw1r + swoff, sw1i + swoff,
                                              sw2r + swoff, sw2i + swoff, Yfr, Yfi);
    k_idft_h<<<512, 256, 0, stream>>>(Yfr, Yfi, XTr, XTi);
    k_pw<<<dim3(128, 8), 256, 0, stream>>>(G, pww + d * 4096, pwb + d * 64, y);
    k_idft_w<<<512, 256, 0, stream>>>(XTr, XTi, y, G);
  }

  k_g2p<<<2048, 256, 0, stream>>>(G, pd_idx, pd_th, pd_tw, p1w, p1b, p2w, p2b, out);
}

// Round 3
// 755.177 us; speedup vs baseline: 1.6492x; 1.1306x over previous
//
#include <hip/hip_runtime.h>
#include <math.h>

#define GH 128
#define GW 128
#define HWC 16384
#define NMODE 1152
#define PI_F 3.14159265358979323846f

__device__ __forceinline__ float gelu_f(float x) {
  return 0.5f * x * (1.0f + erff(x * 0.70710678118654752f));
}

// ---------------- points: deform MLP + scatter raw inputs + rank + bilinear data ----------------
__global__ __launch_bounds__(256) void k_points(
    const float* __restrict__ coords, const float* __restrict__ feats,
    const float* __restrict__ dw0, const float* __restrict__ db0,
    const float* __restrict__ dw1, const float* __restrict__ db1,
    const float* __restrict__ dw2, const float* __restrict__ db2,
    float* __restrict__ sums5, int* __restrict__ cnt_i,
    int* __restrict__ ptrank, int* __restrict__ pd_cell,
    int* __restrict__ pd_idx, float* __restrict__ pd_th, float* __restrict__ pd_tw)
{
  __shared__ float s_dw0[64], s_db0[32], s_dw1[1024], s_db1[32], s_dw2[64], s_db2[2];
  int t = threadIdx.x;
  for (int i = t; i < 1024; i += 256) s_dw1[i] = dw1[i];
  if (t < 64) { s_dw0[t] = dw0[t]; s_dw2[t] = dw2[t]; }
  if (t < 32) { s_db0[t] = db0[t]; s_db1[t] = db1[t]; }
  if (t < 2)  { s_db2[t] = db2[t]; }
  __syncthreads();

  int pid = blockIdx.x * 256 + t;
  float2 c = ((const float2*)coords)[pid];
  float h1[32], h2[32];
#pragma unroll
  for (int j = 0; j < 32; ++j)
    h1[j] = gelu_f(fmaf(c.x, s_dw0[j], fmaf(c.y, s_dw0[32 + j], s_db0[j])));
#pragma unroll
  for (int j = 0; j < 32; ++j) {
    float a = s_db1[j];
#pragma unroll
    for (int k = 0; k < 32; ++k) a = fmaf(h1[k], s_dw1[k * 32 + j], a);
    h2[j] = gelu_f(a);
  }
  float d0 = s_db2[0], d1 = s_db2[1];
#pragma unroll
  for (int k = 0; k < 32; ++k) { d0 = fmaf(h2[k], s_dw2[2 * k], d0); d1 = fmaf(h2[k], s_dw2[2 * k + 1], d1); }
  float l0 = fminf(fmaxf(c.x + d0, -1.f), 1.f);
  float l1 = fminf(fmaxf(c.y + d1, -1.f), 1.f);
  float ph = (l0 + 1.f) * 0.5f * 127.f;
  float pw = (l1 + 1.f) * 0.5f * 127.f;
  int ih = min(max((int)rintf(ph), 0), 127);
  int iw = min(max((int)rintf(pw), 0), 127);
  int b = pid >> 14;
  int cell = b * HWC + ih * GW + iw;

  float f0 = feats[pid * 3], f1 = feats[pid * 3 + 1], f2 = feats[pid * 3 + 2];
  float* srow = sums5 + (size_t)cell * 5;
  atomicAdd(srow + 0, f0);
  atomicAdd(srow + 1, f1);
  atomicAdd(srow + 2, f2);
  atomicAdd(srow + 3, c.x);
  atomicAdd(srow + 4, c.y);
  int r = atomicAdd(&cnt_i[cell], 1);
  ptrank[pid] = r;
  pd_cell[pid] = cell;

  float fh = floorf(ph), fw = floorf(pw);
  int h0i = min(max((int)fh, 0), 127), w0i = min(max((int)fw, 0), 127);
  pd_idx[pid] = h0i | (w0i << 8);
  pd_th[pid] = ph - fh;
  pd_tw[pid] = pw - fw;
}

// ---------------- scan A: per-512-cell block exclusive scan ----------------
__global__ __launch_bounds__(256) void k_scanA(const int* __restrict__ cnt,
                                               int* __restrict__ starts, int* __restrict__ btot)
{
  __shared__ int sh[256];
  int blk = blockIdx.x, t = threadIdx.x;
  int base = blk * 512;
  int v0 = cnt[base + 2 * t], v1 = cnt[base + 2 * t + 1];
  int pair = v0 + v1;
  sh[t] = pair; __syncthreads();
  int acc = pair;
  for (int off = 1; off < 256; off <<= 1) {
    int add = (t >= off) ? sh[t - off] : 0;
    __syncthreads();
    acc += add; sh[t] = acc;
    __syncthreads();
  }
  int excl = acc - pair;
  starts[base + 2 * t] = excl;
  starts[base + 2 * t + 1] = excl + v0;
  if (t == 255) btot[blk] = acc;
}

// ---------------- scan B: exclusive scan of 256 block totals ----------------
__global__ __launch_bounds__(256) void k_scanB(const int* __restrict__ btot, int* __restrict__ boff)
{
  __shared__ int sh[256];
  int t = threadIdx.x;
  int v = btot[t];
  sh[t] = v; __syncthreads();
  int acc = v;
  for (int off = 1; off < 256; off <<= 1) {
    int add = (t >= off) ? sh[t - off] : 0;
    __syncthreads();
    acc += add; sh[t] = acc;
    __syncthreads();
  }
  boff[t] = acc - v;
}

// ---------------- permute: sorted point records ----------------
__global__ __launch_bounds__(256) void k_perm(const int* __restrict__ pd_cell, const int* __restrict__ ptrank,
                                              const int* __restrict__ starts, const int* __restrict__ boff,
                                              const int* __restrict__ pd_idx, const float* __restrict__ pd_th,
                                              const float* __restrict__ pd_tw, int4* __restrict__ pds)
{
  int pid = blockIdx.x * 256 + threadIdx.x;
  int cell = pd_cell[pid];
  int dst = starts[cell] + boff[cell >> 9] + ptrank[pid];
  int4 rec;
  rec.x = pid;
  rec.y = pd_idx[pid];
  rec.z = __float_as_int(pd_th[pid]);
  rec.w = __float_as_int(pd_tw[pid]);
  pds[dst] = rec;
}

// ---------------- scatter-mean normalize + lift: sums5(B,HW,5) -> G(B,C,HW) ----------------
__global__ __launch_bounds__(256) void k_gridlift(const float* __restrict__ sums5,
                                                  const int* __restrict__ cnt_i,
                                                  const float* __restrict__ lw,
                                                  const float* __restrict__ lb,
                                                  float* __restrict__ G)
{
  __shared__ float s5[128][5];
  __shared__ float s_lw[5][64];
  __shared__ float s_lb[64];
  int b = blockIdx.y, cbase = blockIdx.x * 128, tid = threadIdx.x;
  for (int l = tid; l < 640; l += 256) ((float*)s5)[l] = sums5[(size_t)(b * HWC + cbase) * 5 + l];
  for (int l = tid; l < 320; l += 256) ((float*)s_lw)[l] = lw[l];
  if (tid < 64) s_lb[tid] = lb[tid];
  __syncthreads();
  int cl = tid & 127, oh = tid >> 7;
  float v0 = s5[cl][0], v1 = s5[cl][1], v2 = s5[cl][2], v3 = s5[cl][3], v4 = s5[cl][4];
  float cnt = (float)cnt_i[b * HWC + cbase + cl];
  float inv = 1.f / fmaxf(cnt, 1.f);
#pragma unroll
  for (int j = 0; j < 32; ++j) {
    int o = oh * 32 + j;
    float val = cnt * s_lb[o];
    val = fmaf(v0, s_lw[0][o], val);
    val = fmaf(v1, s_lw[1][o], val);
    val = fmaf(v2, s_lw[2][o], val);
    val = fmaf(v3, s_lw[3][o], val);
    val = fmaf(v4, s_lw[4][o], val);
    G[(size_t)(b * 64 + o) * HWC + cbase + cl] = val * inv;
  }
}

// ---------------- fused forward DFT: G(bc,H,W) -> Xf2(bc,1152) complex ----------------
__global__ __launch_bounds__(256) void k_fwd_dft(const float* __restrict__ G, float2* __restrict__ Xf2)
{
  __shared__ float img[64][132];
  __shared__ float2 xwl[24][130];
  int bc = blockIdx.x;
  int tid = threadIdx.x;
  int hq = tid >> 3, kg = tid & 7;
  float stc[3], sts[3];
#pragma unroll
  for (int tt = 0; tt < 3; ++tt) {
    float s, c2;
    sincosf((float)(kg * 3 + tt) * (PI_F / 64.f), &s, &c2);
    sts[tt] = s; stc[tt] = c2;
  }
  // phase 1: W-DFT into LDS (24 ky x 128 h)
  for (int half = 0; half < 2; ++half) {
    __syncthreads();
    for (int l = tid; l < 8192; l += 256) {
      int hl = l >> 7, w = l & 127;
      img[hl][w] = G[(size_t)bc * HWC + (half * 64 + hl) * 128 + w];
    }
    __syncthreads();
    float aR0[3] = {0,0,0}, aI0[3] = {0,0,0}, aR1[3] = {0,0,0}, aI1[3] = {0,0,0};
    float pR[3] = {1.f,1.f,1.f}, pI[3] = {0.f,0.f,0.f};
    int h0 = hq * 2;
    for (int w = 0; w < 128; ++w) {
      float x0 = img[h0][w], x1 = img[h0 + 1][w];
#pragma unroll
      for (int tt = 0; tt < 3; ++tt) {
        aR0[tt] = fmaf(x0, pR[tt], aR0[tt]);
        aI0[tt] = fmaf(x0, pI[tt], aI0[tt]);
        aR1[tt] = fmaf(x1, pR[tt], aR1[tt]);
        aI1[tt] = fmaf(x1, pI[tt], aI1[tt]);
        float nr = fmaf(pR[tt], stc[tt], pI[tt] * sts[tt]);
        pI[tt] = fmaf(pI[tt], stc[tt], -pR[tt] * sts[tt]);
        pR[tt] = nr;
      }
    }
    int hg = half * 64 + h0;
#pragma unroll
    for (int tt = 0; tt < 3; ++tt) {
      int ky = kg * 3 + tt;
      xwl[ky][hg]     = make_float2(aR0[tt], aI0[tt]);
      xwl[ky][hg + 1] = make_float2(aR1[tt], aI1[tt]);
    }
  }
  __syncthreads();
  // phase 2: H-DFT (48 kx x 24 ky), 192 active threads
  if (tid < 192) {
    int kxi = tid >> 2, kg2 = tid & 3;
    int kxe = kxi < 24 ? kxi : kxi + 80;
    float sn, cn;
    sincosf((float)kxe * (PI_F / 64.f), &sn, &cn);
    float aR[6] = {0,0,0,0,0,0}, aI[6] = {0,0,0,0,0,0};
    float pR = 1.f, pI = 0.f;
    for (int h = 0; h < 128; ++h) {
#pragma unroll
      for (int tt = 0; tt < 6; ++tt) {
        float2 v = xwl[kg2 * 6 + tt][h];
        aR[tt] = fmaf(v.x, pR, aR[tt]); aR[tt] = fmaf(-v.y, pI, aR[tt]);
        aI[tt] = fmaf(v.x, pI, aI[tt]); aI[tt] = fmaf(v.y, pR, aI[tt]);
      }
      float nr = fmaf(pR, cn, pI * sn);
      pI = fmaf(pI, cn, -pR * sn);
      pR = nr;
    }
#pragma unroll
    for (int tt = 0; tt < 6; ++tt) {
      int m = kxi * 24 + kg2 * 6 + tt;
      Xf2[bc * NMODE + m] = make_float2(aR[tt], aI[tt]);
    }
  }
}

// ---------------- per-mode 64x64 complex channel mix ----------------
__global__ __launch_bounds__(256) void k_mix(const float2* __restrict__ Xf2,
    const float* __restrict__ w1r, const float* __restrict__ w1i,
    const float* __restrict__ w2r, const float* __restrict__ w2i,
    float2* __restrict__ Yf2)
{
  int m = blockIdx.x * 64 + (threadIdx.x & 63);
  int o = blockIdx.y * 4 + (threadIdx.x >> 6);
  int half = blockIdx.z;
  int gm = half * 576 + m;
  const float* wr_ = half ? w2r : w1r;
  const float* wi_ = half ? w2i : w1i;
  float aR[8] = {}, aI[8] = {};
#pragma unroll 2
  for (int i = 0; i < 64; ++i) {
    int widx = (i * 64 + o) * 576 + m;
    float wr = wr_[widx], wi = wi_[widx];
#pragma unroll
    for (int b = 0; b < 8; ++b) {
      float2 x = Xf2[(b * 64 + i) * NMODE + gm];
      aR[b] = fmaf(x.x, wr, aR[b]); aR[b] = fmaf(-x.y, wi, aR[b]);
      aI[b] = fmaf(x.x, wi, aI[b]); aI[b] = fmaf(x.y, wr, aI[b]);
    }
  }
#pragma unroll
  for (int b = 0; b < 8; ++b)
    Yf2[(b * 64 + o) * NMODE + gm] = make_float2(aR[b], aI[b]);
}

// ---------------- pointwise conv: y = G @ pw + bias ----------------
__global__ __launch_bounds__(256) void k_pw(const float* __restrict__ G, const float* __restrict__ pww,
                                            const float* __restrict__ pwb, float* __restrict__ y)
{
  __shared__ float g_lds[64][132];
  __shared__ float pw_lds[64][64];
  int b = blockIdx.y;
  int pbase = blockIdx.x * 128;
  int tid = threadIdx.x;
  for (int l = tid; l < 8192; l += 256) {
    int i = l >> 7, p = l & 127;
    g_lds[i][p] = G[(size_t)(b * 64 + i) * HWC + pbase + p];
  }
  for (int l = tid; l < 4096; l += 256) pw_lds[l >> 6][l & 63] = pww[l];
  __syncthreads();
  int og = tid >> 5, pg = tid & 31;
  int o0 = og * 8, px0 = pg * 4;
  float acc[8][4] = {};
  for (int i = 0; i < 64; ++i) {
    float4 xv = *(const float4*)&g_lds[i][px0];
    float4 wa = *(const float4*)&pw_lds[i][o0];
    float4 wb = *(const float4*)&pw_lds[i][o0 + 4];
    float xs[4] = {xv.x, xv.y, xv.z, xv.w};
    float wv[8] = {wa.x, wa.y, wa.z, wa.w, wb.x, wb.y, wb.z, wb.w};
#pragma unroll
    for (int oo = 0; oo < 8; ++oo)
#pragma unroll
      for (int j = 0; j < 4; ++j) acc[oo][j] = fmaf(xs[j], wv[oo], acc[oo][j]);
  }
#pragma unroll
  for (int oo = 0; oo < 8; ++oo) {
    float bias = pwb[o0 + oo];
    float4 v = make_float4(acc[oo][0] + bias, acc[oo][1] + bias, acc[oo][2] + bias, acc[oo][3] + bias);
    *(float4*)&y[(size_t)(b * 64 + o0 + oo) * HWC + pbase + px0] = v;
  }
}

// ---------------- fused inverse DFT + add + instnorm + gelu: Yf2 -> G ----------------
__global__ __launch_bounds__(256) void k_inv_dft(const float2* __restrict__ Yf2,
                                                 const float* __restrict__ y, float* __restrict__ G)
{
  __shared__ float2 yf[48][24];
  __shared__ float2 t_lds[128][26];
  __shared__ float2 base[128];
  __shared__ float rs[256], rq[256];
  __shared__ float s_mu, s_rstd;
  int bc = blockIdx.x;
  int tid = threadIdx.x;
  for (int l = tid; l < 1152; l += 256) {
    int kxi = l / 24, ky = l - kxi * 24;
    yf[kxi][ky] = Yf2[bc * NMODE + l];
  }
  if (tid < 128) {
    float s, c2; sincosf((float)tid * (PI_F / 64.f), &s, &c2);
    base[tid] = make_float2(c2, s);
  }
  __syncthreads();
  // phase 1: inverse H-DFT -> t_lds[h][ky]
  {
    int h = tid & 127, kyb = (tid >> 7) * 12;
    float aR[12] = {}, aI[12] = {};
    float sc, cc;
    float2 bb = base[h]; cc = bb.x; sc = bb.y;
    float pR = 1.f, pI = 0.f;
    for (int run = 0; run < 2; ++run) {
      if (run == 1) {
        float2 b0 = base[(104 * h) & 127];
        pR = b0.x; pI = b0.y;
      }
      int kxs = run * 24;
      for (int kk = 0; kk < 24; ++kk) {
        int kxi = kxs + kk;
#pragma unroll
        for (int q = 0; q < 12; ++q) {
          float2 v = yf[kxi][kyb + q];
          aR[q] = fmaf(v.x, pR, aR[q]); aR[q] = fmaf(-v.y, pI, aR[q]);
          aI[q] = fmaf(v.x, pI, aI[q]); aI[q] = fmaf(v.y, pR, aI[q]);
        }
        float nr = fmaf(pR, cc, -pI * sc);
        pI = fmaf(pI, cc, pR * sc);
        pR = nr;
      }
    }
#pragma unroll
    for (int q = 0; q < 12; ++q) t_lds[h][kyb + q] = make_float2(aR[q], aI[q]);
  }
  __syncthreads();
  // phase 2: inverse W-DFT + add pw-output + stats
  int w = tid & 127, hh = tid >> 7;
  float csr[23], csi[23];
#pragma unroll
  for (int ky = 1; ky < 24; ++ky) {
    float2 cc2 = base[(ky * w) & 127];
    csr[ky - 1] = cc2.x; csi[ky - 1] = cc2.y;
  }
  float vst[64];
  float sum = 0.f, ssq = 0.f;
#pragma unroll
  for (int j = 0; j < 64; ++j) {
    int h = hh * 64 + j;
    float t0 = t_lds[h][0].x;
    float s2 = 0.f;
#pragma unroll
    for (int ky = 1; ky < 24; ++ky) {
      float2 tv = t_lds[h][ky];
      s2 = fmaf(tv.x, csr[ky - 1], s2);
      s2 = fmaf(-tv.y, csi[ky - 1], s2);
    }
    float v = y[bc * HWC + h * 128 + w] + (t0 + 2.f * s2) * (1.f / 16384.f);
    vst[j] = v;
    sum += v; ssq = fmaf(v, v, ssq);
  }
  rs[tid] = sum; rq[tid] = ssq;
  __syncthreads();
  for (int sft = 128; sft > 0; sft >>= 1) {
    if (tid < sft) { rs[tid] += rs[tid + sft]; rq[tid] += rq[tid + sft]; }
    __syncthreads();
  }
  if (tid == 0) {
    float mu = rs[0] * (1.f / 16384.f);
    float var = fmaxf(rq[0] * (1.f / 16384.f) - mu * mu, 0.f);
    s_mu = mu;
    s_rstd = rsqrtf(var + 1e-5f);
  }
  __syncthreads();
  float mu = s_mu, rstd = s_rstd;
#pragma unroll
  for (int j = 0; j < 64; ++j) {
    int h = hh * 64 + j;
    G[bc * HWC + h * 128 + w] = gelu_f((vst[j] - mu) * rstd);
  }
}

// ---------------- G2P bilinear gather (cell-sorted) + projection MLP ----------------
__global__ __launch_bounds__(256) void k_g2p(const float* __restrict__ G,
    const int4* __restrict__ pds,
    const float* __restrict__ p1w, const float* __restrict__ p1b,
    const float* __restrict__ p2w, const float* __restrict__ p2b,
    float* __restrict__ out)
{
  __shared__ float s_lds[64][65];
  __shared__ float p1_lds[64][128];
  __shared__ float p1b_lds[128];
  __shared__ float p2_lds[128];
  __shared__ float red[4][64];
  int tid = threadIdx.x;
  for (int l = tid; l < 8192; l += 256) ((float*)p1_lds)[l] = p1w[l];
  if (tid < 128) { p1b_lds[tid] = p1b[tid]; p2_lds[tid] = p2w[tid]; }

  int pt = tid & 63, og = tid >> 6;
  int4 rec = pds[blockIdx.x * 64 + pt];
  int pid = rec.x;
  int packed = rec.y;
  float th = __int_as_float(rec.z), tw = __int_as_float(rec.w);
  int b = pid >> 14;
  int h0 = packed & 255, w0 = (packed >> 8) & 255;
  int h1 = min(h0 + 1, 127), w1 = min(w0 + 1, 127);
  int i00 = h0 * 128 + w0, i01 = h0 * 128 + w1, i10 = h1 * 128 + w0, i11 = h1 * 128 + w1;
  float w00 = (1.f - th) * (1.f - tw), w01 = (1.f - th) * tw;
  float w10 = th * (1.f - tw), w11 = th * tw;
#pragma unroll
  for (int j = 0; j < 16; ++j) {
    int o = og * 16 + j;
    const float* gb = G + (size_t)(b * 64 + o) * HWC;
    s_lds[pt][o] = w00 * gb[i00] + w01 * gb[i01] + w10 * gb[i10] + w11 * gb[i11];
  }
  __syncthreads();

  int jg = og;
  float acc[32] = {};
  for (int o = 0; o < 64; ++o) {
    float sv = s_lds[pt][o];
    const float* prow = &p1_lds[o][jg * 32];
#pragma unroll
    for (int q = 0; q < 8; ++q) {
      float4 pv = *(const float4*)&prow[q * 4];
      acc[q * 4 + 0] = fmaf(sv, pv.x, acc[q * 4 + 0]);
      acc[q * 4 + 1] = fmaf(sv, pv.y, acc[q * 4 + 1]);
      acc[q * 4 + 2] = fmaf(sv, pv.z, acc[q * 4 + 2]);
      acc[q * 4 + 3] = fmaf(sv, pv.w, acc[q * 4 + 3]);
    }
  }
  float partial = 0.f;
#pragma unroll
  for (int jj = 0; jj < 32; ++jj) {
    int j = jg * 32 + jj;
    partial = fmaf(gelu_f(acc[jj] + p1b_lds[j]), p2_lds[j], partial);
  }
  red[jg][pt] = partial;
  __syncthreads();
  if (tid < 64) {
    int4 rec2 = pds[blockIdx.x * 64 + tid];
    out[rec2.x] = red[0][tid] + red[1][tid] + red[2][tid] + red[3][tid] + p2b[0];
  }
}

extern "C" void kernel_launch(void* const* d_in, const int* in_sizes, int n_in,
                              void* d_out, int out_size, void* d_ws, size_t ws_size,
                              hipStream_t stream) {
  const float* coords = (const float*)d_in[0];
  const float* feats  = (const float*)d_in[1];
  const float* dw0 = (const float*)d_in[2];
  const float* db0 = (const float*)d_in[3];
  const float* dw1 = (const float*)d_in[4];
  const float* db1 = (const float*)d_in[5];
  const float* dw2 = (const float*)d_in[6];
  const float* db2 = (const float*)d_in[7];
  const float* liftw = (const float*)d_in[8];
  const float* liftb = (const float*)d_in[9];
  const float* sw1r = (const float*)d_in[10];
  const float* sw1i = (const float*)d_in[11];
  const float* sw2r = (const float*)d_in[12];
  const float* sw2i = (const float*)d_in[13];
  const float* pww = (const float*)d_in[14];
  const float* pwb = (const float*)d_in[15];
  const float* p1w = (const float*)d_in[16];
  const float* p1b = (const float*)d_in[17];
  const float* p2w = (const float*)d_in[18];
  const float* p2b = (const float*)d_in[19];
  float* out = (float*)d_out;
  float* ws = (float*)d_ws;

  // region A (8.4M floats): sums5 + sort staging, later overwritten by y (pw output)
  float*  y      = ws;
  float*  sums5  = ws;                           // 655,360 f
  int*    cnt_i  = (int*)(ws + 655360);          // 131,072 i
  int*    ptrank = (int*)(ws + 786432);
  int*    pd_cell= (int*)(ws + 917504);
  int*    starts = (int*)(ws + 1048576);
  int*    btot   = (int*)(ws + 1179648);
  int*    boff   = (int*)(ws + 1179904);
  int*    pd_idx = (int*)(ws + 1180160);
  float*  pd_th  = ws + 1311232;
  float*  pd_tw  = ws + 1442304;
  float*  G      = ws + 8388608;
  float2* Xf2    = (float2*)(ws + 16777216);     // 512*1152 c
  float2* Yf2    = (float2*)(ws + 19136512);
  int4*   pds    = (int4*)(ws + 21495808);       // 131072 * int4

  hipMemsetAsync(sums5, 0, (size_t)(655360 + 131072) * sizeof(float), stream);

  k_points<<<512, 256, 0, stream>>>(coords, feats, dw0, db0, dw1, db1, dw2, db2,
                                    sums5, cnt_i, ptrank, pd_cell, pd_idx, pd_th, pd_tw);
  k_scanA<<<256, 256, 0, stream>>>(cnt_i, starts, btot);
  k_scanB<<<1, 256, 0, stream>>>(btot, boff);
  k_perm<<<512, 256, 0, stream>>>(pd_cell, ptrank, starts, boff, pd_idx, pd_th, pd_tw, pds);
  k_gridlift<<<dim3(128, 8), 256, 0, stream>>>(sums5, cnt_i, liftw, liftb, G);

  for (int d = 0; d < 4; ++d) {
    const int swoff = d * 2359296;   // 64*64*24*24
    k_fwd_dft<<<512, 256, 0, stream>>>(G, Xf2);
    k_mix<<<dim3(9, 16, 2), 256, 0, stream>>>(Xf2, sw1r + swoff, sw1i + swoff,
                                              sw2r + swoff, sw2i + swoff, Yf2);
    k_pw<<<dim3(128, 8), 256, 0, stream>>>(G, pww + d * 4096, pwb + d * 64, y);
    k_inv_dft<<<512, 256, 0, stream>>>(Yf2, y, G);
  }

  k_g2p<<<2048, 256, 0, stream>>>(G, pds, p1w, p1b, p2w, p2b, out);
}

// Round 4
// 728.864 us; speedup vs baseline: 1.7087x; 1.0361x over previous
//
#include <hip/hip_runtime.h>
#include <hip/hip_bf16.h>
#include <math.h>

#define GH 128
#define GW 128
#define HWC 16384
#define NMODE 1152
#define PI_F 3.14159265358979323846f

typedef __hip_bfloat16 bf16;
typedef __attribute__((ext_vector_type(8))) short short8;
typedef __attribute__((ext_vector_type(4))) float f32x4;

__device__ __forceinline__ float gelu_f(float x) {
  return 0.5f * x * (1.0f + erff(x * 0.70710678118654752f));
}

// ---------------- points: deform MLP + scatter raw inputs + rank + bilinear data ----------------
__global__ __launch_bounds__(256) void k_points(
    const float* __restrict__ coords, const float* __restrict__ feats,
    const float* __restrict__ dw0, const float* __restrict__ db0,
    const float* __restrict__ dw1, const float* __restrict__ db1,
    const float* __restrict__ dw2, const float* __restrict__ db2,
    float* __restrict__ sums5, int* __restrict__ cnt_i,
    int* __restrict__ ptrank, int* __restrict__ pd_cell,
    int* __restrict__ pd_idx, float* __restrict__ pd_th, float* __restrict__ pd_tw)
{
  __shared__ float s_dw0[64], s_db0[32], s_dw1[1024], s_db1[32], s_dw2[64], s_db2[2];
  int t = threadIdx.x;
  for (int i = t; i < 1024; i += 256) s_dw1[i] = dw1[i];
  if (t < 64) { s_dw0[t] = dw0[t]; s_dw2[t] = dw2[t]; }
  if (t < 32) { s_db0[t] = db0[t]; s_db1[t] = db1[t]; }
  if (t < 2)  { s_db2[t] = db2[t]; }
  __syncthreads();

  int pid = blockIdx.x * 256 + t;
  float2 c = ((const float2*)coords)[pid];
  float h1[32], h2[32];
#pragma unroll
  for (int j = 0; j < 32; ++j)
    h1[j] = gelu_f(fmaf(c.x, s_dw0[j], fmaf(c.y, s_dw0[32 + j], s_db0[j])));
#pragma unroll
  for (int j = 0; j < 32; ++j) {
    float a = s_db1[j];
#pragma unroll
    for (int k = 0; k < 32; ++k) a = fmaf(h1[k], s_dw1[k * 32 + j], a);
    h2[j] = gelu_f(a);
  }
  float d0 = s_db2[0], d1 = s_db2[1];
#pragma unroll
  for (int k = 0; k < 32; ++k) { d0 = fmaf(h2[k], s_dw2[2 * k], d0); d1 = fmaf(h2[k], s_dw2[2 * k + 1], d1); }
  float l0 = fminf(fmaxf(c.x + d0, -1.f), 1.f);
  float l1 = fminf(fmaxf(c.y + d1, -1.f), 1.f);
  float ph = (l0 + 1.f) * 0.5f * 127.f;
  float pw = (l1 + 1.f) * 0.5f * 127.f;
  int ih = min(max((int)rintf(ph), 0), 127);
  int iw = min(max((int)rintf(pw), 0), 127);
  int b = pid >> 14;
  int cell = b * HWC + ih * GW + iw;

  float f0 = feats[pid * 3], f1 = feats[pid * 3 + 1], f2 = feats[pid * 3 + 2];
  float* srow = sums5 + (size_t)cell * 5;
  atomicAdd(srow + 0, f0);
  atomicAdd(srow + 1, f1);
  atomicAdd(srow + 2, f2);
  atomicAdd(srow + 3, c.x);
  atomicAdd(srow + 4, c.y);
  int r = atomicAdd(&cnt_i[cell], 1);
  ptrank[pid] = r;
  pd_cell[pid] = cell;

  float fh = floorf(ph), fw = floorf(pw);
  int h0i = min(max((int)fh, 0), 127), w0i = min(max((int)fw, 0), 127);
  pd_idx[pid] = h0i | (w0i << 8);
  pd_th[pid] = ph - fh;
  pd_tw[pid] = pw - fw;
}

// ---------------- scan A ----------------
__global__ __launch_bounds__(256) void k_scanA(const int* __restrict__ cnt,
                                               int* __restrict__ starts, int* __restrict__ btot)
{
  __shared__ int sh[256];
  int blk = blockIdx.x, t = threadIdx.x;
  int base = blk * 512;
  int v0 = cnt[base + 2 * t], v1 = cnt[base + 2 * t + 1];
  int pair = v0 + v1;
  sh[t] = pair; __syncthreads();
  int acc = pair;
  for (int off = 1; off < 256; off <<= 1) {
    int add = (t >= off) ? sh[t - off] : 0;
    __syncthreads();
    acc += add; sh[t] = acc;
    __syncthreads();
  }
  int excl = acc - pair;
  starts[base + 2 * t] = excl;
  starts[base + 2 * t + 1] = excl + v0;
  if (t == 255) btot[blk] = acc;
}

// ---------------- scan B ----------------
__global__ __launch_bounds__(256) void k_scanB(const int* __restrict__ btot, int* __restrict__ boff)
{
  __shared__ int sh[256];
  int t = threadIdx.x;
  int v = btot[t];
  sh[t] = v; __syncthreads();
  int acc = v;
  for (int off = 1; off < 256; off <<= 1) {
    int add = (t >= off) ? sh[t - off] : 0;
    __syncthreads();
    acc += add; sh[t] = acc;
    __syncthreads();
  }
  boff[t] = acc - v;
}

// ---------------- permute ----------------
__global__ __launch_bounds__(256) void k_perm(const int* __restrict__ pd_cell, const int* __restrict__ ptrank,
                                              const int* __restrict__ starts, const int* __restrict__ boff,
                                              const int* __restrict__ pd_idx, const float* __restrict__ pd_th,
                                              const float* __restrict__ pd_tw, int4* __restrict__ pds)
{
  int pid = blockIdx.x * 256 + threadIdx.x;
  int cell = pd_cell[pid];
  int dst = starts[cell] + boff[cell >> 9] + ptrank[pid];
  int4 rec;
  rec.x = pid;
  rec.y = pd_idx[pid];
  rec.z = __float_as_int(pd_th[pid]);
  rec.w = __float_as_int(pd_tw[pid]);
  pds[dst] = rec;
}

// ---------------- scatter-mean + lift -> Gh (bf16) ----------------
__global__ __launch_bounds__(256) void k_gridlift(const float* __restrict__ sums5,
                                                  const int* __restrict__ cnt_i,
                                                  const float* __restrict__ lw,
                                                  const float* __restrict__ lb,
                                                  bf16* __restrict__ Gh)
{
  __shared__ float s5[128][5];
  __shared__ float s_lw[5][64];
  __shared__ float s_lb[64];
  int b = blockIdx.y, cbase = blockIdx.x * 128, tid = threadIdx.x;
  for (int l = tid; l < 640; l += 256) ((float*)s5)[l] = sums5[(size_t)(b * HWC + cbase) * 5 + l];
  for (int l = tid; l < 320; l += 256) ((float*)s_lw)[l] = lw[l];
  if (tid < 64) s_lb[tid] = lb[tid];
  __syncthreads();
  int cl = tid & 127, oh = tid >> 7;
  float v0 = s5[cl][0], v1 = s5[cl][1], v2 = s5[cl][2], v3 = s5[cl][3], v4 = s5[cl][4];
  float cnt = (float)cnt_i[b * HWC + cbase + cl];
  float inv = 1.f / fmaxf(cnt, 1.f);
#pragma unroll
  for (int j = 0; j < 32; ++j) {
    int o = oh * 32 + j;
    float val = cnt * s_lb[o];
    val = fmaf(v0, s_lw[0][o], val);
    val = fmaf(v1, s_lw[1][o], val);
    val = fmaf(v2, s_lw[2][o], val);
    val = fmaf(v3, s_lw[3][o], val);
    val = fmaf(v4, s_lw[4][o], val);
    Gh[(size_t)(b * 64 + o) * HWC + cbase + cl] = __float2bfloat16(val * inv);
  }
}

// ---------------- fused forward DFT: Gh(bc,H,W) -> Xf2(bc,1152) complex ----------------
__global__ __launch_bounds__(256) void k_fwd_dft(const bf16* __restrict__ Gh, float2* __restrict__ Xf2)
{
  __shared__ float img[64][132];
  __shared__ float2 xwl[24][130];
  int bc = blockIdx.x;
  int tid = threadIdx.x;
  int hq = tid >> 3, kg = tid & 7;
  float stc[3], sts[3];
#pragma unroll
  for (int tt = 0; tt < 3; ++tt) {
    float s, c2;
    sincosf((float)(kg * 3 + tt) * (PI_F / 64.f), &s, &c2);
    sts[tt] = s; stc[tt] = c2;
  }
  for (int half = 0; half < 2; ++half) {
    __syncthreads();
    for (int l = tid; l < 1024; l += 256) {
      int hl = l >> 4, wc = (l & 15) * 8;
      short8 v = *(const short8*)(Gh + (size_t)bc * HWC + (half * 64 + hl) * 128 + wc);
#pragma unroll
      for (int j = 0; j < 8; ++j) img[hl][wc + j] = __bfloat162float(((const bf16*)&v)[j]);
    }
    __syncthreads();
    float aR0[3] = {0,0,0}, aI0[3] = {0,0,0}, aR1[3] = {0,0,0}, aI1[3] = {0,0,0};
    float pR[3] = {1.f,1.f,1.f}, pI[3] = {0.f,0.f,0.f};
    int h0 = hq * 2;
    for (int w = 0; w < 128; ++w) {
      float x0 = img[h0][w], x1 = img[h0 + 1][w];
#pragma unroll
      for (int tt = 0; tt < 3; ++tt) {
        aR0[tt] = fmaf(x0, pR[tt], aR0[tt]);
        aI0[tt] = fmaf(x0, pI[tt], aI0[tt]);
        aR1[tt] = fmaf(x1, pR[tt], aR1[tt]);
        aI1[tt] = fmaf(x1, pI[tt], aI1[tt]);
        float nr = fmaf(pR[tt], stc[tt], pI[tt] * sts[tt]);
        pI[tt] = fmaf(pI[tt], stc[tt], -pR[tt] * sts[tt]);
        pR[tt] = nr;
      }
    }
    int hg = half * 64 + h0;
#pragma unroll
    for (int tt = 0; tt < 3; ++tt) {
      int ky = kg * 3 + tt;
      xwl[ky][hg]     = make_float2(aR0[tt], aI0[tt]);
      xwl[ky][hg + 1] = make_float2(aR1[tt], aI1[tt]);
    }
  }
  __syncthreads();
  if (tid < 192) {
    int kxi = tid >> 2, kg2 = tid & 3;
    int kxe = kxi < 24 ? kxi : kxi + 80;
    float sn, cn;
    sincosf((float)kxe * (PI_F / 64.f), &sn, &cn);
    float aR[6] = {0,0,0,0,0,0}, aI[6] = {0,0,0,0,0,0};
    float pR = 1.f, pI = 0.f;
    for (int h = 0; h < 128; ++h) {
#pragma unroll
      for (int tt = 0; tt < 6; ++tt) {
        float2 v = xwl[kg2 * 6 + tt][h];
        aR[tt] = fmaf(v.x, pR, aR[tt]); aR[tt] = fmaf(-v.y, pI, aR[tt]);
        aI[tt] = fmaf(v.x, pI, aI[tt]); aI[tt] = fmaf(v.y, pR, aI[tt]);
      }
      float nr = fmaf(pR, cn, pI * sn);
      pI = fmaf(pI, cn, -pR * sn);
      pR = nr;
    }
#pragma unroll
    for (int tt = 0; tt < 6; ++tt) {
      int m = kxi * 24 + kg2 * 6 + tt;
      Xf2[bc * NMODE + m] = make_float2(aR[tt], aI[tt]);
    }
  }
}

// ---------------- per-mode 64x64 complex channel mix ----------------
__global__ __launch_bounds__(256) void k_mix(const float2* __restrict__ Xf2,
    const float* __restrict__ w1r, const float* __restrict__ w1i,
    const float* __restrict__ w2r, const float* __restrict__ w2i,
    float2* __restrict__ Yf2)
{
  int m = blockIdx.x * 64 + (threadIdx.x & 63);
  int o = blockIdx.y * 4 + (threadIdx.x >> 6);
  int half = blockIdx.z;
  int gm = half * 576 + m;
  const float* wr_ = half ? w2r : w1r;
  const float* wi_ = half ? w2i : w1i;
  float aR[8] = {}, aI[8] = {};
#pragma unroll 2
  for (int i = 0; i < 64; ++i) {
    int widx = (i * 64 + o) * 576 + m;
    float wr = wr_[widx], wi = wi_[widx];
#pragma unroll
    for (int b = 0; b < 8; ++b) {
      float2 x = Xf2[(b * 64 + i) * NMODE + gm];
      aR[b] = fmaf(x.x, wr, aR[b]); aR[b] = fmaf(-x.y, wi, aR[b]);
      aI[b] = fmaf(x.x, wi, aI[b]); aI[b] = fmaf(x.y, wr, aI[b]);
    }
  }
#pragma unroll
  for (int b = 0; b < 8; ++b)
    Yf2[(b * 64 + o) * NMODE + gm] = make_float2(aR[b], aI[b]);
}

// ---------------- pointwise conv via MFMA: yh = pw^T x Gh (bf16 in, bf16 out) ----------------
__global__ __launch_bounds__(256) void k_pw_mfma(const bf16* __restrict__ Gh,
                                                 const float* __restrict__ pww,
                                                 const float* __restrict__ pwb,
                                                 bf16* __restrict__ yh)
{
  __shared__ bf16 gt[256][72];   // [p][i] transposed G tile
  __shared__ bf16 wt[64][72];    // [o][i] = W[i][o]
  __shared__ float s_b[64];
  int b = blockIdx.y, p0 = blockIdx.x * 256, tid = threadIdx.x;
  for (int l = tid; l < 4096; l += 256) {
    int i = l >> 6, o = l & 63;
    wt[o][i] = __float2bfloat16(pww[l]);
  }
  if (tid < 64) s_b[tid] = pwb[tid];
  for (int l = tid; l < 2048; l += 256) {
    int i = l >> 5, pc = (l & 31) * 8;
    short8 v = *(const short8*)(Gh + (size_t)(b * 64 + i) * HWC + p0 + pc);
#pragma unroll
    for (int j = 0; j < 8; ++j) gt[pc + j][i] = ((const bf16*)&v)[j];
  }
  __syncthreads();
  int wave = tid >> 6, lane = tid & 63;
  int lr = lane & 15, lg = lane >> 4;
  int pw_ = wave * 64;
  f32x4 acc[4][4] = {};
#pragma unroll
  for (int kk = 0; kk < 2; ++kk) {
    short8 a[4], bb[4];
#pragma unroll
    for (int mi = 0; mi < 4; ++mi) a[mi] = *(const short8*)&wt[16 * mi + lr][kk * 32 + lg * 8];
#pragma unroll
    for (int ni = 0; ni < 4; ++ni) bb[ni] = *(const short8*)&gt[pw_ + 16 * ni + lr][kk * 32 + lg * 8];
#pragma unroll
    for (int mi = 0; mi < 4; ++mi)
#pragma unroll
      for (int ni = 0; ni < 4; ++ni)
        acc[mi][ni] = __builtin_amdgcn_mfma_f32_16x16x32_bf16(a[mi], bb[ni], acc[mi][ni], 0, 0, 0);
  }
#pragma unroll
  for (int mi = 0; mi < 4; ++mi)
#pragma unroll
    for (int ni = 0; ni < 4; ++ni) {
#pragma unroll
      for (int r = 0; r < 4; ++r) {
        int o = 16 * mi + lg * 4 + r;
        int p = p0 + pw_ + 16 * ni + lr;
        yh[(size_t)(b * 64 + o) * HWC + p] = __float2bfloat16(acc[mi][ni][r] + s_b[o]);
      }
    }
}

// ---------------- fused inverse DFT + add + instnorm + gelu: Yf2 + yh -> Gh ----------------
__global__ __launch_bounds__(256) void k_inv_dft(const float2* __restrict__ Yf2,
                                                 const bf16* __restrict__ yh, bf16* __restrict__ Gh)
{
  __shared__ float2 yf[48][24];
  __shared__ float2 t_lds[128][26];
  __shared__ float2 base[128];
  __shared__ float rs[256], rq[256];
  __shared__ float s_mu, s_rstd;
  int bc = blockIdx.x;
  int tid = threadIdx.x;
  for (int l = tid; l < 1152; l += 256) {
    int kxi = l / 24, ky = l - kxi * 24;
    yf[kxi][ky] = Yf2[bc * NMODE + l];
  }
  if (tid < 128) {
    float s, c2; sincosf((float)tid * (PI_F / 64.f), &s, &c2);
    base[tid] = make_float2(c2, s);
  }
  __syncthreads();
  {
    int h = tid & 127, kyb = (tid >> 7) * 12;
    float aR[12] = {}, aI[12] = {};
    float2 bb = base[h];
    float cc = bb.x, sc = bb.y;
    float pR = 1.f, pI = 0.f;
    for (int run = 0; run < 2; ++run) {
      if (run == 1) {
        float2 b0 = base[(104 * h) & 127];
        pR = b0.x; pI = b0.y;
      }
      int kxs = run * 24;
      for (int kk = 0; kk < 24; ++kk) {
        int kxi = kxs + kk;
#pragma unroll
        for (int q = 0; q < 12; ++q) {
          float2 v = yf[kxi][kyb + q];
          aR[q] = fmaf(v.x, pR, aR[q]); aR[q] = fmaf(-v.y, pI, aR[q]);
          aI[q] = fmaf(v.x, pI, aI[q]); aI[q] = fmaf(v.y, pR, aI[q]);
        }
        float nr = fmaf(pR, cc, -pI * sc);
        pI = fmaf(pI, cc, pR * sc);
        pR = nr;
      }
    }
#pragma unroll
    for (int q = 0; q < 12; ++q) t_lds[h][kyb + q] = make_float2(aR[q], aI[q]);
  }
  __syncthreads();
  int w = tid & 127, hh = tid >> 7;
  float csr[23], csi[23];
#pragma unroll
  for (int ky = 1; ky < 24; ++ky) {
    float2 cc2 = base[(ky * w) & 127];
    csr[ky - 1] = cc2.x; csi[ky - 1] = cc2.y;
  }
  float vst[64];
  float sum = 0.f, ssq = 0.f;
#pragma unroll
  for (int j = 0; j < 64; ++j) {
    int h = hh * 64 + j;
    float t0 = t_lds[h][0].x;
    float s2 = 0.f;
#pragma unroll
    for (int ky = 1; ky < 24; ++ky) {
      float2 tv = t_lds[h][ky];
      s2 = fmaf(tv.x, csr[ky - 1], s2);
      s2 = fmaf(-tv.y, csi[ky - 1], s2);
    }
    float v = __bfloat162float(yh[bc * HWC + h * 128 + w]) + (t0 + 2.f * s2) * (1.f / 16384.f);
    vst[j] = v;
    sum += v; ssq = fmaf(v, v, ssq);
  }
  rs[tid] = sum; rq[tid] = ssq;
  __syncthreads();
  for (int sft = 128; sft > 0; sft >>= 1) {
    if (tid < sft) { rs[tid] += rs[tid + sft]; rq[tid] += rq[tid + sft]; }
    __syncthreads();
  }
  if (tid == 0) {
    float mu = rs[0] * (1.f / 16384.f);
    float var = fmaxf(rq[0] * (1.f / 16384.f) - mu * mu, 0.f);
    s_mu = mu;
    s_rstd = rsqrtf(var + 1e-5f);
  }
  __syncthreads();
  float mu = s_mu, rstd = s_rstd;
#pragma unroll
  for (int j = 0; j < 64; ++j) {
    int h = hh * 64 + j;
    Gh[bc * HWC + h * 128 + w] = __float2bfloat16(gelu_f((vst[j] - mu) * rstd));
  }
}

// ---------------- G2P bilinear gather (cell-sorted, bf16 grid) + projection MLP ----------------
__global__ __launch_bounds__(256) void k_g2p(const bf16* __restrict__ Gh,
    const int4* __restrict__ pds,
    const float* __restrict__ p1w, const float* __restrict__ p1b,
    const float* __restrict__ p2w, const float* __restrict__ p2b,
    float* __restrict__ out)
{
  __shared__ float s_lds[64][65];
  __shared__ float p1_lds[64][128];
  __shared__ float p1b_lds[128];
  __shared__ float p2_lds[128];
  __shared__ float red[4][64];
  int tid = threadIdx.x;
  for (int l = tid; l < 8192; l += 256) ((float*)p1_lds)[l] = p1w[l];
  if (tid < 128) { p1b_lds[tid] = p1b[tid]; p2_lds[tid] = p2w[tid]; }

  int pt = tid & 63, og = tid >> 6;
  int4 rec = pds[blockIdx.x * 64 + pt];
  int pid = rec.x;
  int packed = rec.y;
  float th = __int_as_float(rec.z), tw = __int_as_float(rec.w);
  int b = pid >> 14;
  int h0 = packed & 255, w0 = (packed >> 8) & 255;
  int h1 = min(h0 + 1, 127), w1 = min(w0 + 1, 127);
  int i00 = h0 * 128 + w0, i01 = h0 * 128 + w1, i10 = h1 * 128 + w0, i11 = h1 * 128 + w1;
  float w00 = (1.f - th) * (1.f - tw), w01 = (1.f - th) * tw;
  float w10 = th * (1.f - tw), w11 = th * tw;
#pragma unroll
  for (int j = 0; j < 16; ++j) {
    int o = og * 16 + j;
    const bf16* gb = Gh + (size_t)(b * 64 + o) * HWC;
    s_lds[pt][o] = w00 * __bfloat162float(gb[i00]) + w01 * __bfloat162float(gb[i01])
                 + w10 * __bfloat162float(gb[i10]) + w11 * __bfloat162float(gb[i11]);
  }
  __syncthreads();

  int jg = og;
  float acc[32] = {};
  for (int o = 0; o < 64; ++o) {
    float sv = s_lds[pt][o];
    const float* prow = &p1_lds[o][jg * 32];
#pragma unroll
    for (int q = 0; q < 8; ++q) {
      float4 pv = *(const float4*)&prow[q * 4];
      acc[q * 4 + 0] = fmaf(sv, pv.x, acc[q * 4 + 0]);
      acc[q * 4 + 1] = fmaf(sv, pv.y, acc[q * 4 + 1]);
      acc[q * 4 + 2] = fmaf(sv, pv.z, acc[q * 4 + 2]);
      acc[q * 4 + 3] = fmaf(sv, pv.w, acc[q * 4 + 3]);
    }
  }
  float partial = 0.f;
#pragma unroll
  for (int jj = 0; jj < 32; ++jj) {
    int j = jg * 32 + jj;
    partial = fmaf(gelu_f(acc[jj] + p1b_lds[j]), p2_lds[j], partial);
  }
  red[jg][pt] = partial;
  __syncthreads();
  if (tid < 64) {
    int4 rec2 = pds[blockIdx.x * 64 + tid];
    out[rec2.x] = red[0][tid] + red[1][tid] + red[2][tid] + red[3][tid] + p2b[0];
  }
}

extern "C" void kernel_launch(void* const* d_in, const int* in_sizes, int n_in,
                              void* d_out, int out_size, void* d_ws, size_t ws_size,
                              hipStream_t stream) {
  const float* coords = (const float*)d_in[0];
  const float* feats  = (const float*)d_in[1];
  const float* dw0 = (const float*)d_in[2];
  const float* db0 = (const float*)d_in[3];
  const float* dw1 = (const float*)d_in[4];
  const float* db1 = (const float*)d_in[5];
  const float* dw2 = (const float*)d_in[6];
  const float* db2 = (const float*)d_in[7];
  const float* liftw = (const float*)d_in[8];
  const float* liftb = (const float*)d_in[9];
  const float* sw1r = (const float*)d_in[10];
  const float* sw1i = (const float*)d_in[11];
  const float* sw2r = (const float*)d_in[12];
  const float* sw2i = (const float*)d_in[13];
  const float* pww = (const float*)d_in[14];
  const float* pwb = (const float*)d_in[15];
  const float* p1w = (const float*)d_in[16];
  const float* p1b = (const float*)d_in[17];
  const float* p2w = (const float*)d_in[18];
  const float* p2b = (const float*)d_in[19];
  float* out = (float*)d_out;
  float* ws = (float*)d_ws;

  float*  sums5  = ws;
  int*    cnt_i  = (int*)(ws + 655360);
  int*    ptrank = (int*)(ws + 786432);
  int*    pd_cell= (int*)(ws + 917504);
  int*    starts = (int*)(ws + 1048576);
  int*    btot   = (int*)(ws + 1179648);
  int*    boff   = (int*)(ws + 1179904);
  int*    pd_idx = (int*)(ws + 1180160);
  float*  pd_th  = ws + 1311232;
  float*  pd_tw  = ws + 1442304;
  bf16*   Gh     = (bf16*)(ws + 2097152);
  bf16*   yh     = (bf16*)(ws + 6291456);
  float2* Xf2    = (float2*)(ws + 10485760);
  float2* Yf2    = (float2*)(ws + 11665408);
  int4*   pds    = (int4*)(ws + 12845056);

  hipMemsetAsync(sums5, 0, (size_t)(655360 + 131072) * sizeof(float), stream);

  k_points<<<512, 256, 0, stream>>>(coords, feats, dw0, db0, dw1, db1, dw2, db2,
                                    sums5, cnt_i, ptrank, pd_cell, pd_idx, pd_th, pd_tw);
  k_scanA<<<256, 256, 0, stream>>>(cnt_i, starts, btot);
  k_scanB<<<1, 256, 0, stream>>>(btot, boff);
  k_perm<<<512, 256, 0, stream>>>(pd_cell, ptrank, starts, boff, pd_idx, pd_th, pd_tw, pds);
  k_gridlift<<<dim3(128, 8), 256, 0, stream>>>(sums5, cnt_i, liftw, liftb, Gh);

  for (int d = 0; d < 4; ++d) {
    const int swoff = d * 2359296;
    k_fwd_dft<<<512, 256, 0, stream>>>(Gh, Xf2);
    k_mix<<<dim3(9, 16, 2), 256, 0, stream>>>(Xf2, sw1r + swoff, sw1i + swoff,
                                              sw2r + swoff, sw2i + swoff, Yf2);
    k_pw_mfma<<<dim3(64, 8), 256, 0, stream>>>(Gh, pww + d * 4096, pwb + d * 64, yh);
    k_inv_dft<<<512, 256, 0, stream>>>(Yf2, yh, Gh);
  }

  k_g2p<<<2048, 256, 0, stream>>>(Gh, pds, p1w, p1b, p2w, p2b, out);
}

// Round 5
// 503.744 us; speedup vs baseline: 2.4724x; 1.4469x over previous
//
#include <hip/hip_runtime.h>
#include <math.h>

#define GH 128
#define GW 128
#define HWC 16384
#define NMODE 1152
#define PI_F 3.14159265358979323846f

typedef _Float16 f16;
typedef __attribute__((ext_vector_type(8))) _Float16 f16x8;
typedef __attribute__((ext_vector_type(4))) float f32x4;

__device__ __forceinline__ float gelu_f(float x) {
  return 0.5f * x * (1.0f + erff(x * 0.70710678118654752f));
}

// ---------------- twiddle tables (f16, integer-exact angles) ----------------
// Fw_t[48][128]:  n=2ky -> cos(2pi ky w/128), n=2ky+1 -> -sin
// Fh_t[96][128]:  n<48: cos(2pi f(n) h/128), n>=48: sin(2pi f(n-48) h/128), f(k)=k<24?k:k+80
// Bh_t[128][96]:  transpose of Fh_t
// Bw_t[128][64]:  k=2ky -> g*cos(2pi ky w/128), k=2ky+1 -> -g*sin ; k==1 -> 0 ; k>=48 -> 0 ; g=(ky?2:1)
__global__ __launch_bounds__(256) void k_twiddle(f16* __restrict__ Fw, f16* __restrict__ Fh,
                                                 f16* __restrict__ Bh, f16* __restrict__ Bw)
{
  int idx = blockIdx.x * 256 + threadIdx.x;
  if (idx < 6144) {
    int n = idx >> 7, w = idx & 127;
    int ky = n >> 1;
    int ang = (ky * w) & 127;
    float s, c; sincosf((float)ang * (PI_F / 64.f), &s, &c);
    Fw[idx] = (f16)((n & 1) ? -s : c);
  } else if (idx < 18432) {
    int t = idx - 6144;
    int n = t >> 7, h = t & 127;
    int kx = n < 48 ? n : n - 48;
    int f = kx < 24 ? kx : kx + 80;
    int ang = (f * h) & 127;
    float s, c; sincosf((float)ang * (PI_F / 64.f), &s, &c);
    float v = (n < 48) ? c : s;
    Fh[t] = (f16)v;
    Bh[h * 96 + n] = (f16)v;
  } else if (idx < 26624) {
    int t = idx - 18432;
    int w = t >> 6, k = t & 63;
    float v = 0.f;
    if (k < 48 && k != 1) {
      int ky = k >> 1;
      float g = (ky == 0) ? 1.f : 2.f;
      int ang = (ky * w) & 127;
      float s, c; sincosf((float)ang * (PI_F / 64.f), &s, &c);
      v = (k & 1) ? -g * s : g * c;
    }
    Bw[t] = (f16)v;
  }
}

// ---------------- points: deform MLP + scatter raw inputs + rank + bilinear data ----------------
__global__ __launch_bounds__(256) void k_points(
    const float* __restrict__ coords, const float* __restrict__ feats,
    const float* __restrict__ dw0, const float* __restrict__ db0,
    const float* __restrict__ dw1, const float* __restrict__ db1,
    const float* __restrict__ dw2, const float* __restrict__ db2,
    float* __restrict__ sums5, int* __restrict__ cnt_i,
    int* __restrict__ ptrank, int* __restrict__ pd_cell,
    int* __restrict__ pd_idx, float* __restrict__ pd_th, float* __restrict__ pd_tw)
{
  __shared__ float s_dw0[64], s_db0[32], s_dw1[1024], s_db1[32], s_dw2[64], s_db2[2];
  int t = threadIdx.x;
  for (int i = t; i < 1024; i += 256) s_dw1[i] = dw1[i];
  if (t < 64) { s_dw0[t] = dw0[t]; s_dw2[t] = dw2[t]; }
  if (t < 32) { s_db0[t] = db0[t]; s_db1[t] = db1[t]; }
  if (t < 2)  { s_db2[t] = db2[t]; }
  __syncthreads();

  int pid = blockIdx.x * 256 + t;
  float2 c = ((const float2*)coords)[pid];
  float h1[32], h2[32];
#pragma unroll
  for (int j = 0; j < 32; ++j)
    h1[j] = gelu_f(fmaf(c.x, s_dw0[j], fmaf(c.y, s_dw0[32 + j], s_db0[j])));
#pragma unroll
  for (int j = 0; j < 32; ++j) {
    float a = s_db1[j];
#pragma unroll
    for (int k = 0; k < 32; ++k) a = fmaf(h1[k], s_dw1[k * 32 + j], a);
    h2[j] = gelu_f(a);
  }
  float d0 = s_db2[0], d1 = s_db2[1];
#pragma unroll
  for (int k = 0; k < 32; ++k) { d0 = fmaf(h2[k], s_dw2[2 * k], d0); d1 = fmaf(h2[k], s_dw2[2 * k + 1], d1); }
  float l0 = fminf(fmaxf(c.x + d0, -1.f), 1.f);
  float l1 = fminf(fmaxf(c.y + d1, -1.f), 1.f);
  float ph = (l0 + 1.f) * 0.5f * 127.f;
  float pw = (l1 + 1.f) * 0.5f * 127.f;
  int ih = min(max((int)rintf(ph), 0), 127);
  int iw = min(max((int)rintf(pw), 0), 127);
  int b = pid >> 14;
  int cell = b * HWC + ih * GW + iw;

  float f0 = feats[pid * 3], f1 = feats[pid * 3 + 1], f2 = feats[pid * 3 + 2];
  float* srow = sums5 + (size_t)cell * 5;
  atomicAdd(srow + 0, f0);
  atomicAdd(srow + 1, f1);
  atomicAdd(srow + 2, f2);
  atomicAdd(srow + 3, c.x);
  atomicAdd(srow + 4, c.y);
  int r = atomicAdd(&cnt_i[cell], 1);
  ptrank[pid] = r;
  pd_cell[pid] = cell;

  float fh = floorf(ph), fw = floorf(pw);
  int h0i = min(max((int)fh, 0), 127), w0i = min(max((int)fw, 0), 127);
  pd_idx[pid] = h0i | (w0i << 8);
  pd_th[pid] = ph - fh;
  pd_tw[pid] = pw - fw;
}

// ---------------- scans + permute ----------------
__global__ __launch_bounds__(256) void k_scanA(const int* __restrict__ cnt,
                                               int* __restrict__ starts, int* __restrict__ btot)
{
  __shared__ int sh[256];
  int blk = blockIdx.x, t = threadIdx.x;
  int base = blk * 512;
  int v0 = cnt[base + 2 * t], v1 = cnt[base + 2 * t + 1];
  int pair = v0 + v1;
  sh[t] = pair; __syncthreads();
  int acc = pair;
  for (int off = 1; off < 256; off <<= 1) {
    int add = (t >= off) ? sh[t - off] : 0;
    __syncthreads();
    acc += add; sh[t] = acc;
    __syncthreads();
  }
  int excl = acc - pair;
  starts[base + 2 * t] = excl;
  starts[base + 2 * t + 1] = excl + v0;
  if (t == 255) btot[blk] = acc;
}

__global__ __launch_bounds__(256) void k_scanB(const int* __restrict__ btot, int* __restrict__ boff)
{
  __shared__ int sh[256];
  int t = threadIdx.x;
  int v = btot[t];
  sh[t] = v; __syncthreads();
  int acc = v;
  for (int off = 1; off < 256; off <<= 1) {
    int add = (t >= off) ? sh[t - off] : 0;
    __syncthreads();
    acc += add; sh[t] = acc;
    __syncthreads();
  }
  boff[t] = acc - v;
}

__global__ __launch_bounds__(256) void k_perm(const int* __restrict__ pd_cell, const int* __restrict__ ptrank,
                                              const int* __restrict__ starts, const int* __restrict__ boff,
                                              const int* __restrict__ pd_idx, const float* __restrict__ pd_th,
                                              const float* __restrict__ pd_tw, int4* __restrict__ pds)
{
  int pid = blockIdx.x * 256 + threadIdx.x;
  int cell = pd_cell[pid];
  int dst = starts[cell] + boff[cell >> 9] + ptrank[pid];
  int4 rec;
  rec.x = pid;
  rec.y = pd_idx[pid];
  rec.z = __float_as_int(pd_th[pid]);
  rec.w = __float_as_int(pd_tw[pid]);
  pds[dst] = rec;
}

// ---------------- scatter-mean + lift -> Gh (f16, channel-major) ----------------
__global__ __launch_bounds__(256) void k_gridlift(const float* __restrict__ sums5,
                                                  const int* __restrict__ cnt_i,
                                                  const float* __restrict__ lw,
                                                  const float* __restrict__ lb,
                                                  f16* __restrict__ Gh)
{
  __shared__ float s5[128][5];
  __shared__ float s_lw[5][64];
  __shared__ float s_lb[64];
  int b = blockIdx.y, cbase = blockIdx.x * 128, tid = threadIdx.x;
  for (int l = tid; l < 640; l += 256) ((float*)s5)[l] = sums5[(size_t)(b * HWC + cbase) * 5 + l];
  for (int l = tid; l < 320; l += 256) ((float*)s_lw)[l] = lw[l];
  if (tid < 64) s_lb[tid] = lb[tid];
  __syncthreads();
  int cl = tid & 127, oh = tid >> 7;
  float v0 = s5[cl][0], v1 = s5[cl][1], v2 = s5[cl][2], v3 = s5[cl][3], v4 = s5[cl][4];
  float cnt = (float)cnt_i[b * HWC + cbase + cl];
  float inv = 1.f / fmaxf(cnt, 1.f);
#pragma unroll
  for (int j = 0; j < 32; ++j) {
    int o = oh * 32 + j;
    float val = cnt * s_lb[o];
    val = fmaf(v0, s_lw[0][o], val);
    val = fmaf(v1, s_lw[1][o], val);
    val = fmaf(v2, s_lw[2][o], val);
    val = fmaf(v3, s_lw[3][o], val);
    val = fmaf(v4, s_lw[4][o], val);
    Gh[(size_t)(b * 64 + o) * HWC + cbase + cl] = (f16)(val * inv);
  }
}

// ---------------- forward DFT (two fused MFMA GEMMs): Gh(bc,H,W) -> Xf2(bc,1152) ----------------
__global__ __launch_bounds__(256) void k_fwd(const f16* __restrict__ Gh,
                                             const f16* __restrict__ Fw_t, const f16* __restrict__ Fh_t,
                                             float2* __restrict__ Xf2)
{
  __shared__ f16 s_fw[48][136];
  __shared__ f16 s_u[19584];   // union: phase1 img[128][136]; phase2 xw[48][136] + fh[96][136]
  f16 (*s_img)[136] = (f16(*)[136])s_u;
  f16 (*s_xw)[136]  = (f16(*)[136])s_u;
  f16 (*s_fh)[136]  = (f16(*)[136])(s_u + 48 * 136);
  int bc = blockIdx.x, tid = threadIdx.x;
  for (int l = tid; l < 2048; l += 256) {
    int r = l >> 4, c = l & 15;
    *(f16x8*)&s_img[r][c * 8] = *(const f16x8*)(Gh + (size_t)bc * HWC + r * 128 + c * 8);
  }
  for (int l = tid; l < 768; l += 256) {
    int r = l >> 4, c = l & 15;
    *(f16x8*)&s_fw[r][c * 8] = *(const f16x8*)(Fw_t + r * 128 + c * 8);
  }
  __syncthreads();
  int wave = tid >> 6, lane = tid & 63, lr = lane & 15, lg = lane >> 4;

  // GEMM1: Xw[h][n] = sum_w img[h][w] * Fw[w][n]; M=128 N=48 K=128
  f32x4 acc1[2][3] = {};
#pragma unroll
  for (int ks = 0; ks < 4; ++ks) {
    f16x8 a[2], b[3];
#pragma unroll
    for (int mm = 0; mm < 2; ++mm) a[mm] = *(const f16x8*)&s_img[(wave * 2 + mm) * 16 + lr][ks * 32 + lg * 8];
#pragma unroll
    for (int nt = 0; nt < 3; ++nt) b[nt] = *(const f16x8*)&s_fw[nt * 16 + lr][ks * 32 + lg * 8];
#pragma unroll
    for (int mm = 0; mm < 2; ++mm)
#pragma unroll
      for (int nt = 0; nt < 3; ++nt)
        acc1[mm][nt] = __builtin_amdgcn_mfma_f32_16x16x32_f16(a[mm], b[nt], acc1[mm][nt], 0, 0, 0);
  }
  __syncthreads();
  // write Xw^T into s_xw ; stage Fh
#pragma unroll
  for (int mm = 0; mm < 2; ++mm)
#pragma unroll
    for (int nt = 0; nt < 3; ++nt) {
      int n = nt * 16 + lr;
      int h0 = (wave * 2 + mm) * 16 + lg * 4;
#pragma unroll
      for (int r = 0; r < 4; ++r) s_xw[n][h0 + r] = (f16)acc1[mm][nt][r];
    }
  for (int l = tid; l < 1536; l += 256) {
    int r = l >> 4, c = l & 15;
    *(f16x8*)&s_fh[r][c * 8] = *(const f16x8*)(Fh_t + r * 128 + c * 8);
  }
  __syncthreads();

  // GEMM2: P[m'][n] = sum_h xw[m'][h] * Fh[h][n]; M=48 N=96 K=128
  // units u = 0..8: mt=u/3, ntC=u%3 ; pair (ntC, ntC+3) -> in-lane complex combine
  for (int u = wave; u < 9; u += 4) {
    int mt = u / 3, ntC = u - mt * 3;
    f32x4 accC = {}, accS = {};
#pragma unroll
    for (int ks = 0; ks < 4; ++ks) {
      f16x8 a  = *(const f16x8*)&s_xw[mt * 16 + lr][ks * 32 + lg * 8];
      f16x8 bC = *(const f16x8*)&s_fh[ntC * 16 + lr][ks * 32 + lg * 8];
      f16x8 bS = *(const f16x8*)&s_fh[(ntC + 3) * 16 + lr][ks * 32 + lg * 8];
      accC = __builtin_amdgcn_mfma_f32_16x16x32_f16(a, bC, accC, 0, 0, 0);
      accS = __builtin_amdgcn_mfma_f32_16x16x32_f16(a, bS, accS, 0, 0, 0);
    }
    int kx = ntC * 16 + lr;
    int ky0 = (mt * 16 + lg * 4) >> 1;
    Xf2[bc * NMODE + kx * 24 + ky0]     = make_float2(accC[0] + accS[1], accC[1] - accS[0]);
    Xf2[bc * NMODE + kx * 24 + ky0 + 1] = make_float2(accC[2] + accS[3], accC[3] - accS[2]);
  }
}

// ---------------- per-mode 64x64 complex channel mix (f32 VALU) ----------------
__global__ __launch_bounds__(256) void k_mix(const float2* __restrict__ Xf2,
    const float* __restrict__ w1r, const float* __restrict__ w1i,
    const float* __restrict__ w2r, const float* __restrict__ w2i,
    float2* __restrict__ Yf2)
{
  int m = blockIdx.x * 64 + (threadIdx.x & 63);
  int o = blockIdx.y * 4 + (threadIdx.x >> 6);
  int half = blockIdx.z;
  int gm = half * 576 + m;
  const float* wr_ = half ? w2r : w1r;
  const float* wi_ = half ? w2i : w1i;
  float aR[8] = {}, aI[8] = {};
#pragma unroll 2
  for (int i = 0; i < 64; ++i) {
    int widx = (i * 64 + o) * 576 + m;
    float wr = wr_[widx], wi = wi_[widx];
#pragma unroll
    for (int b = 0; b < 8; ++b) {
      float2 x = Xf2[(b * 64 + i) * NMODE + gm];
      aR[b] = fmaf(x.x, wr, aR[b]); aR[b] = fmaf(-x.y, wi, aR[b]);
      aI[b] = fmaf(x.x, wi, aI[b]); aI[b] = fmaf(x.y, wr, aI[b]);
    }
  }
#pragma unroll
  for (int b = 0; b < 8; ++b)
    Yf2[(b * 64 + o) * NMODE + gm] = make_float2(aR[b], aI[b]);
}

// ---------------- pointwise conv via MFMA f16 ----------------
__global__ __launch_bounds__(256) void k_pw(const f16* __restrict__ Gh,
                                            const float* __restrict__ pww,
                                            const float* __restrict__ pwb,
                                            f16* __restrict__ yh)
{
  __shared__ f16 gt[256][72];   // [p][i]
  __shared__ f16 wt[64][72];    // [o][i]
  __shared__ float s_b[64];
  int b = blockIdx.y, p0 = blockIdx.x * 256, tid = threadIdx.x;
  for (int l = tid; l < 4096; l += 256) {
    int i = l >> 6, o = l & 63;
    wt[o][i] = (f16)pww[l];
  }
  if (tid < 64) s_b[tid] = pwb[tid];
  for (int l = tid; l < 2048; l += 256) {
    int i = l >> 5, pc = (l & 31) * 8;
    f16x8 v = *(const f16x8*)(Gh + (size_t)(b * 64 + i) * HWC + p0 + pc);
#pragma unroll
    for (int j = 0; j < 8; ++j) gt[pc + j][i] = v[j];
  }
  __syncthreads();
  int wave = tid >> 6, lane = tid & 63;
  int lr = lane & 15, lg = lane >> 4;
  int pw_ = wave * 64;
  f32x4 acc[4][4] = {};
#pragma unroll
  for (int kk = 0; kk < 2; ++kk) {
    f16x8 a[4], bb[4];
#pragma unroll
    for (int mi = 0; mi < 4; ++mi) a[mi] = *(const f16x8*)&wt[16 * mi + lr][kk * 32 + lg * 8];
#pragma unroll
    for (int ni = 0; ni < 4; ++ni) bb[ni] = *(const f16x8*)&gt[pw_ + 16 * ni + lr][kk * 32 + lg * 8];
#pragma unroll
    for (int mi = 0; mi < 4; ++mi)
#pragma unroll
      for (int ni = 0; ni < 4; ++ni)
        acc[mi][ni] = __builtin_amdgcn_mfma_f32_16x16x32_f16(a[mi], bb[ni], acc[mi][ni], 0, 0, 0);
  }
#pragma unroll
  for (int mi = 0; mi < 4; ++mi)
#pragma unroll
    for (int ni = 0; ni < 4; ++ni) {
#pragma unroll
      for (int r = 0; r < 4; ++r) {
        int o = 16 * mi + lg * 4 + r;
        int p = p0 + pw_ + 16 * ni + lr;
        yh[(size_t)(b * 64 + o) * HWC + p] = (f16)(acc[mi][ni][r] + s_b[o]);
      }
    }
}

// ---------------- inverse DFT (two fused MFMA GEMMs) + add + instnorm + gelu ----------------
__global__ __launch_bounds__(256) void k_inv(const float2* __restrict__ Yf2,
                                             const f16* __restrict__ Bh_t, const f16* __restrict__ Bw_t,
                                             const f16* __restrict__ yh, f16* __restrict__ Gh)
{
  __shared__ f16 s_u[21120];   // phase1: a[48][120] + bh[128][120] ; phase2: t[128][72] + bw[128][72]
  __shared__ float rs[256], rq[256];
  __shared__ float s_mu, s_rstd;
  f16 (*s_a)[120]  = (f16(*)[120])s_u;
  f16 (*s_bh)[120] = (f16(*)[120])(s_u + 48 * 120);
  f16 (*s_t)[72]   = (f16(*)[72])s_u;
  f16 (*s_bw)[72]  = (f16(*)[72])(s_u + 128 * 72);
  int bc = blockIdx.x, tid = threadIdx.x;

  for (int l = tid; l < 1152; l += 256) {
    int kx = l / 24, ky = l - kx * 24;
    float2 y = Yf2[bc * NMODE + l];
    s_a[2 * ky][kx]          = (f16)y.x;
    s_a[2 * ky][48 + kx]     = (f16)(-y.y);
    s_a[2 * ky + 1][kx]      = (f16)y.y;
    s_a[2 * ky + 1][48 + kx] = (f16)y.x;
  }
  for (int l = tid; l < 1536; l += 256) {
    int r = l / 12, c = l - r * 12;
    *(f16x8*)&s_bh[r][c * 8] = *(const f16x8*)(Bh_t + r * 96 + c * 8);
  }
  __syncthreads();
  int wave = tid >> 6, lane = tid & 63, lr = lane & 15, lg = lane >> 4;

  // GEMM-A: T[m'][h] = sum_k a[m'][k] * Bh[k][h]; M=48 N=128 K=96
  f32x4 acc_a[6];
#pragma unroll
  for (int i = 0; i < 6; ++i) acc_a[i] = (f32x4){0.f, 0.f, 0.f, 0.f};
#pragma unroll
  for (int i = 0; i < 6; ++i) {
    int t = wave + 4 * i;
    int mt = t >> 3, nt = t & 7;
#pragma unroll
    for (int ks = 0; ks < 3; ++ks) {
      f16x8 a = *(const f16x8*)&s_a[mt * 16 + lr][ks * 32 + lg * 8];
      f16x8 b = *(const f16x8*)&s_bh[nt * 16 + lr][ks * 32 + lg * 8];
      acc_a[i] = __builtin_amdgcn_mfma_f32_16x16x32_f16(a, b, acc_a[i], 0, 0, 0);
    }
  }
  __syncthreads();
  // write T^T into s_t ; zero pad cols 48..63 ; stage Bw
#pragma unroll
  for (int i = 0; i < 6; ++i) {
    int t = wave + 4 * i;
    int mt = t >> 3, nt = t & 7;
    int h = nt * 16 + lr;
    int m0 = mt * 16 + lg * 4;
#pragma unroll
    for (int r = 0; r < 4; ++r) s_t[h][m0 + r] = (f16)acc_a[i][r];
  }
  for (int l = tid; l < 2048; l += 256) {
    int h = l >> 4, c = 48 + (l & 15);
    s_t[h][c] = (f16)0.f;
  }
  for (int l = tid; l < 1024; l += 256) {
    int r = l >> 3, c = l & 7;
    *(f16x8*)&s_bw[r][c * 8] = *(const f16x8*)(Bw_t + r * 64 + c * 8);
  }
  __syncthreads();

  // GEMM-B: y_spec[h][w] = sum_k t[h][k] * Bw[k][w]; M=128 N=128 K=64
  f32x4 acc_b[2][8] = {};
#pragma unroll
  for (int ks = 0; ks < 2; ++ks) {
    f16x8 a[2], b[8];
#pragma unroll
    for (int mm = 0; mm < 2; ++mm) a[mm] = *(const f16x8*)&s_t[(wave * 2 + mm) * 16 + lr][ks * 32 + lg * 8];
#pragma unroll
    for (int nt = 0; nt < 8; ++nt) b[nt] = *(const f16x8*)&s_bw[nt * 16 + lr][ks * 32 + lg * 8];
#pragma unroll
    for (int mm = 0; mm < 2; ++mm)
#pragma unroll
      for (int nt = 0; nt < 8; ++nt)
        acc_b[mm][nt] = __builtin_amdgcn_mfma_f32_16x16x32_f16(a[mm], b[nt], acc_b[mm][nt], 0, 0, 0);
  }
  // epilogue: v = y_spec/16384 + yh ; instnorm stats
  float sum = 0.f, ssq = 0.f;
#pragma unroll
  for (int mm = 0; mm < 2; ++mm)
#pragma unroll
    for (int nt = 0; nt < 8; ++nt)
#pragma unroll
      for (int r = 0; r < 4; ++r) {
        int h = (wave * 2 + mm) * 16 + lg * 4 + r;
        int w = nt * 16 + lr;
        float v = acc_b[mm][nt][r] * (1.f / 16384.f) + (float)yh[(size_t)bc * HWC + h * 128 + w];
        acc_b[mm][nt][r] = v;
        sum += v; ssq = fmaf(v, v, ssq);
      }
  rs[tid] = sum; rq[tid] = ssq;
  __syncthreads();
  for (int sft = 128; sft > 0; sft >>= 1) {
    if (tid < sft) { rs[tid] += rs[tid + sft]; rq[tid] += rq[tid + sft]; }
    __syncthreads();
  }
  if (tid == 0) {
    float mu = rs[0] * (1.f / 16384.f);
    float var = fmaxf(rq[0] * (1.f / 16384.f) - mu * mu, 0.f);
    s_mu = mu;
    s_rstd = rsqrtf(var + 1e-5f);
  }
  __syncthreads();
  float mu = s_mu, rstd = s_rstd;
#pragma unroll
  for (int mm = 0; mm < 2; ++mm)
#pragma unroll
    for (int nt = 0; nt < 8; ++nt)
#pragma unroll
      for (int r = 0; r < 4; ++r) {
        int h = (wave * 2 + mm) * 16 + lg * 4 + r;
        int w = nt * 16 + lr;
        Gh[(size_t)bc * HWC + h * 128 + w] = (f16)gelu_f((acc_b[mm][nt][r] - mu) * rstd);
      }
}

// ---------------- transpose final grid: Gh[b*64+c][cell] -> Gp[b*16384+cell][c] ----------------
__global__ __launch_bounds__(256) void k_tr(const f16* __restrict__ Gh, f16* __restrict__ Gp)
{
  __shared__ f16 t[64][264];
  int b = blockIdx.x >> 6, cell0 = (blockIdx.x & 63) * 256, tid = threadIdx.x;
  for (int l = tid; l < 2048; l += 256) {
    int c = l >> 5, q = l & 31;
    *(f16x8*)&t[c][q * 8] = *(const f16x8*)(Gh + (size_t)(b * 64 + c) * HWC + cell0 + q * 8);
  }
  __syncthreads();
  int cell = tid;
  f16* dst = Gp + ((size_t)b * HWC + cell0 + cell) * 64;
#pragma unroll
  for (int q = 0; q < 8; ++q) {
    f16x8 v;
#pragma unroll
    for (int j = 0; j < 8; ++j) v[j] = t[q * 8 + j][cell];
    *(f16x8*)(dst + q * 8) = v;
  }
}

// ---------------- gather: bilinear sample channel-last grid (sorted points) ----------------
__global__ __launch_bounds__(256) void k_gather(const f16* __restrict__ Gp,
                                                const int4* __restrict__ pds,
                                                f16* __restrict__ smp)
{
  int spt = blockIdx.x * 256 + threadIdx.x;
  int4 rec = pds[spt];
  int pid = rec.x;
  int b = pid >> 14;
  int h0 = rec.y & 255, w0 = (rec.y >> 8) & 255;
  int h1 = min(h0 + 1, 127), w1 = min(w0 + 1, 127);
  float th = __int_as_float(rec.z), tw = __int_as_float(rec.w);
  float w00 = (1.f - th) * (1.f - tw), w01 = (1.f - th) * tw;
  float w10 = th * (1.f - tw), w11 = th * tw;
  const f16* base = Gp + ((size_t)b << 14) * 64;
  const f16* g00 = base + (h0 * 128 + w0) * 64;
  const f16* g01 = base + (h0 * 128 + w1) * 64;
  const f16* g10 = base + (h1 * 128 + w0) * 64;
  const f16* g11 = base + (h1 * 128 + w1) * 64;
  f16* dst = smp + (size_t)spt * 64;
#pragma unroll
  for (int c8 = 0; c8 < 8; ++c8) {
    f16x8 a = *(const f16x8*)(g00 + c8 * 8);
    f16x8 b2 = *(const f16x8*)(g01 + c8 * 8);
    f16x8 c = *(const f16x8*)(g10 + c8 * 8);
    f16x8 d = *(const f16x8*)(g11 + c8 * 8);
    f16x8 o;
#pragma unroll
    for (int j = 0; j < 8; ++j)
      o[j] = (f16)(w00 * (float)a[j] + w01 * (float)b2[j] + w10 * (float)c[j] + w11 * (float)d[j]);
    *(f16x8*)(dst + c8 * 8) = o;
  }
}

// ---------------- projection MLP via MFMA: smp[128pts][64] @ p1[64][128] -> gelu -> @ p2 ----------------
__global__ __launch_bounds__(256) void k_mlp(const f16* __restrict__ smp,
                                             const int4* __restrict__ pds,
                                             const float* __restrict__ p1w, const float* __restrict__ p1b,
                                             const float* __restrict__ p2w, const float* __restrict__ p2b,
                                             float* __restrict__ out)
{
  __shared__ f16 s_in[128][72];
  __shared__ f16 s_p1[128][72];   // [j][i]
  __shared__ float s_b1[128], s_p2[128];
  int blk = blockIdx.x, tid = threadIdx.x;
  for (int l = tid; l < 1024; l += 256) {
    int row = l >> 3, c = l & 7;
    *(f16x8*)&s_in[row][c * 8] = *(const f16x8*)(smp + ((size_t)blk * 128 + row) * 64 + c * 8);
  }
  for (int l = tid; l < 8192; l += 256) {
    int i = l >> 7, j = l & 127;
    s_p1[j][i] = (f16)p1w[l];
  }
  if (tid < 128) { s_b1[tid] = p1b[tid]; s_p2[tid] = p2w[tid]; }
  __syncthreads();
  int wave = tid >> 6, lane = tid & 63, lr = lane & 15, lg = lane >> 4;
  f32x4 acc[2][8] = {};
#pragma unroll
  for (int ks = 0; ks < 2; ++ks) {
    f16x8 a[2], b[8];
#pragma unroll
    for (int mm = 0; mm < 2; ++mm) a[mm] = *(const f16x8*)&s_in[(wave * 2 + mm) * 16 + lr][ks * 32 + lg * 8];
#pragma unroll
    for (int nt = 0; nt < 8; ++nt) b[nt] = *(const f16x8*)&s_p1[nt * 16 + lr][ks * 32 + lg * 8];
#pragma unroll
    for (int mm = 0; mm < 2; ++mm)
#pragma unroll
      for (int nt = 0; nt < 8; ++nt)
        acc[mm][nt] = __builtin_amdgcn_mfma_f32_16x16x32_f16(a[mm], b[nt], acc[mm][nt], 0, 0, 0);
  }
  float p2b0 = p2b[0];
  float part[2][4] = {};
#pragma unroll
  for (int mm = 0; mm < 2; ++mm)
#pragma unroll
    for (int nt = 0; nt < 8; ++nt) {
#pragma unroll
      for (int r = 0; r < 4; ++r) {
        int j = nt * 16 + lr;
        part[mm][r] += gelu_f(acc[mm][nt][r] + s_b1[j]) * s_p2[j];
      }
    }
#pragma unroll
  for (int mm = 0; mm < 2; ++mm)
#pragma unroll
    for (int r = 0; r < 4; ++r) {
      float v = part[mm][r];
      v += __shfl_xor(v, 1, 16);
      v += __shfl_xor(v, 2, 16);
      v += __shfl_xor(v, 4, 16);
      v += __shfl_xor(v, 8, 16);
      if (lr == 0) {
        int pt = (wave * 2 + mm) * 16 + lg * 4 + r;
        int opid = pds[blk * 128 + pt].x;
        out[opid] = v + p2b0;
      }
    }
}

extern "C" void kernel_launch(void* const* d_in, const int* in_sizes, int n_in,
                              void* d_out, int out_size, void* d_ws, size_t ws_size,
                              hipStream_t stream) {
  const float* coords = (const float*)d_in[0];
  const float* feats  = (const float*)d_in[1];
  const float* dw0 = (const float*)d_in[2];
  const float* db0 = (const float*)d_in[3];
  const float* dw1 = (const float*)d_in[4];
  const float* db1 = (const float*)d_in[5];
  const float* dw2 = (const float*)d_in[6];
  const float* db2 = (const float*)d_in[7];
  const float* liftw = (const float*)d_in[8];
  const float* liftb = (const float*)d_in[9];
  const float* sw1r = (const float*)d_in[10];
  const float* sw1i = (const float*)d_in[11];
  const float* sw2r = (const float*)d_in[12];
  const float* sw2i = (const float*)d_in[13];
  const float* pww = (const float*)d_in[14];
  const float* pwb = (const float*)d_in[15];
  const float* p1w = (const float*)d_in[16];
  const float* p1b = (const float*)d_in[17];
  const float* p2w = (const float*)d_in[18];
  const float* p2b = (const float*)d_in[19];
  float* out = (float*)d_out;
  char* base = (char*)d_ws;

  float*  sums5  = (float*)(base + 0);          // 2,621,440 B
  int*    cnt_i  = (int*)(base + 2621440);      // 524,288 B
  int*    ptrank = (int*)(base + 3145728);
  int*    pd_cell= (int*)(base + 3670016);
  int*    starts = (int*)(base + 4194304);
  int*    btot   = (int*)(base + 4718592);
  int*    boff   = (int*)(base + 4719616);
  int*    pd_idx = (int*)(base + 4720640);
  float*  pd_th  = (float*)(base + 5244928);
  float*  pd_tw  = (float*)(base + 5769216);
  f16*    Gh     = (f16*)(base + 8388608);      // 16,777,216 B
  f16*    yh     = (f16*)(base + 25165824);     // 16,777,216 B
  float2* Xf2    = (float2*)(base + 41943040);  // 4,718,592 B
  float2* Yf2    = (float2*)(base + 46661632);  // 4,718,592 B
  int4*   pds    = (int4*)(base + 51380224);    // 2,097,152 B
  f16*    Gp     = (f16*)(base + 53477376);     // 16,777,216 B
  f16*    smp    = (f16*)(base + 70254592);     // 16,777,216 B
  f16*    Fw_t   = (f16*)(base + 87031808);     // 12,288 B
  f16*    Fh_t   = (f16*)(base + 87044096);     // 24,576 B
  f16*    Bh_t   = (f16*)(base + 87068672);     // 24,576 B
  f16*    Bw_t   = (f16*)(base + 87093248);     // 16,384 B

  hipMemsetAsync(sums5, 0, 3145728, stream);

  k_twiddle<<<104, 256, 0, stream>>>(Fw_t, Fh_t, Bh_t, Bw_t);
  k_points<<<512, 256, 0, stream>>>(coords, feats, dw0, db0, dw1, db1, dw2, db2,
                                    sums5, cnt_i, ptrank, pd_cell, pd_idx, pd_th, pd_tw);
  k_scanA<<<256, 256, 0, stream>>>(cnt_i, starts, btot);
  k_scanB<<<1, 256, 0, stream>>>(btot, boff);
  k_perm<<<512, 256, 0, stream>>>(pd_cell, ptrank, starts, boff, pd_idx, pd_th, pd_tw, pds);
  k_gridlift<<<dim3(128, 8), 256, 0, stream>>>(sums5, cnt_i, liftw, liftb, Gh);

  for (int d = 0; d < 4; ++d) {
    const int swoff = d * 2359296;
    k_fwd<<<512, 256, 0, stream>>>(Gh, Fw_t, Fh_t, Xf2);
    k_mix<<<dim3(9, 16, 2), 256, 0, stream>>>(Xf2, sw1r + swoff, sw1i + swoff,
                                              sw2r + swoff, sw2i + swoff, Yf2);
    k_pw<<<dim3(64, 8), 256, 0, stream>>>(Gh, pww + d * 4096, pwb + d * 64, yh);
    k_inv<<<512, 256, 0, stream>>>(Yf2, Bh_t, Bw_t, yh, Gh);
  }

  k_tr<<<512, 256, 0, stream>>>(Gh, Gp);
  k_gather<<<512, 256, 0, stream>>>(Gp, pds, smp);
  k_mlp<<<1024, 256, 0, stream>>>(smp, pds, p1w, p1b, p2w, p2b, out);
}

// Round 6
// 471.772 us; speedup vs baseline: 2.6399x; 1.0678x over previous
//
#include <hip/hip_runtime.h>
#include <math.h>

#define GH 128
#define GW 128
#define HWC 16384
#define NMODE 1152
#define PI_F 3.14159265358979323846f

typedef _Float16 f16;
typedef __attribute__((ext_vector_type(8))) _Float16 f16x8;
typedef __attribute__((ext_vector_type(4))) float f32x4;

__device__ __forceinline__ float gelu_f(float x) {
  return 0.5f * x * (1.0f + erff(x * 0.70710678118654752f));
}

// ---------------- twiddle tables (f16, integer-exact angles) ----------------
__global__ __launch_bounds__(256) void k_twiddle(f16* __restrict__ Fw, f16* __restrict__ Fh,
                                                 f16* __restrict__ Bh, f16* __restrict__ Bw)
{
  int idx = blockIdx.x * 256 + threadIdx.x;
  if (idx < 6144) {
    int n = idx >> 7, w = idx & 127;
    int ky = n >> 1;
    int ang = (ky * w) & 127;
    float s, c; sincosf((float)ang * (PI_F / 64.f), &s, &c);
    Fw[idx] = (f16)((n & 1) ? -s : c);
  } else if (idx < 18432) {
    int t = idx - 6144;
    int n = t >> 7, h = t & 127;
    int kx = n < 48 ? n : n - 48;
    int f = kx < 24 ? kx : kx + 80;
    int ang = (f * h) & 127;
    float s, c; sincosf((float)ang * (PI_F / 64.f), &s, &c);
    float v = (n < 48) ? c : s;
    Fh[t] = (f16)v;
    Bh[h * 96 + n] = (f16)v;
  } else if (idx < 26624) {
    int t = idx - 18432;
    int w = t >> 6, k = t & 63;
    float v = 0.f;
    if (k < 48 && k != 1) {
      int ky = k >> 1;
      float g = (ky == 0) ? 1.f : 2.f;
      int ang = (ky * w) & 127;
      float s, c; sincosf((float)ang * (PI_F / 64.f), &s, &c);
      v = (k & 1) ? -g * s : g * c;
    }
    Bw[t] = (f16)v;
  }
}

// ---------------- points: deform MLP (scalar-weight GEMV, f32) + scatter + bilinear data ----------------
__global__ __launch_bounds__(256) void k_points(
    const float* __restrict__ coords, const float* __restrict__ feats,
    const float* __restrict__ dw0, const float* __restrict__ db0,
    const float* __restrict__ dw1, const float* __restrict__ db1,
    const float* __restrict__ dw2, const float* __restrict__ db2,
    float* __restrict__ sums5, int* __restrict__ cnt_i,
    int* __restrict__ ptrank, int* __restrict__ pd_cell,
    int* __restrict__ pd_idx, float* __restrict__ pd_th, float* __restrict__ pd_tw)
{
  int pid = blockIdx.x * 256 + threadIdx.x;
  float2 c = ((const float2*)coords)[pid];

  // layer 1: h1[j] = gelu(cx*W[0][j] + cy*W[1][j] + b[j])  (weights: uniform scalar loads)
  float h1[32];
#pragma unroll
  for (int j = 0; j < 32; ++j)
    h1[j] = gelu_f(fmaf(c.x, dw0[j], fmaf(c.y, dw0[32 + j], db0[j])));

  // layer 2: a[j] = b1[j] + sum_k h1[k] * W1[k][j]  (32 independent accumulators)
  float a[32];
#pragma unroll
  for (int j = 0; j < 32; ++j) a[j] = db1[j];
#pragma unroll 4
  for (int k = 0; k < 32; ++k) {
    float hk = h1[k];
    const float* wr = dw1 + k * 32;
#pragma unroll
    for (int j = 0; j < 32; ++j) a[j] = fmaf(hk, wr[j], a[j]);
  }

  // layer 3: d = b2 + sum_k gelu(a[k]) * W2[k][:]
  float d0 = db2[0], d1 = db2[1];
#pragma unroll 4
  for (int k = 0; k < 32; ++k) {
    float hk = gelu_f(a[k]);
    d0 = fmaf(hk, dw2[2 * k], d0);
    d1 = fmaf(hk, dw2[2 * k + 1], d1);
  }

  float l0 = fminf(fmaxf(c.x + d0, -1.f), 1.f);
  float l1 = fminf(fmaxf(c.y + d1, -1.f), 1.f);
  float ph = (l0 + 1.f) * 0.5f * 127.f;
  float pw = (l1 + 1.f) * 0.5f * 127.f;
  int ih = min(max((int)rintf(ph), 0), 127);
  int iw = min(max((int)rintf(pw), 0), 127);
  int b = pid >> 14;
  int cell = b * HWC + ih * GW + iw;

  float f0 = feats[pid * 3], f1 = feats[pid * 3 + 1], f2 = feats[pid * 3 + 2];
  float* srow = sums5 + (size_t)cell * 5;
  atomicAdd(srow + 0, f0);
  atomicAdd(srow + 1, f1);
  atomicAdd(srow + 2, f2);
  atomicAdd(srow + 3, c.x);
  atomicAdd(srow + 4, c.y);
  int r = atomicAdd(&cnt_i[cell], 1);
  ptrank[pid] = r;
  pd_cell[pid] = cell;

  float fh = floorf(ph), fw = floorf(pw);
  int h0i = min(max((int)fh, 0), 127), w0i = min(max((int)fw, 0), 127);
  pd_idx[pid] = h0i | (w0i << 8);
  pd_th[pid] = ph - fh;
  pd_tw[pid] = pw - fw;
}

// ---------------- scans + permute ----------------
__global__ __launch_bounds__(256) void k_scanA(const int* __restrict__ cnt,
                                               int* __restrict__ starts, int* __restrict__ btot)
{
  __shared__ int sh[256];
  int blk = blockIdx.x, t = threadIdx.x;
  int base = blk * 512;
  int v0 = cnt[base + 2 * t], v1 = cnt[base + 2 * t + 1];
  int pair = v0 + v1;
  sh[t] = pair; __syncthreads();
  int acc = pair;
  for (int off = 1; off < 256; off <<= 1) {
    int add = (t >= off) ? sh[t - off] : 0;
    __syncthreads();
    acc += add; sh[t] = acc;
    __syncthreads();
  }
  int excl = acc - pair;
  starts[base + 2 * t] = excl;
  starts[base + 2 * t + 1] = excl + v0;
  if (t == 255) btot[blk] = acc;
}

__global__ __launch_bounds__(256) void k_scanB(const int* __restrict__ btot, int* __restrict__ boff)
{
  __shared__ int sh[256];
  int t = threadIdx.x;
  int v = btot[t];
  sh[t] = v; __syncthreads();
  int acc = v;
  for (int off = 1; off < 256; off <<= 1) {
    int add = (t >= off) ? sh[t - off] : 0;
    __syncthreads();
    acc += add; sh[t] = acc;
    __syncthreads();
  }
  boff[t] = acc - v;
}

__global__ __launch_bounds__(256) void k_perm(const int* __restrict__ pd_cell, const int* __restrict__ ptrank,
                                              const int* __restrict__ starts, const int* __restrict__ boff,
                                              const int* __restrict__ pd_idx, const float* __restrict__ pd_th,
                                              const float* __restrict__ pd_tw, int4* __restrict__ pds)
{
  int pid = blockIdx.x * 256 + threadIdx.x;
  int cell = pd_cell[pid];
  int dst = starts[cell] + boff[cell >> 9] + ptrank[pid];
  int4 rec;
  rec.x = pid;
  rec.y = pd_idx[pid];
  rec.z = __float_as_int(pd_th[pid]);
  rec.w = __float_as_int(pd_tw[pid]);
  pds[dst] = rec;
}

// ---------------- scatter-mean + lift -> Gh (f16, channel-major) ----------------
__global__ __launch_bounds__(256) void k_gridlift(const float* __restrict__ sums5,
                                                  const int* __restrict__ cnt_i,
                                                  const float* __restrict__ lw,
                                                  const float* __restrict__ lb,
                                                  f16* __restrict__ Gh)
{
  __shared__ float s5[128][5];
  __shared__ float s_lw[5][64];
  __shared__ float s_lb[64];
  int b = blockIdx.y, cbase = blockIdx.x * 128, tid = threadIdx.x;
  for (int l = tid; l < 640; l += 256) ((float*)s5)[l] = sums5[(size_t)(b * HWC + cbase) * 5 + l];
  for (int l = tid; l < 320; l += 256) ((float*)s_lw)[l] = lw[l];
  if (tid < 64) s_lb[tid] = lb[tid];
  __syncthreads();
  int cl = tid & 127, oh = tid >> 7;
  float v0 = s5[cl][0], v1 = s5[cl][1], v2 = s5[cl][2], v3 = s5[cl][3], v4 = s5[cl][4];
  float cnt = (float)cnt_i[b * HWC + cbase + cl];
  float inv = 1.f / fmaxf(cnt, 1.f);
#pragma unroll
  for (int j = 0; j < 32; ++j) {
    int o = oh * 32 + j;
    float val = cnt * s_lb[o];
    val = fmaf(v0, s_lw[0][o], val);
    val = fmaf(v1, s_lw[1][o], val);
    val = fmaf(v2, s_lw[2][o], val);
    val = fmaf(v3, s_lw[3][o], val);
    val = fmaf(v4, s_lw[4][o], val);
    Gh[(size_t)(b * 64 + o) * HWC + cbase + cl] = (f16)(val * inv);
  }
}

// ---------------- forward DFT (two fused MFMA GEMMs): Gh(bc,H,W) -> Xf2(bc,1152) ----------------
__global__ __launch_bounds__(256) void k_fwd(const f16* __restrict__ Gh,
                                             const f16* __restrict__ Fw_t, const f16* __restrict__ Fh_t,
                                             float2* __restrict__ Xf2)
{
  __shared__ f16 s_fw[48][136];
  __shared__ f16 s_u[19584];   // union: phase1 img[128][136]; phase2 xw[48][136] + fh[96][136]
  f16 (*s_img)[136] = (f16(*)[136])s_u;
  f16 (*s_xw)[136]  = (f16(*)[136])s_u;
  f16 (*s_fh)[136]  = (f16(*)[136])(s_u + 48 * 136);
  int bc = blockIdx.x, tid = threadIdx.x;
  for (int l = tid; l < 2048; l += 256) {
    int r = l >> 4, c = l & 15;
    *(f16x8*)&s_img[r][c * 8] = *(const f16x8*)(Gh + (size_t)bc * HWC + r * 128 + c * 8);
  }
  for (int l = tid; l < 768; l += 256) {
    int r = l >> 4, c = l & 15;
    *(f16x8*)&s_fw[r][c * 8] = *(const f16x8*)(Fw_t + r * 128 + c * 8);
  }
  __syncthreads();
  int wave = tid >> 6, lane = tid & 63, lr = lane & 15, lg = lane >> 4;

  // GEMM1: Xw[h][n] = sum_w img[h][w] * Fw[w][n]; M=128 N=48 K=128
  f32x4 acc1[2][3] = {};
#pragma unroll
  for (int ks = 0; ks < 4; ++ks) {
    f16x8 a[2], b[3];
#pragma unroll
    for (int mm = 0; mm < 2; ++mm) a[mm] = *(const f16x8*)&s_img[(wave * 2 + mm) * 16 + lr][ks * 32 + lg * 8];
#pragma unroll
    for (int nt = 0; nt < 3; ++nt) b[nt] = *(const f16x8*)&s_fw[nt * 16 + lr][ks * 32 + lg * 8];
#pragma unroll
    for (int mm = 0; mm < 2; ++mm)
#pragma unroll
      for (int nt = 0; nt < 3; ++nt)
        acc1[mm][nt] = __builtin_amdgcn_mfma_f32_16x16x32_f16(a[mm], b[nt], acc1[mm][nt], 0, 0, 0);
  }
  __syncthreads();
  // write Xw^T into s_xw ; stage Fh
#pragma unroll
  for (int mm = 0; mm < 2; ++mm)
#pragma unroll
    for (int nt = 0; nt < 3; ++nt) {
      int n = nt * 16 + lr;
      int h0 = (wave * 2 + mm) * 16 + lg * 4;
#pragma unroll
      for (int r = 0; r < 4; ++r) s_xw[n][h0 + r] = (f16)acc1[mm][nt][r];
    }
  for (int l = tid; l < 1536; l += 256) {
    int r = l >> 4, c = l & 15;
    *(f16x8*)&s_fh[r][c * 8] = *(const f16x8*)(Fh_t + r * 128 + c * 8);
  }
  __syncthreads();

  // GEMM2: P[m'][n] = sum_h xw[m'][h] * Fh[h][n]; M=48 N=96 K=128
  for (int u = wave; u < 9; u += 4) {
    int mt = u / 3, ntC = u - mt * 3;
    f32x4 accC = {}, accS = {};
#pragma unroll
    for (int ks = 0; ks < 4; ++ks) {
      f16x8 a  = *(const f16x8*)&s_xw[mt * 16 + lr][ks * 32 + lg * 8];
      f16x8 bC = *(const f16x8*)&s_fh[ntC * 16 + lr][ks * 32 + lg * 8];
      f16x8 bS = *(const f16x8*)&s_fh[(ntC + 3) * 16 + lr][ks * 32 + lg * 8];
      accC = __builtin_amdgcn_mfma_f32_16x16x32_f16(a, bC, accC, 0, 0, 0);
      accS = __builtin_amdgcn_mfma_f32_16x16x32_f16(a, bS, accS, 0, 0, 0);
    }
    int kx = ntC * 16 + lr;
    int ky0 = (mt * 16 + lg * 4) >> 1;
    Xf2[bc * NMODE + kx * 24 + ky0]     = make_float2(accC[0] + accS[1], accC[1] - accS[0]);
    Xf2[bc * NMODE + kx * 24 + ky0 + 1] = make_float2(accC[2] + accS[3], accC[3] - accS[2]);
  }
}

// ---------------- per-mode 64x64 complex channel mix (f32 VALU, weight-stream-bound) ----------------
// 128 threads: (64 m-lanes) x (2 o-slots); o-range 2 per block; grid (9, 32, 2) = 576 blocks
__global__ __launch_bounds__(128) void k_mix(const float2* __restrict__ Xf2,
    const float* __restrict__ w1r, const float* __restrict__ w1i,
    const float* __restrict__ w2r, const float* __restrict__ w2i,
    float2* __restrict__ Yf2)
{
  int m = blockIdx.x * 64 + (threadIdx.x & 63);
  int o = blockIdx.y * 2 + (threadIdx.x >> 6);
  int half = blockIdx.z;
  int gm = half * 576 + m;
  const float* wr_ = half ? w2r : w1r;
  const float* wi_ = half ? w2i : w1i;
  float aR[8] = {}, aI[8] = {};
#pragma unroll 2
  for (int i = 0; i < 64; ++i) {
    int widx = (i * 64 + o) * 576 + m;
    float wr = wr_[widx], wi = wi_[widx];
#pragma unroll
    for (int b = 0; b < 8; ++b) {
      float2 x = Xf2[(b * 64 + i) * NMODE + gm];
      aR[b] = fmaf(x.x, wr, aR[b]); aR[b] = fmaf(-x.y, wi, aR[b]);
      aI[b] = fmaf(x.x, wi, aI[b]); aI[b] = fmaf(x.y, wr, aI[b]);
    }
  }
#pragma unroll
  for (int b = 0; b < 8; ++b)
    Yf2[(b * 64 + o) * NMODE + gm] = make_float2(aR[b], aI[b]);
}

// ---------------- pointwise conv via MFMA f16 ----------------
__global__ __launch_bounds__(256) void k_pw(const f16* __restrict__ Gh,
                                            const float* __restrict__ pww,
                                            const float* __restrict__ pwb,
                                            f16* __restrict__ yh)
{
  __shared__ f16 gt[256][72];   // [p][i]
  __shared__ f16 wt[64][72];    // [o][i]
  __shared__ float s_b[64];
  int b = blockIdx.y, p0 = blockIdx.x * 256, tid = threadIdx.x;
  for (int l = tid; l < 4096; l += 256) {
    int i = l >> 6, o = l & 63;
    wt[o][i] = (f16)pww[l];
  }
  if (tid < 64) s_b[tid] = pwb[tid];
  for (int l = tid; l < 2048; l += 256) {
    int i = l >> 5, pc = (l & 31) * 8;
    f16x8 v = *(const f16x8*)(Gh + (size_t)(b * 64 + i) * HWC + p0 + pc);
#pragma unroll
    for (int j = 0; j < 8; ++j) gt[pc + j][i] = v[j];
  }
  __syncthreads();
  int wave = tid >> 6, lane = tid & 63;
  int lr = lane & 15, lg = lane >> 4;
  int pw_ = wave * 64;
  f32x4 acc[4][4] = {};
#pragma unroll
  for (int kk = 0; kk < 2; ++kk) {
    f16x8 a[4], bb[4];
#pragma unroll
    for (int mi = 0; mi < 4; ++mi) a[mi] = *(const f16x8*)&wt[16 * mi + lr][kk * 32 + lg * 8];
#pragma unroll
    for (int ni = 0; ni < 4; ++ni) bb[ni] = *(const f16x8*)&gt[pw_ + 16 * ni + lr][kk * 32 + lg * 8];
#pragma unroll
    for (int mi = 0; mi < 4; ++mi)
#pragma unroll
      for (int ni = 0; ni < 4; ++ni)
        acc[mi][ni] = __builtin_amdgcn_mfma_f32_16x16x32_f16(a[mi], bb[ni], acc[mi][ni], 0, 0, 0);
  }
#pragma unroll
  for (int mi = 0; mi < 4; ++mi)
#pragma unroll
    for (int ni = 0; ni < 4; ++ni) {
#pragma unroll
      for (int r = 0; r < 4; ++r) {
        int o = 16 * mi + lg * 4 + r;
        int p = p0 + pw_ + 16 * ni + lr;
        yh[(size_t)(b * 64 + o) * HWC + p] = (f16)(acc[mi][ni][r] + s_b[o]);
      }
    }
}

// ---------------- inverse DFT (two fused MFMA GEMMs) + add + instnorm + gelu ----------------
__global__ __launch_bounds__(256) void k_inv(const float2* __restrict__ Yf2,
                                             const f16* __restrict__ Bh_t, const f16* __restrict__ Bw_t,
                                             const f16* __restrict__ yh, f16* __restrict__ Gh)
{
  __shared__ f16 s_u[21120];   // phase1: a[48][120] + bh[128][120] ; phase2: t[128][72] + bw[128][72]
  __shared__ float rs[256], rq[256];
  __shared__ float s_mu, s_rstd;
  f16 (*s_a)[120]  = (f16(*)[120])s_u;
  f16 (*s_bh)[120] = (f16(*)[120])(s_u + 48 * 120);
  f16 (*s_t)[72]   = (f16(*)[72])s_u;
  f16 (*s_bw)[72]  = (f16(*)[72])(s_u + 128 * 72);
  int bc = blockIdx.x, tid = threadIdx.x;

  for (int l = tid; l < 1152; l += 256) {
    int kx = l / 24, ky = l - kx * 24;
    float2 y = Yf2[bc * NMODE + l];
    s_a[2 * ky][kx]          = (f16)y.x;
    s_a[2 * ky][48 + kx]     = (f16)(-y.y);
    s_a[2 * ky + 1][kx]      = (f16)y.y;
    s_a[2 * ky + 1][48 + kx] = (f16)y.x;
  }
  for (int l = tid; l < 1536; l += 256) {
    int r = l / 12, c = l - r * 12;
    *(f16x8*)&s_bh[r][c * 8] = *(const f16x8*)(Bh_t + r * 96 + c * 8);
  }
  __syncthreads();
  int wave = tid >> 6, lane = tid & 63, lr = lane & 15, lg = lane >> 4;

  // GEMM-A: T[m'][h] = sum_k a[m'][k] * Bh[k][h]; M=48 N=128 K=96
  f32x4 acc_a[6];
#pragma unroll
  for (int i = 0; i < 6; ++i) acc_a[i] = (f32x4){0.f, 0.f, 0.f, 0.f};
#pragma unroll
  for (int i = 0; i < 6; ++i) {
    int t = wave + 4 * i;
    int mt = t >> 3, nt = t & 7;
#pragma unroll
    for (int ks = 0; ks < 3; ++ks) {
      f16x8 a = *(const f16x8*)&s_a[mt * 16 + lr][ks * 32 + lg * 8];
      f16x8 b = *(const f16x8*)&s_bh[nt * 16 + lr][ks * 32 + lg * 8];
      acc_a[i] = __builtin_amdgcn_mfma_f32_16x16x32_f16(a, b, acc_a[i], 0, 0, 0);
    }
  }
  __syncthreads();
#pragma unroll
  for (int i = 0; i < 6; ++i) {
    int t = wave + 4 * i;
    int mt = t >> 3, nt = t & 7;
    int h = nt * 16 + lr;
    int m0 = mt * 16 + lg * 4;
#pragma unroll
    for (int r = 0; r < 4; ++r) s_t[h][m0 + r] = (f16)acc_a[i][r];
  }
  for (int l = tid; l < 2048; l += 256) {
    int h = l >> 4, c = 48 + (l & 15);
    s_t[h][c] = (f16)0.f;
  }
  for (int l = tid; l < 1024; l += 256) {
    int r = l >> 3, c = l & 7;
    *(f16x8*)&s_bw[r][c * 8] = *(const f16x8*)(Bw_t + r * 64 + c * 8);
  }
  __syncthreads();

  // GEMM-B: y_spec[h][w] = sum_k t[h][k] * Bw[k][w]; M=128 N=128 K=64
  f32x4 acc_b[2][8] = {};
#pragma unroll
  for (int ks = 0; ks < 2; ++ks) {
    f16x8 a[2], b[8];
#pragma unroll
    for (int mm = 0; mm < 2; ++mm) a[mm] = *(const f16x8*)&s_t[(wave * 2 + mm) * 16 + lr][ks * 32 + lg * 8];
#pragma unroll
    for (int nt = 0; nt < 8; ++nt) b[nt] = *(const f16x8*)&s_bw[nt * 16 + lr][ks * 32 + lg * 8];
#pragma unroll
    for (int mm = 0; mm < 2; ++mm)
#pragma unroll
      for (int nt = 0; nt < 8; ++nt)
        acc_b[mm][nt] = __builtin_amdgcn_mfma_f32_16x16x32_f16(a[mm], b[nt], acc_b[mm][nt], 0, 0, 0);
  }
  float sum = 0.f, ssq = 0.f;
#pragma unroll
  for (int mm = 0; mm < 2; ++mm)
#pragma unroll
    for (int nt = 0; nt < 8; ++nt)
#pragma unroll
      for (int r = 0; r < 4; ++r) {
        int h = (wave * 2 + mm) * 16 + lg * 4 + r;
        int w = nt * 16 + lr;
        float v = acc_b[mm][nt][r] * (1.f / 16384.f) + (float)yh[(size_t)bc * HWC + h * 128 + w];
        acc_b[mm][nt][r] = v;
        sum += v; ssq = fmaf(v, v, ssq);
      }
  rs[tid] = sum; rq[tid] = ssq;
  __syncthreads();
  for (int sft = 128; sft > 0; sft >>= 1) {
    if (tid < sft) { rs[tid] += rs[tid + sft]; rq[tid] += rq[tid + sft]; }
    __syncthreads();
  }
  if (tid == 0) {
    float mu = rs[0] * (1.f / 16384.f);
    float var = fmaxf(rq[0] * (1.f / 16384.f) - mu * mu, 0.f);
    s_mu = mu;
    s_rstd = rsqrtf(var + 1e-5f);
  }
  __syncthreads();
  float mu = s_mu, rstd = s_rstd;
#pragma unroll
  for (int mm = 0; mm < 2; ++mm)
#pragma unroll
    for (int nt = 0; nt < 8; ++nt)
#pragma unroll
      for (int r = 0; r < 4; ++r) {
        int h = (wave * 2 + mm) * 16 + lg * 4 + r;
        int w = nt * 16 + lr;
        Gh[(size_t)bc * HWC + h * 128 + w] = (f16)gelu_f((acc_b[mm][nt][r] - mu) * rstd);
      }
}

// ---------------- transpose final grid: Gh[b*64+c][cell] -> Gp[b*16384+cell][c] ----------------
__global__ __launch_bounds__(256) void k_tr(const f16* __restrict__ Gh, f16* __restrict__ Gp)
{
  __shared__ f16 t[64][264];
  int b = blockIdx.x >> 6, cell0 = (blockIdx.x & 63) * 256, tid = threadIdx.x;
  for (int l = tid; l < 2048; l += 256) {
    int c = l >> 5, q = l & 31;
    *(f16x8*)&t[c][q * 8] = *(const f16x8*)(Gh + (size_t)(b * 64 + c) * HWC + cell0 + q * 8);
  }
  __syncthreads();
  int cell = tid;
  f16* dst = Gp + ((size_t)b * HWC + cell0 + cell) * 64;
#pragma unroll
  for (int q = 0; q < 8; ++q) {
    f16x8 v;
#pragma unroll
    for (int j = 0; j < 8; ++j) v[j] = t[q * 8 + j][cell];
    *(f16x8*)(dst + q * 8) = v;
  }
}

// ---------------- gather: bilinear sample channel-last grid (sorted points) ----------------
__global__ __launch_bounds__(256) void k_gather(const f16* __restrict__ Gp,
                                                const int4* __restrict__ pds,
                                                f16* __restrict__ smp)
{
  int spt = blockIdx.x * 256 + threadIdx.x;
  int4 rec = pds[spt];
  int pid = rec.x;
  int b = pid >> 14;
  int h0 = rec.y & 255, w0 = (rec.y >> 8) & 255;
  int h1 = min(h0 + 1, 127), w1 = min(w0 + 1, 127);
  float th = __int_as_float(rec.z), tw = __int_as_float(rec.w);
  float w00 = (1.f - th) * (1.f - tw), w01 = (1.f - th) * tw;
  float w10 = th * (1.f - tw), w11 = th * tw;
  const f16* base = Gp + ((size_t)b << 14) * 64;
  const f16* g00 = base + (h0 * 128 + w0) * 64;
  const f16* g01 = base + (h0 * 128 + w1) * 64;
  const f16* g10 = base + (h1 * 128 + w0) * 64;
  const f16* g11 = base + (h1 * 128 + w1) * 64;
  f16* dst = smp + (size_t)spt * 64;
#pragma unroll
  for (int c8 = 0; c8 < 8; ++c8) {
    f16x8 a = *(const f16x8*)(g00 + c8 * 8);
    f16x8 b2 = *(const f16x8*)(g01 + c8 * 8);
    f16x8 c = *(const f16x8*)(g10 + c8 * 8);
    f16x8 d = *(const f16x8*)(g11 + c8 * 8);
    f16x8 o;
#pragma unroll
    for (int j = 0; j < 8; ++j)
      o[j] = (f16)(w00 * (float)a[j] + w01 * (float)b2[j] + w10 * (float)c[j] + w11 * (float)d[j]);
    *(f16x8*)(dst + c8 * 8) = o;
  }
}

// ---------------- projection MLP via MFMA ----------------
__global__ __launch_bounds__(256) void k_mlp(const f16* __restrict__ smp,
                                             const int4* __restrict__ pds,
                                             const float* __restrict__ p1w, const float* __restrict__ p1b,
                                             const float* __restrict__ p2w, const float* __restrict__ p2b,
                                             float* __restrict__ out)
{
  __shared__ f16 s_in[128][72];
  __shared__ f16 s_p1[128][72];   // [j][i]
  __shared__ float s_b1[128], s_p2[128];
  int blk = blockIdx.x, tid = threadIdx.x;
  for (int l = tid; l < 1024; l += 256) {
    int row = l >> 3, c = l & 7;
    *(f16x8*)&s_in[row][c * 8] = *(const f16x8*)(smp + ((size_t)blk * 128 + row) * 64 + c * 8);
  }
  for (int l = tid; l < 8192; l += 256) {
    int i = l >> 7, j = l & 127;
    s_p1[j][i] = (f16)p1w[l];
  }
  if (tid < 128) { s_b1[tid] = p1b[tid]; s_p2[tid] = p2w[tid]; }
  __syncthreads();
  int wave = tid >> 6, lane = tid & 63, lr = lane & 15, lg = lane >> 4;
  f32x4 acc[2][8] = {};
#pragma unroll
  for (int ks = 0; ks < 2; ++ks) {
    f16x8 a[2], b[8];
#pragma unroll
    for (int mm = 0; mm < 2; ++mm) a[mm] = *(const f16x8*)&s_in[(wave * 2 + mm) * 16 + lr][ks * 32 + lg * 8];
#pragma unroll
    for (int nt = 0; nt < 8; ++nt) b[nt] = *(const f16x8*)&s_p1[nt * 16 + lr][ks * 32 + lg * 8];
#pragma unroll
    for (int mm = 0; mm < 2; ++mm)
#pragma unroll
      for (int nt = 0; nt < 8; ++nt)
        acc[mm][nt] = __builtin_amdgcn_mfma_f32_16x16x32_f16(a[mm], b[nt], acc[mm][nt], 0, 0, 0);
  }
  float p2b0 = p2b[0];
  float part[2][4] = {};
#pragma unroll
  for (int mm = 0; mm < 2; ++mm)
#pragma unroll
    for (int nt = 0; nt < 8; ++nt) {
#pragma unroll
      for (int r = 0; r < 4; ++r) {
        int j = nt * 16 + lr;
        part[mm][r] += gelu_f(acc[mm][nt][r] + s_b1[j]) * s_p2[j];
      }
    }
#pragma unroll
  for (int mm = 0; mm < 2; ++mm)
#pragma unroll
    for (int r = 0; r < 4; ++r) {
      float v = part[mm][r];
      v += __shfl_xor(v, 1, 16);
      v += __shfl_xor(v, 2, 16);
      v += __shfl_xor(v, 4, 16);
      v += __shfl_xor(v, 8, 16);
      if (lr == 0) {
        int pt = (wave * 2 + mm) * 16 + lg * 4 + r;
        int opid = pds[blk * 128 + pt].x;
        out[opid] = v + p2b0;
      }
    }
}

extern "C" void kernel_launch(void* const* d_in, const int* in_sizes, int n_in,
                              void* d_out, int out_size, void* d_ws, size_t ws_size,
                              hipStream_t stream) {
  const float* coords = (const float*)d_in[0];
  const float* feats  = (const float*)d_in[1];
  const float* dw0 = (const float*)d_in[2];
  const float* db0 = (const float*)d_in[3];
  const float* dw1 = (const float*)d_in[4];
  const float* db1 = (const float*)d_in[5];
  const float* dw2 = (const float*)d_in[6];
  const float* db2 = (const float*)d_in[7];
  const float* liftw = (const float*)d_in[8];
  const float* liftb = (const float*)d_in[9];
  const float* sw1r = (const float*)d_in[10];
  const float* sw1i = (const float*)d_in[11];
  const float* sw2r = (const float*)d_in[12];
  const float* sw2i = (const float*)d_in[13];
  const float* pww = (const float*)d_in[14];
  const float* pwb = (const float*)d_in[15];
  const float* p1w = (const float*)d_in[16];
  const float* p1b = (const float*)d_in[17];
  const float* p2w = (const float*)d_in[18];
  const float* p2b = (const float*)d_in[19];
  float* out = (float*)d_out;
  char* base = (char*)d_ws;

  float*  sums5  = (float*)(base + 0);
  int*    cnt_i  = (int*)(base + 2621440);
  int*    ptrank = (int*)(base + 3145728);
  int*    pd_cell= (int*)(base + 3670016);
  int*    starts = (int*)(base + 4194304);
  int*    btot   = (int*)(base + 4718592);
  int*    boff   = (int*)(base + 4719616);
  int*    pd_idx = (int*)(base + 4720640);
  float*  pd_th  = (float*)(base + 5244928);
  float*  pd_tw  = (float*)(base + 5769216);
  f16*    Gh     = (f16*)(base + 8388608);
  f16*    yh     = (f16*)(base + 25165824);
  float2* Xf2    = (float2*)(base + 41943040);
  float2* Yf2    = (float2*)(base + 46661632);
  int4*   pds    = (int4*)(base + 51380224);
  f16*    Gp     = (f16*)(base + 53477376);
  f16*    smp    = (f16*)(base + 70254592);
  f16*    Fw_t   = (f16*)(base + 87031808);
  f16*    Fh_t   = (f16*)(base + 87044096);
  f16*    Bh_t   = (f16*)(base + 87068672);
  f16*    Bw_t   = (f16*)(base + 87093248);

  hipMemsetAsync(sums5, 0, 3145728, stream);

  k_twiddle<<<104, 256, 0, stream>>>(Fw_t, Fh_t, Bh_t, Bw_t);
  k_points<<<512, 256, 0, stream>>>(coords, feats, dw0, db0, dw1, db1, dw2, db2,
                                    sums5, cnt_i, ptrank, pd_cell, pd_idx, pd_th, pd_tw);
  k_scanA<<<256, 256, 0, stream>>>(cnt_i, starts, btot);
  k_scanB<<<1, 256, 0, stream>>>(btot, boff);
  k_perm<<<512, 256, 0, stream>>>(pd_cell, ptrank, starts, boff, pd_idx, pd_th, pd_tw, pds);
  k_gridlift<<<dim3(128, 8), 256, 0, stream>>>(sums5, cnt_i, liftw, liftb, Gh);

  for (int d = 0; d < 4; ++d) {
    const int swoff = d * 2359296;
    k_fwd<<<512, 256, 0, stream>>>(Gh, Fw_t, Fh_t, Xf2);
    k_mix<<<dim3(9, 32, 2), 128, 0, stream>>>(Xf2, sw1r + swoff, sw1i + swoff,
                                              sw2r + swoff, sw2i + swoff, Yf2);
    k_pw<<<dim3(64, 8), 256, 0, stream>>>(Gh, pww + d * 4096, pwb + d * 64, yh);
    k_inv<<<512, 256, 0, stream>>>(Yf2, Bh_t, Bw_t, yh, Gh);
  }

  k_tr<<<512, 256, 0, stream>>>(Gh, Gp);
  k_gather<<<512, 256, 0, stream>>>(Gp, pds, smp);
  k_mlp<<<1024, 256, 0, stream>>>(smp, pds, p1w, p1b, p2w, p2b, out);
}

// Round 7
// 405.869 us; speedup vs baseline: 3.0686x; 1.1624x over previous
//
#include <hip/hip_runtime.h>
#include <math.h>

#define GH 128
#define GW 128
#define HWC 16384
#define NMODE 1152
#define PI_F 3.14159265358979323846f

typedef _Float16 f16;
typedef __attribute__((ext_vector_type(8))) _Float16 f16x8;
typedef __attribute__((ext_vector_type(4))) float f32x4;

__device__ __forceinline__ float gelu_f(float x) {
  return 0.5f * x * (1.0f + erff(x * 0.70710678118654752f));
}

// ---------------- twiddle tables (f16, integer-exact angles) ----------------
__global__ __launch_bounds__(256) void k_twiddle(f16* __restrict__ Fw, f16* __restrict__ Fh,
                                                 f16* __restrict__ Bh, f16* __restrict__ Bw)
{
  int idx = blockIdx.x * 256 + threadIdx.x;
  if (idx < 6144) {
    int n = idx >> 7, w = idx & 127;
    int ky = n >> 1;
    int ang = (ky * w) & 127;
    float s, c; sincosf((float)ang * (PI_F / 64.f), &s, &c);
    Fw[idx] = (f16)((n & 1) ? -s : c);
  } else if (idx < 18432) {
    int t = idx - 6144;
    int n = t >> 7, h = t & 127;
    int kx = n < 48 ? n : n - 48;
    int f = kx < 24 ? kx : kx + 80;
    int ang = (f * h) & 127;
    float s, c; sincosf((float)ang * (PI_F / 64.f), &s, &c);
    float v = (n < 48) ? c : s;
    Fh[t] = (f16)v;
    Bh[h * 96 + n] = (f16)v;
  } else if (idx < 26624) {
    int t = idx - 18432;
    int w = t >> 6, k = t & 63;
    float v = 0.f;
    if (k < 48 && k != 1) {
      int ky = k >> 1;
      float g = (ky == 0) ? 1.f : 2.f;
      int ang = (ky * w) & 127;
      float s, c; sincosf((float)ang * (PI_F / 64.f), &s, &c);
      v = (k & 1) ? -g * s : g * c;
    }
    Bw[t] = (f16)v;
  }
}

// ---------------- points: deform MLP (f32) + rank atomic + bilinear data (NO value atomics) ----------------
__global__ __launch_bounds__(256) void k_points(
    const float* __restrict__ coords,
    const float* __restrict__ dw0, const float* __restrict__ db0,
    const float* __restrict__ dw1, const float* __restrict__ db1,
    const float* __restrict__ dw2, const float* __restrict__ db2,
    int* __restrict__ cnt_i,
    int* __restrict__ ptrank, int* __restrict__ pd_cell,
    int* __restrict__ pd_idx, float* __restrict__ pd_th, float* __restrict__ pd_tw)
{
  int pid = blockIdx.x * 256 + threadIdx.x;
  float2 c = ((const float2*)coords)[pid];

  float h1[32];
#pragma unroll
  for (int j = 0; j < 32; ++j)
    h1[j] = gelu_f(fmaf(c.x, dw0[j], fmaf(c.y, dw0[32 + j], db0[j])));

  float a[32];
#pragma unroll
  for (int j = 0; j < 32; ++j) a[j] = db1[j];
#pragma unroll 4
  for (int k = 0; k < 32; ++k) {
    float hk = h1[k];
    const float* wr = dw1 + k * 32;
#pragma unroll
    for (int j = 0; j < 32; ++j) a[j] = fmaf(hk, wr[j], a[j]);
  }

  float d0 = db2[0], d1 = db2[1];
#pragma unroll 4
  for (int k = 0; k < 32; ++k) {
    float hk = gelu_f(a[k]);
    d0 = fmaf(hk, dw2[2 * k], d0);
    d1 = fmaf(hk, dw2[2 * k + 1], d1);
  }

  float l0 = fminf(fmaxf(c.x + d0, -1.f), 1.f);
  float l1 = fminf(fmaxf(c.y + d1, -1.f), 1.f);
  float ph = (l0 + 1.f) * 0.5f * 127.f;
  float pw = (l1 + 1.f) * 0.5f * 127.f;
  int ih = min(max((int)rintf(ph), 0), 127);
  int iw = min(max((int)rintf(pw), 0), 127);
  int b = pid >> 14;
  int cell = b * HWC + ih * GW + iw;

  int r = atomicAdd(&cnt_i[cell], 1);
  ptrank[pid] = r;
  pd_cell[pid] = cell;

  float fh = floorf(ph), fw = floorf(pw);
  int h0i = min(max((int)fh, 0), 127), w0i = min(max((int)fw, 0), 127);
  pd_idx[pid] = h0i | (w0i << 8);
  pd_th[pid] = ph - fh;
  pd_tw[pid] = pw - fw;
}

// ---------------- scans ----------------
__global__ __launch_bounds__(256) void k_scanA(const int* __restrict__ cnt,
                                               int* __restrict__ starts, int* __restrict__ btot)
{
  __shared__ int sh[256];
  int blk = blockIdx.x, t = threadIdx.x;
  int base = blk * 512;
  int v0 = cnt[base + 2 * t], v1 = cnt[base + 2 * t + 1];
  int pair = v0 + v1;
  sh[t] = pair; __syncthreads();
  int acc = pair;
  for (int off = 1; off < 256; off <<= 1) {
    int add = (t >= off) ? sh[t - off] : 0;
    __syncthreads();
    acc += add; sh[t] = acc;
    __syncthreads();
  }
  int excl = acc - pair;
  starts[base + 2 * t] = excl;
  starts[base + 2 * t + 1] = excl + v0;
  if (t == 255) btot[blk] = acc;
}

__global__ __launch_bounds__(256) void k_scanB(const int* __restrict__ btot, int* __restrict__ boff)
{
  __shared__ int sh[256];
  int t = threadIdx.x;
  int v = btot[t];
  sh[t] = v; __syncthreads();
  int acc = v;
  for (int off = 1; off < 256; off <<= 1) {
    int add = (t >= off) ? sh[t - off] : 0;
    __syncthreads();
    acc += add; sh[t] = acc;
    __syncthreads();
  }
  boff[t] = acc - v;
}

// ---------------- permute: sorted point records + sorted raw scatter values ----------------
__global__ __launch_bounds__(256) void k_perm(const int* __restrict__ pd_cell, const int* __restrict__ ptrank,
                                              const int* __restrict__ starts, const int* __restrict__ boff,
                                              const int* __restrict__ pd_idx, const float* __restrict__ pd_th,
                                              const float* __restrict__ pd_tw,
                                              const float* __restrict__ coords, const float* __restrict__ feats,
                                              int4* __restrict__ pds,
                                              float4* __restrict__ scA, float* __restrict__ scB)
{
  int pid = blockIdx.x * 256 + threadIdx.x;
  int cell = pd_cell[pid];
  int dst = starts[cell] + boff[cell >> 9] + ptrank[pid];
  int4 rec;
  rec.x = pid;
  rec.y = pd_idx[pid];
  rec.z = __float_as_int(pd_th[pid]);
  rec.w = __float_as_int(pd_tw[pid]);
  pds[dst] = rec;
  float2 c = ((const float2*)coords)[pid];
  scA[dst] = make_float4(feats[pid * 3], feats[pid * 3 + 1], feats[pid * 3 + 2], c.x);
  scB[dst] = c.y;
}

// ---------------- segmented cell-sum + lift -> Gh (f16, channel-major); no atomics ----------------
__global__ __launch_bounds__(256) void k_gridlift(const float4* __restrict__ scA, const float* __restrict__ scB,
                                                  const int* __restrict__ starts, const int* __restrict__ boff,
                                                  const int* __restrict__ cnt_i,
                                                  const float* __restrict__ lw,
                                                  const float* __restrict__ lb,
                                                  f16* __restrict__ Gh)
{
  __shared__ float sp[2][128][5];
  __shared__ float s_lw[5][64];
  __shared__ float s_lb[64];
  __shared__ float s_cnt[128];
  int b = blockIdx.y, cbase = blockIdx.x * 128, tid = threadIdx.x;
  int cl = tid & 127, par = tid >> 7;
  int gcell = b * HWC + cbase + cl;
  int start = starts[gcell] + boff[gcell >> 9];
  int cnt = cnt_i[gcell];
  float a0 = 0.f, a1 = 0.f, a2 = 0.f, a3 = 0.f, a4 = 0.f;
  for (int p = start + par; p < start + cnt; p += 2) {
    float4 A = scA[p];
    a0 += A.x; a1 += A.y; a2 += A.z; a3 += A.w; a4 += scB[p];
  }
  sp[par][cl][0] = a0; sp[par][cl][1] = a1; sp[par][cl][2] = a2;
  sp[par][cl][3] = a3; sp[par][cl][4] = a4;
  if (par == 0) s_cnt[cl] = (float)cnt;
  for (int l = tid; l < 320; l += 256) ((float*)s_lw)[l] = lw[l];
  if (tid < 64) s_lb[tid] = lb[tid];
  __syncthreads();
  float v0 = sp[0][cl][0] + sp[1][cl][0];
  float v1 = sp[0][cl][1] + sp[1][cl][1];
  float v2 = sp[0][cl][2] + sp[1][cl][2];
  float v3 = sp[0][cl][3] + sp[1][cl][3];
  float v4 = sp[0][cl][4] + sp[1][cl][4];
  float cntf = s_cnt[cl];
  float inv = 1.f / fmaxf(cntf, 1.f);
  int oh = tid >> 7;
#pragma unroll
  for (int j = 0; j < 32; ++j) {
    int o = oh * 32 + j;
    float val = cntf * s_lb[o];
    val = fmaf(v0, s_lw[0][o], val);
    val = fmaf(v1, s_lw[1][o], val);
    val = fmaf(v2, s_lw[2][o], val);
    val = fmaf(v3, s_lw[3][o], val);
    val = fmaf(v4, s_lw[4][o], val);
    Gh[(size_t)(b * 64 + o) * HWC + cbase + cl] = (f16)(val * inv);
  }
}

// ---------------- fused forward DFT (blocks 0..511) + pointwise conv (blocks 512..1023) ----------------
__global__ __launch_bounds__(256) void k_fwdpw(const f16* __restrict__ Gh,
                                               const f16* __restrict__ Fw_t, const f16* __restrict__ Fh_t,
                                               float2* __restrict__ Xf2,
                                               const float* __restrict__ pww, const float* __restrict__ pwb,
                                               f16* __restrict__ yh)
{
  __shared__ char smem[52224];
  int tid = threadIdx.x;
  int wave = tid >> 6, lane = tid & 63, lr = lane & 15, lg = lane >> 4;

  if (blockIdx.x < 512) {
    // ---- forward DFT: bc = blockIdx.x ----
    f16 (*s_fw)[136]  = (f16(*)[136])smem;                // 48*136*2 = 13056
    f16 (*s_img)[136] = (f16(*)[136])(smem + 13056);      // 128*136*2 = 34816 (union w/ xw+fh)
    f16 (*s_xw)[136]  = (f16(*)[136])(smem + 13056);
    f16 (*s_fh)[136]  = (f16(*)[136])(smem + 13056 + 48 * 136 * 2);
    int bc = blockIdx.x;
    for (int l = tid; l < 2048; l += 256) {
      int r = l >> 4, c = l & 15;
      *(f16x8*)&s_img[r][c * 8] = *(const f16x8*)(Gh + (size_t)bc * HWC + r * 128 + c * 8);
    }
    for (int l = tid; l < 768; l += 256) {
      int r = l >> 4, c = l & 15;
      *(f16x8*)&s_fw[r][c * 8] = *(const f16x8*)(Fw_t + r * 128 + c * 8);
    }
    __syncthreads();

    // GEMM1: Xw[h][n] = sum_w img[h][w] * Fw[w][n]; M=128 N=48 K=128
    f32x4 acc1[2][3] = {};
#pragma unroll
    for (int ks = 0; ks < 4; ++ks) {
      f16x8 a[2], b[3];
#pragma unroll
      for (int mm = 0; mm < 2; ++mm) a[mm] = *(const f16x8*)&s_img[(wave * 2 + mm) * 16 + lr][ks * 32 + lg * 8];
#pragma unroll
      for (int nt = 0; nt < 3; ++nt) b[nt] = *(const f16x8*)&s_fw[nt * 16 + lr][ks * 32 + lg * 8];
#pragma unroll
      for (int mm = 0; mm < 2; ++mm)
#pragma unroll
        for (int nt = 0; nt < 3; ++nt)
          acc1[mm][nt] = __builtin_amdgcn_mfma_f32_16x16x32_f16(a[mm], b[nt], acc1[mm][nt], 0, 0, 0);
    }
    __syncthreads();
#pragma unroll
    for (int mm = 0; mm < 2; ++mm)
#pragma unroll
      for (int nt = 0; nt < 3; ++nt) {
        int n = nt * 16 + lr;
        int h0 = (wave * 2 + mm) * 16 + lg * 4;
#pragma unroll
        for (int r = 0; r < 4; ++r) s_xw[n][h0 + r] = (f16)acc1[mm][nt][r];
      }
    for (int l = tid; l < 1536; l += 256) {
      int r = l >> 4, c = l & 15;
      *(f16x8*)&s_fh[r][c * 8] = *(const f16x8*)(Fh_t + r * 128 + c * 8);
    }
    __syncthreads();

    // GEMM2: P[m'][n] = sum_h xw[m'][h] * Fh[h][n]; M=48 N=96 K=128
    for (int u = wave; u < 9; u += 4) {
      int mt = u / 3, ntC = u - mt * 3;
      f32x4 accC = {}, accS = {};
#pragma unroll
      for (int ks = 0; ks < 4; ++ks) {
        f16x8 a  = *(const f16x8*)&s_xw[mt * 16 + lr][ks * 32 + lg * 8];
        f16x8 bC = *(const f16x8*)&s_fh[ntC * 16 + lr][ks * 32 + lg * 8];
        f16x8 bS = *(const f16x8*)&s_fh[(ntC + 3) * 16 + lr][ks * 32 + lg * 8];
        accC = __builtin_amdgcn_mfma_f32_16x16x32_f16(a, bC, accC, 0, 0, 0);
        accS = __builtin_amdgcn_mfma_f32_16x16x32_f16(a, bS, accS, 0, 0, 0);
      }
      int kx = ntC * 16 + lr;
      int ky0 = (mt * 16 + lg * 4) >> 1;
      Xf2[bc * NMODE + kx * 24 + ky0]     = make_float2(accC[0] + accS[1], accC[1] - accS[0]);
      Xf2[bc * NMODE + kx * 24 + ky0 + 1] = make_float2(accC[2] + accS[3], accC[3] - accS[2]);
    }
  } else {
    // ---- pointwise conv: blk = blockIdx.x - 512 ----
    f16 (*gt)[72] = (f16(*)[72])smem;                 // 256*72*2 = 36864
    f16 (*wt)[72] = (f16(*)[72])(smem + 36864);       // 64*72*2 = 9216
    float* s_b    = (float*)(smem + 46080);           // 256
    int blk = blockIdx.x - 512;
    int b = blk >> 6, p0 = (blk & 63) * 256;
    for (int l = tid; l < 4096; l += 256) {
      int i = l >> 6, o = l & 63;
      wt[o][i] = (f16)pww[l];
    }
    if (tid < 64) s_b[tid] = pwb[tid];
    for (int l = tid; l < 2048; l += 256) {
      int i = l >> 5, pc = (l & 31) * 8;
      f16x8 v = *(const f16x8*)(Gh + (size_t)(b * 64 + i) * HWC + p0 + pc);
#pragma unroll
      for (int j = 0; j < 8; ++j) gt[pc + j][i] = v[j];
    }
    __syncthreads();
    int pw_ = wave * 64;
    f32x4 acc[4][4] = {};
#pragma unroll
    for (int kk = 0; kk < 2; ++kk) {
      f16x8 a[4], bb[4];
#pragma unroll
      for (int mi = 0; mi < 4; ++mi) a[mi] = *(const f16x8*)&wt[16 * mi + lr][kk * 32 + lg * 8];
#pragma unroll
      for (int ni = 0; ni < 4; ++ni) bb[ni] = *(const f16x8*)&gt[pw_ + 16 * ni + lr][kk * 32 + lg * 8];
#pragma unroll
      for (int mi = 0; mi < 4; ++mi)
#pragma unroll
        for (int ni = 0; ni < 4; ++ni)
          acc[mi][ni] = __builtin_amdgcn_mfma_f32_16x16x32_f16(a[mi], bb[ni], acc[mi][ni], 0, 0, 0);
    }
#pragma unroll
    for (int mi = 0; mi < 4; ++mi)
#pragma unroll
      for (int ni = 0; ni < 4; ++ni) {
#pragma unroll
        for (int r = 0; r < 4; ++r) {
          int o = 16 * mi + lg * 4 + r;
          int p = p0 + pw_ + 16 * ni + lr;
          yh[(size_t)(b * 64 + o) * HWC + p] = (f16)(acc[mi][ni][r] + s_b[o]);
        }
      }
  }
}

// ---------------- per-mode 64x64 complex channel mix (f32 VALU, weight-stream-bound) ----------------
__global__ __launch_bounds__(128) void k_mix(const float2* __restrict__ Xf2,
    const float* __restrict__ w1r, const float* __restrict__ w1i,
    const float* __restrict__ w2r, const float* __restrict__ w2i,
    float2* __restrict__ Yf2)
{
  int m = blockIdx.x * 64 + (threadIdx.x & 63);
  int o = blockIdx.y * 2 + (threadIdx.x >> 6);
  int half = blockIdx.z;
  int gm = half * 576 + m;
  const float* wr_ = half ? w2r : w1r;
  const float* wi_ = half ? w2i : w1i;
  float aR[8] = {}, aI[8] = {};
#pragma unroll 2
  for (int i = 0; i < 64; ++i) {
    int widx = (i * 64 + o) * 576 + m;
    float wr = wr_[widx], wi = wi_[widx];
#pragma unroll
    for (int b = 0; b < 8; ++b) {
      float2 x = Xf2[(b * 64 + i) * NMODE + gm];
      aR[b] = fmaf(x.x, wr, aR[b]); aR[b] = fmaf(-x.y, wi, aR[b]);
      aI[b] = fmaf(x.x, wi, aI[b]); aI[b] = fmaf(x.y, wr, aI[b]);
    }
  }
#pragma unroll
  for (int b = 0; b < 8; ++b)
    Yf2[(b * 64 + o) * NMODE + gm] = make_float2(aR[b], aI[b]);
}

// ---------------- inverse DFT (two fused MFMA GEMMs) + add + instnorm + gelu ----------------
__global__ __launch_bounds__(256) void k_inv(const float2* __restrict__ Yf2,
                                             const f16* __restrict__ Bh_t, const f16* __restrict__ Bw_t,
                                             const f16* __restrict__ yh, f16* __restrict__ Gh)
{
  __shared__ f16 s_u[21120];
  __shared__ float rs[256], rq[256];
  __shared__ float s_mu, s_rstd;
  f16 (*s_a)[120]  = (f16(*)[120])s_u;
  f16 (*s_bh)[120] = (f16(*)[120])(s_u + 48 * 120);
  f16 (*s_t)[72]   = (f16(*)[72])s_u;
  f16 (*s_bw)[72]  = (f16(*)[72])(s_u + 128 * 72);
  int bc = blockIdx.x, tid = threadIdx.x;

  for (int l = tid; l < 1152; l += 256) {
    int kx = l / 24, ky = l - kx * 24;
    float2 y = Yf2[bc * NMODE + l];
    s_a[2 * ky][kx]          = (f16)y.x;
    s_a[2 * ky][48 + kx]     = (f16)(-y.y);
    s_a[2 * ky + 1][kx]      = (f16)y.y;
    s_a[2 * ky + 1][48 + kx] = (f16)y.x;
  }
  for (int l = tid; l < 1536; l += 256) {
    int r = l / 12, c = l - r * 12;
    *(f16x8*)&s_bh[r][c * 8] = *(const f16x8*)(Bh_t + r * 96 + c * 8);
  }
  __syncthreads();
  int wave = tid >> 6, lane = tid & 63, lr = lane & 15, lg = lane >> 4;

  f32x4 acc_a[6];
#pragma unroll
  for (int i = 0; i < 6; ++i) acc_a[i] = (f32x4){0.f, 0.f, 0.f, 0.f};
#pragma unroll
  for (int i = 0; i < 6; ++i) {
    int t = wave + 4 * i;
    int mt = t >> 3, nt = t & 7;
#pragma unroll
    for (int ks = 0; ks < 3; ++ks) {
      f16x8 a = *(const f16x8*)&s_a[mt * 16 + lr][ks * 32 + lg * 8];
      f16x8 b = *(const f16x8*)&s_bh[nt * 16 + lr][ks * 32 + lg * 8];
      acc_a[i] = __builtin_amdgcn_mfma_f32_16x16x32_f16(a, b, acc_a[i], 0, 0, 0);
    }
  }
  __syncthreads();
#pragma unroll
  for (int i = 0; i < 6; ++i) {
    int t = wave + 4 * i;
    int mt = t >> 3, nt = t & 7;
    int h = nt * 16 + lr;
    int m0 = mt * 16 + lg * 4;
#pragma unroll
    for (int r = 0; r < 4; ++r) s_t[h][m0 + r] = (f16)acc_a[i][r];
  }
  for (int l = tid; l < 2048; l += 256) {
    int h = l >> 4, c = 48 + (l & 15);
    s_t[h][c] = (f16)0.f;
  }
  for (int l = tid; l < 1024; l += 256) {
    int r = l >> 3, c = l & 7;
    *(f16x8*)&s_bw[r][c * 8] = *(const f16x8*)(Bw_t + r * 64 + c * 8);
  }
  __syncthreads();

  f32x4 acc_b[2][8] = {};
#pragma unroll
  for (int ks = 0; ks < 2; ++ks) {
    f16x8 a[2], b[8];
#pragma unroll
    for (int mm = 0; mm < 2; ++mm) a[mm] = *(const f16x8*)&s_t[(wave * 2 + mm) * 16 + lr][ks * 32 + lg * 8];
#pragma unroll
    for (int nt = 0; nt < 8; ++nt) b[nt] = *(const f16x8*)&s_bw[nt * 16 + lr][ks * 32 + lg * 8];
#pragma unroll
    for (int mm = 0; mm < 2; ++mm)
#pragma unroll
      for (int nt = 0; nt < 8; ++nt)
        acc_b[mm][nt] = __builtin_amdgcn_mfma_f32_16x16x32_f16(a[mm], b[nt], acc_b[mm][nt], 0, 0, 0);
  }
  float sum = 0.f, ssq = 0.f;
#pragma unroll
  for (int mm = 0; mm < 2; ++mm)
#pragma unroll
    for (int nt = 0; nt < 8; ++nt)
#pragma unroll
      for (int r = 0; r < 4; ++r) {
        int h = (wave * 2 + mm) * 16 + lg * 4 + r;
        int w = nt * 16 + lr;
        float v = acc_b[mm][nt][r] * (1.f / 16384.f) + (float)yh[(size_t)bc * HWC + h * 128 + w];
        acc_b[mm][nt][r] = v;
        sum += v; ssq = fmaf(v, v, ssq);
      }
  rs[tid] = sum; rq[tid] = ssq;
  __syncthreads();
  for (int sft = 128; sft > 0; sft >>= 1) {
    if (tid < sft) { rs[tid] += rs[tid + sft]; rq[tid] += rq[tid + sft]; }
    __syncthreads();
  }
  if (tid == 0) {
    float mu = rs[0] * (1.f / 16384.f);
    float var = fmaxf(rq[0] * (1.f / 16384.f) - mu * mu, 0.f);
    s_mu = mu;
    s_rstd = rsqrtf(var + 1e-5f);
  }
  __syncthreads();
  float mu = s_mu, rstd = s_rstd;
#pragma unroll
  for (int mm = 0; mm < 2; ++mm)
#pragma unroll
    for (int nt = 0; nt < 8; ++nt)
#pragma unroll
      for (int r = 0; r < 4; ++r) {
        int h = (wave * 2 + mm) * 16 + lg * 4 + r;
        int w = nt * 16 + lr;
        Gh[(size_t)bc * HWC + h * 128 + w] = (f16)gelu_f((acc_b[mm][nt][r] - mu) * rstd);
      }
}

// ---------------- transpose final grid: Gh[b*64+c][cell] -> Gp[b*16384+cell][c] ----------------
__global__ __launch_bounds__(256) void k_tr(const f16* __restrict__ Gh, f16* __restrict__ Gp)
{
  __shared__ f16 t[64][264];
  int b = blockIdx.x >> 6, cell0 = (blockIdx.x & 63) * 256, tid = threadIdx.x;
  for (int l = tid; l < 2048; l += 256) {
    int c = l >> 5, q = l & 31;
    *(f16x8*)&t[c][q * 8] = *(const f16x8*)(Gh + (size_t)(b * 64 + c) * HWC + cell0 + q * 8);
  }
  __syncthreads();
  int cell = tid;
  f16* dst = Gp + ((size_t)b * HWC + cell0 + cell) * 64;
#pragma unroll
  for (int q = 0; q < 8; ++q) {
    f16x8 v;
#pragma unroll
    for (int j = 0; j < 8; ++j) v[j] = t[q * 8 + j][cell];
    *(f16x8*)(dst + q * 8) = v;
  }
}

// ---------------- fused bilinear gather + projection MLP ----------------
__global__ __launch_bounds__(256) void k_mlp(const f16* __restrict__ Gp,
                                             const int4* __restrict__ pds,
                                             const float* __restrict__ p1w, const float* __restrict__ p1b,
                                             const float* __restrict__ p2w, const float* __restrict__ p2b,
                                             float* __restrict__ out)
{
  __shared__ f16 s_in[128][72];
  __shared__ f16 s_p1[128][72];   // [j][i]
  __shared__ float s_b1[128], s_p2[128];
  __shared__ unsigned s_c0[128], s_c1[128], s_c2[128], s_c3[128];
  __shared__ float4 s_w[128];
  __shared__ int s_pid[128];
  int blk = blockIdx.x, tid = threadIdx.x;
  if (tid < 128) {
    int4 rec = pds[blk * 128 + tid];
    s_pid[tid] = rec.x;
    int b = rec.x >> 14;
    int h0 = rec.y & 255, w0 = (rec.y >> 8) & 255;
    int h1 = min(h0 + 1, 127), w1 = min(w0 + 1, 127);
    float th = __int_as_float(rec.z), tw = __int_as_float(rec.w);
    unsigned gb = ((unsigned)b << 14) * 64u;
    s_c0[tid] = gb + (unsigned)(h0 * 128 + w0) * 64u;
    s_c1[tid] = gb + (unsigned)(h0 * 128 + w1) * 64u;
    s_c2[tid] = gb + (unsigned)(h1 * 128 + w0) * 64u;
    s_c3[tid] = gb + (unsigned)(h1 * 128 + w1) * 64u;
    s_w[tid] = make_float4((1.f - th) * (1.f - tw), (1.f - th) * tw,
                           th * (1.f - tw), th * tw);
    s_b1[tid] = p1b[tid];
    s_p2[tid] = p2w[tid];
  }
  for (int l = tid; l < 8192; l += 256) {
    int i = l >> 7, j = l & 127;
    s_p1[j][i] = (f16)p1w[l];
  }
  __syncthreads();
  for (int l = tid; l < 1024; l += 256) {
    int row = l >> 3, c8 = (l & 7) * 8;
    float4 wv = s_w[row];
    f16x8 a  = *(const f16x8*)(Gp + s_c0[row] + c8);
    f16x8 b2 = *(const f16x8*)(Gp + s_c1[row] + c8);
    f16x8 c  = *(const f16x8*)(Gp + s_c2[row] + c8);
    f16x8 d  = *(const f16x8*)(Gp + s_c3[row] + c8);
    f16x8 o;
#pragma unroll
    for (int j = 0; j < 8; ++j)
      o[j] = (f16)(wv.x * (float)a[j] + wv.y * (float)b2[j] + wv.z * (float)c[j] + wv.w * (float)d[j]);
    *(f16x8*)&s_in[row][c8] = o;
  }
  __syncthreads();
  int wave = tid >> 6, lane = tid & 63, lr = lane & 15, lg = lane >> 4;
  f32x4 acc[2][8] = {};
#pragma unroll
  for (int ks = 0; ks < 2; ++ks) {
    f16x8 a[2], b[8];
#pragma unroll
    for (int mm = 0; mm < 2; ++mm) a[mm] = *(const f16x8*)&s_in[(wave * 2 + mm) * 16 + lr][ks * 32 + lg * 8];
#pragma unroll
    for (int nt = 0; nt < 8; ++nt) b[nt] = *(const f16x8*)&s_p1[nt * 16 + lr][ks * 32 + lg * 8];
#pragma unroll
    for (int mm = 0; mm < 2; ++mm)
#pragma unroll
      for (int nt = 0; nt < 8; ++nt)
        acc[mm][nt] = __builtin_amdgcn_mfma_f32_16x16x32_f16(a[mm], b[nt], acc[mm][nt], 0, 0, 0);
  }
  float p2b0 = p2b[0];
  float part[2][4] = {};
#pragma unroll
  for (int mm = 0; mm < 2; ++mm)
#pragma unroll
    for (int nt = 0; nt < 8; ++nt) {
#pragma unroll
      for (int r = 0; r < 4; ++r) {
        int j = nt * 16 + lr;
        part[mm][r] += gelu_f(acc[mm][nt][r] + s_b1[j]) * s_p2[j];
      }
    }
#pragma unroll
  for (int mm = 0; mm < 2; ++mm)
#pragma unroll
    for (int r = 0; r < 4; ++r) {
      float v = part[mm][r];
      v += __shfl_xor(v, 1, 16);
      v += __shfl_xor(v, 2, 16);
      v += __shfl_xor(v, 4, 16);
      v += __shfl_xor(v, 8, 16);
      if (lr == 0) {
        int pt = (wave * 2 + mm) * 16 + lg * 4 + r;
        out[s_pid[pt]] = v + p2b0;
      }
    }
}

extern "C" void kernel_launch(void* const* d_in, const int* in_sizes, int n_in,
                              void* d_out, int out_size, void* d_ws, size_t ws_size,
                              hipStream_t stream) {
  const float* coords = (const float*)d_in[0];
  const float* feats  = (const float*)d_in[1];
  const float* dw0 = (const float*)d_in[2];
  const float* db0 = (const float*)d_in[3];
  const float* dw1 = (const float*)d_in[4];
  const float* db1 = (const float*)d_in[5];
  const float* dw2 = (const float*)d_in[6];
  const float* db2 = (const float*)d_in[7];
  const float* liftw = (const float*)d_in[8];
  const float* liftb = (const float*)d_in[9];
  const float* sw1r = (const float*)d_in[10];
  const float* sw1i = (const float*)d_in[11];
  const float* sw2r = (const float*)d_in[12];
  const float* sw2i = (const float*)d_in[13];
  const float* pww = (const float*)d_in[14];
  const float* pwb = (const float*)d_in[15];
  const float* p1w = (const float*)d_in[16];
  const float* p1b = (const float*)d_in[17];
  const float* p2w = (const float*)d_in[18];
  const float* p2b = (const float*)d_in[19];
  float* out = (float*)d_out;
  char* base = (char*)d_ws;

  int*    cnt_i  = (int*)(base + 0);            // 524,288 B
  int*    ptrank = (int*)(base + 524288);
  int*    pd_cell= (int*)(base + 1048576);
  int*    starts = (int*)(base + 1572864);
  int*    btot   = (int*)(base + 2097152);
  int*    boff   = (int*)(base + 2098176);
  int*    pd_idx = (int*)(base + 2099200);
  float*  pd_th  = (float*)(base + 2623488);
  float*  pd_tw  = (float*)(base + 3147776);
  f16*    Gh     = (f16*)(base + 8388608);      // 16 MB
  f16*    yh     = (f16*)(base + 25165824);
  float2* Xf2    = (float2*)(base + 41943040);
  float2* Yf2    = (float2*)(base + 46661632);
  int4*   pds    = (int4*)(base + 51380224);
  f16*    Gp     = (f16*)(base + 53477376);
  float4* scA    = (float4*)(base + 70254592);  // 2 MB
  float*  scB    = (float*)(base + 72351744);   // 0.5 MB
  f16*    Fw_t   = (f16*)(base + 87031808);
  f16*    Fh_t   = (f16*)(base + 87044096);
  f16*    Bh_t   = (f16*)(base + 87068672);
  f16*    Bw_t   = (f16*)(base + 87093248);

  hipMemsetAsync(cnt_i, 0, 524288, stream);

  k_twiddle<<<104, 256, 0, stream>>>(Fw_t, Fh_t, Bh_t, Bw_t);
  k_points<<<512, 256, 0, stream>>>(coords, dw0, db0, dw1, db1, dw2, db2,
                                    cnt_i, ptrank, pd_cell, pd_idx, pd_th, pd_tw);
  k_scanA<<<256, 256, 0, stream>>>(cnt_i, starts, btot);
  k_scanB<<<1, 256, 0, stream>>>(btot, boff);
  k_perm<<<512, 256, 0, stream>>>(pd_cell, ptrank, starts, boff, pd_idx, pd_th, pd_tw,
                                  coords, feats, pds, scA, scB);
  k_gridlift<<<dim3(128, 8), 256, 0, stream>>>(scA, scB, starts, boff, cnt_i, liftw, liftb, Gh);

  for (int d = 0; d < 4; ++d) {
    const int swoff = d * 2359296;
    k_fwdpw<<<1024, 256, 0, stream>>>(Gh, Fw_t, Fh_t, Xf2, pww + d * 4096, pwb + d * 64, yh);
    k_mix<<<dim3(9, 32, 2), 128, 0, stream>>>(Xf2, sw1r + swoff, sw1i + swoff,
                                              sw2r + swoff, sw2i + swoff, Yf2);
    k_inv<<<512, 256, 0, stream>>>(Yf2, Bh_t, Bw_t, yh, Gh);
  }

  k_tr<<<512, 256, 0, stream>>>(Gh, Gp);
  k_mlp<<<1024, 256, 0, stream>>>(Gp, pds, p1w, p1b, p2w, p2b, out);
}